// Round 12
// baseline (5357.906 us; speedup 1.0000x reference)
//
#include <hip/hip_runtime.h>
#include <math.h>

namespace {

constexpr int NB  = 256;
constexpr int NT  = 20;
constexpr int NR  = 100;
constexpr int IND = 300;
constexpr int NH  = 1024;
constexpr int VD  = 2048;
constexpr int H4  = 4096;
constexpr int VOC = 10000;
constexpr int VOCP2 = 10240;  // vocab padded to 256 (BN=256 tiles)

// Chunk-interleaved split-bf16 K' layout (A side), dedup B:
//   orig k -> A hi at seg + ((k>>3)<<4) + (k&7), A lo at +8
//   B stored PLAIN [N][K_orig] bf16; duplicated at ds_write into paired slots.
constexpr int KGV = 4704;  constexpr int KGVO = 2352;
constexpr int KGC = 8192;  constexpr int KGCO = 4096;
constexpr int KCL = 2048;  constexpr int KCLO = 1024;
constexpr int A2VLD = 4096;
constexpr int X2LD  = 608;

constexpr int ZGV = 8; constexpr int KSV = 608;
constexpr int ZGC = 8; constexpr int KSC = 1024;

typedef short  s8v  __attribute__((ext_vector_type(8)));
typedef float  f4v  __attribute__((ext_vector_type(4)));

__device__ __forceinline__ float sigm(float x) { return 1.f / (1.f + expf(-x)); }
__device__ __forceinline__ unsigned short f2b(float x) {
  return __builtin_bit_cast(unsigned short, (__bf16)x);
}
__device__ __forceinline__ float b2f(unsigned short u) {
  return (float)__builtin_bit_cast(__bf16, u);
}
__device__ __forceinline__ int Frow(int row) { return (row ^ (row >> 2)) & 3; }
__device__ __forceinline__ void storeCK(unsigned short* rowbase, int segkp, int korig,
                                        float x, int Fs) {
  const unsigned short h = f2b(x);
  const unsigned short l = f2b(x - b2f(h));
  const int ph = segkp + ((korig >> 3) << 4) + (korig & 7);
  rowbase[ph ^ Fs] = h;
  rowbase[(ph + 8) ^ Fs] = l;
}

__device__ __forceinline__ void gload16(const unsigned short* g, unsigned short* l) {
  __builtin_amdgcn_global_load_lds(
      (const __attribute__((address_space(1))) void*)g,
      (__attribute__((address_space(3))) void*)l, 16, 0, 0);
}

#define BARRIER()  __syncthreads()
#define VMWAIT0()  asm volatile("s_waitcnt vmcnt(0)" ::: "memory")

// =================== 128x256 bf16 MFMA GEMM: 32 MFMA/wave/barrier ===============
// 4 waves (2m x 2n), wave tile 64x128, acc[4][8]. LDS 48KB dbuf -> 2-3 blocks/CU.
// DUPB: A chunked (gload), B plain [N][Korig] reg-staged + dup ds_write.
// !DUPB: A,B plain bf16 swizzled rows, both gload.
template<bool OUT_BF16, bool DUPB>
__global__ __launch_bounds__(256)
void gemm_wide(const unsigned short* __restrict__ A, int lda,
               const unsigned short* __restrict__ Bt, int ldb,
               void* __restrict__ Cv, int ldc,
               const float* __restrict__ bias,
               int N, int Kp)
{
  __shared__ unsigned short As[2][128 * 32];
  __shared__ unsigned short Bs[2][256 * 32];
  const int tid = threadIdx.x, wid = tid >> 6, lane = tid & 63;
  const int wm = (wid >> 1) * 64, wn = (wid & 1) * 128;
  const int m0 = blockIdx.x * 128, n0 = blockIdx.y * 256;
  const int sr = tid >> 2, sc = (tid & 3) * 8;
  const unsigned short* a0 = A + (size_t)(m0 + sr) * lda + sc;
  const unsigned short* a1 = a0 + (size_t)64 * lda;
  // plain B staging (4 x 64-row groups)
  const unsigned short* b0 = Bt + (size_t)(n0 + sr) * ldb + sc;
  // DUPB reg staging: rows tid>>1 and 128+(tid>>1), chunk c8=tid&1
  const unsigned short* bD0 = Bt + (size_t)(n0 + (tid >> 1)) * ldb + (tid & 1) * 8;
  const unsigned short* bD1 = bD0 + (size_t)128 * ldb;
  const int rr = lane & 15;
  const int kc = (((lane >> 4) ^ Frow(rr)) & 3) * 8;
  const int wrow = tid >> 1, wc8 = tid & 1;
  const int wF = Frow(wrow & 15);

  f4v acc[4][8] = {};

  auto stageA = [&](int s, int k) {
    gload16(a0 + k, &As[s][tid * 8]);
    gload16(a1 + k, &As[s][2048 + tid * 8]);
  };
  auto stageBplain = [&](int s, int k) {
#pragma unroll
    for (int g = 0; g < 4; ++g)
      gload16(b0 + (size_t)(64 * g) * ldb + k, &Bs[s][2048 * g + tid * 8]);
  };
  auto writeBdup = [&](int s, s8v v0, s8v v1) {
    *(s8v*)&Bs[s][wrow * 32 + (((2 * wc8) ^ wF) * 8)] = v0;
    *(s8v*)&Bs[s][wrow * 32 + (((2 * wc8 + 1) ^ wF) * 8)] = v0;
    *(s8v*)&Bs[s][(128 + wrow) * 32 + (((2 * wc8) ^ wF) * 8)] = v1;
    *(s8v*)&Bs[s][(128 + wrow) * 32 + (((2 * wc8 + 1) ^ wF) * 8)] = v1;
  };
  auto compute = [&](int s) {
    s8v a[4], b[8];
#pragma unroll
    for (int i = 0; i < 4; ++i) a[i] = *(const s8v*)&As[s][(wm + i * 16 + rr) * 32 + kc];
#pragma unroll
    for (int j = 0; j < 8; ++j) b[j] = *(const s8v*)&Bs[s][(wn + j * 16 + rr) * 32 + kc];
#pragma unroll
    for (int i = 0; i < 4; ++i)
#pragma unroll
      for (int j = 0; j < 8; ++j)
        acc[i][j] = __builtin_amdgcn_mfma_f32_16x16x32_bf16(a[i], b[j], acc[i][j], 0, 0, 0);
  };

  // prologue
  stageA(0, 0);
  if constexpr (DUPB) {
    s8v v0 = *(const s8v*)(bD0);
    s8v v1 = *(const s8v*)(bD1);
    VMWAIT0();
    writeBdup(0, v0, v1);
  } else {
    stageBplain(0, 0);
    VMWAIT0();
  }
  BARRIER();

  int cur = 0;
  for (int k0 = 0; k0 < Kp; k0 += 32) {
    const bool more = (k0 + 32 < Kp);
    if constexpr (DUPB) {
      s8v v0, v1;
      if (more) {
        stageA(cur ^ 1, k0 + 32);
        v0 = *(const s8v*)(bD0 + ((k0 + 32) >> 1));
        v1 = *(const s8v*)(bD1 + ((k0 + 32) >> 1));
      }
      compute(cur);
      VMWAIT0();
      if (more) writeBdup(cur ^ 1, v0, v1);
    } else {
      if (more) { stageA(cur ^ 1, k0 + 32); stageBplain(cur ^ 1, k0 + 32); }
      compute(cur);
      VMWAIT0();
    }
    BARRIER();
    cur ^= 1;
  }

  const int cr = (lane >> 4) * 4, cc = lane & 15;
#pragma unroll
  for (int i = 0; i < 4; ++i) {
#pragma unroll
    for (int j = 0; j < 8; ++j) {
      const int gn = n0 + wn + j * 16 + cc;
      if (gn >= N) continue;
#pragma unroll
      for (int r = 0; r < 4; ++r) {
        const int gm = m0 + wm + i * 16 + cr + r;
        float v = acc[i][j][r] + bias[gn];
        if constexpr (OUT_BF16) ((unsigned short*)Cv)[(size_t)gm * ldc + gn] = f2b(v);
        else                    ((float*)Cv)[(size_t)gm * ldc + gn] = v;
      }
    }
  }
}

// =================== split-K GEMM, BM=128 (grid.y), BN=128, dedup-B =============
template<bool XSEG>
__global__ __launch_bounds__(256)
void gemm_sk2(const unsigned short* __restrict__ A, int lda,
              const unsigned short* __restrict__ X2, int t,
              const unsigned short* __restrict__ Bt, int ldb,   // orig-K stride
              float* __restrict__ P, int N, int Kp, int Ksplit)
{
  __shared__ unsigned short As[2][128 * 32];
  __shared__ unsigned short Bs[2][128 * 32];
  const int tid = threadIdx.x, wid = tid >> 6, lane = tid & 63;
  const int wm = (wid >> 1) * 64, wn = (wid & 1) * 64;
  const int m0 = blockIdx.y * 128, n0 = blockIdx.x * 128;
  const int kbeg = blockIdx.z * Ksplit;
  const int kend = min(Kp, kbeg + Ksplit);
  const int sr = tid >> 2, sc = (tid & 3) * 8;
  const unsigned short* a0 = A + (size_t)(m0 + sr) * lda + sc;
  const unsigned short* a1 = a0 + (size_t)64 * lda;
  const unsigned short* x0 = nullptr;
  const unsigned short* x1 = nullptr;
  if constexpr (XSEG) {
    x0 = X2 + ((size_t)(m0 + sr) * NT + t) * X2LD + sc;
    x1 = x0 + (size_t)64 * NT * X2LD;
  }
  const unsigned short* bsrcD = Bt + (size_t)(n0 + (tid >> 1)) * ldb + (tid & 1) * 8;
  const int rr = lane & 15;
  const int kc = (((lane >> 4) ^ Frow(rr)) & 3) * 8;
  const int wrow = tid >> 1, wc8 = tid & 1;
  const int wF = Frow(wrow & 15);

  f4v acc[4][4] = {};

  auto stageA = [&](int s, int k) {
    if constexpr (XSEG) {
      if (k >= A2VLD) {
        gload16(x0 + (k - A2VLD), &As[s][tid * 8]);
        gload16(x1 + (k - A2VLD), &As[s][2048 + tid * 8]);
      } else {
        gload16(a0 + k, &As[s][tid * 8]);
        gload16(a1 + k, &As[s][2048 + tid * 8]);
      }
    } else {
      gload16(a0 + k, &As[s][tid * 8]);
      gload16(a1 + k, &As[s][2048 + tid * 8]);
    }
  };
  auto writeBdup = [&](int s, s8v v) {
    *(s8v*)&Bs[s][wrow * 32 + (((2 * wc8) ^ wF) * 8)] = v;
    *(s8v*)&Bs[s][wrow * 32 + (((2 * wc8 + 1) ^ wF) * 8)] = v;
  };
  auto compute = [&](int s) {
    s8v a[4], b[4];
#pragma unroll
    for (int i = 0; i < 4; ++i) a[i] = *(const s8v*)&As[s][(wm + i * 16 + rr) * 32 + kc];
#pragma unroll
    for (int j = 0; j < 4; ++j) b[j] = *(const s8v*)&Bs[s][(wn + j * 16 + rr) * 32 + kc];
#pragma unroll
    for (int i = 0; i < 4; ++i)
#pragma unroll
      for (int j = 0; j < 4; ++j)
        acc[i][j] = __builtin_amdgcn_mfma_f32_16x16x32_bf16(a[i], b[j], acc[i][j], 0, 0, 0);
  };

  stageA(0, kbeg);
  {
    s8v v = *(const s8v*)(bsrcD + (kbeg >> 1));
    VMWAIT0();
    writeBdup(0, v);
  }
  BARRIER();

  int cur = 0;
  for (int k0 = kbeg; k0 < kend; k0 += 32) {
    const bool more = (k0 + 32 < kend);
    s8v v;
    if (more) { stageA(cur ^ 1, k0 + 32); v = *(const s8v*)(bsrcD + ((k0 + 32) >> 1)); }
    compute(cur);
    VMWAIT0();
    if (more) writeBdup(cur ^ 1, v);
    BARRIER();
    cur ^= 1;
  }

  float* out = P + (size_t)blockIdx.z * 256 * N;
  const int cr = (lane >> 4) * 4, cc = lane & 15;
#pragma unroll
  for (int i = 0; i < 4; ++i)
#pragma unroll
    for (int j = 0; j < 4; ++j)
#pragma unroll
      for (int r = 0; r < 4; ++r)
        out[(size_t)(m0 + wm + i * 16 + cr + r) * N + n0 + wn + j * 16 + cc] = acc[i][j][r];
}

// =================== 128x128 VA fallback (fp32 A converted on stage) ============
__global__ __launch_bounds__(256)
void gemm_va_f32(const float* __restrict__ A, int lda,
                 const unsigned short* __restrict__ Bt, int ldb,
                 unsigned short* __restrict__ C, int ldc,
                 const float* __restrict__ bias, int N, int Kp)
{
  __shared__ unsigned short As[128 * 32];
  __shared__ unsigned short Bs[128 * 32];
  const int tid = threadIdx.x, wid = tid >> 6, lane = tid & 63;
  const int wm = (wid >> 1) * 64, wn = (wid & 1) * 64;
  const int m0 = blockIdx.x * 128, n0 = blockIdx.y * 128;
  const unsigned short* bsrc0 = Bt + (size_t)(n0 + (tid >> 2)) * ldb + (tid & 3) * 8;
  const unsigned short* bsrc1 = bsrc0 + (size_t)64 * ldb;
  const int rr = lane & 15;
  const int kc = (((lane >> 4) ^ Frow(rr)) & 3) * 8;

  f4v acc[4][4] = {};
  for (int k0 = 0; k0 < Kp; k0 += 32) {
#pragma unroll
    for (int it = 0; it < 4; ++it) {
      const int r = it * 32 + (tid >> 3), c = (tid & 7) * 4;
      const float4 v = *(const float4*)(A + (size_t)(m0 + r) * lda + k0 + c);
      ushort4 w;
      w.x = f2b(v.x); w.y = f2b(v.y); w.z = f2b(v.z); w.w = f2b(v.w);
      *(ushort4*)&As[r * 32 + (c ^ (Frow(r & 15) << 3))] = w;
    }
    gload16(bsrc0 + k0, &Bs[tid * 8]);
    gload16(bsrc1 + k0, &Bs[2048 + tid * 8]);
    __syncthreads();
    s8v a[4], b[4];
#pragma unroll
    for (int i = 0; i < 4; ++i) a[i] = *(const s8v*)&As[(wm + i * 16 + rr) * 32 + kc];
#pragma unroll
    for (int j = 0; j < 4; ++j) b[j] = *(const s8v*)&Bs[(wn + j * 16 + rr) * 32 + kc];
#pragma unroll
    for (int i = 0; i < 4; ++i)
#pragma unroll
      for (int j = 0; j < 4; ++j)
        acc[i][j] = __builtin_amdgcn_mfma_f32_16x16x32_bf16(a[i], b[j], acc[i][j], 0, 0, 0);
    __syncthreads();
  }
  const int cr = (lane >> 4) * 4, cc = lane & 15;
#pragma unroll
  for (int i = 0; i < 4; ++i)
#pragma unroll
    for (int j = 0; j < 4; ++j) {
      const int gn = n0 + wn + j * 16 + cc;
      if (gn >= N) continue;
#pragma unroll
      for (int r = 0; r < 4; ++r)
        C[(size_t)(m0 + wm + i * 16 + cr + r) * ldc + gn] = f2b(acc[i][j][r] + bias[gn]);
    }
}

// =================== fp32 GEMM (setup-only) ===================
__global__ __launch_bounds__(256)
void gemm_f32(const float* __restrict__ Ap, int lda,
              const float* __restrict__ Bp, int ldb,
              float* __restrict__ Cp, int ldc,
              const float* __restrict__ bias,
              int M, int N, int K)
{
  __shared__ float As[16][64];
  __shared__ float Bs[16][64];
  const int n0 = blockIdx.x * 64, m0 = blockIdx.y * 64;
  const int tid = threadIdx.x;
  const int tx = tid & 15, ty = tid >> 4;
  float acc[4][4] = {};
  for (int k0 = 0; k0 < K; k0 += 16) {
    {
      const int e = tid << 2;
      const int m = e >> 4, k = e & 15;
      const int gm = m0 + m, gk = k0 + k;
      float4 v = make_float4(0.f, 0.f, 0.f, 0.f);
      if (gm < M) {
        const float* src = Ap + (size_t)gm * lda + gk;
        if (gk + 3 < K) v = *(const float4*)src;
        else {
          if (gk     < K) v.x = src[0];
          if (gk + 1 < K) v.y = src[1];
          if (gk + 2 < K) v.z = src[2];
          if (gk + 3 < K) v.w = src[3];
        }
      }
      As[k][m] = v.x; As[k + 1][m] = v.y; As[k + 2][m] = v.z; As[k + 3][m] = v.w;
    }
    {
      const int e = tid << 2;
      const int k = e >> 6, n = e & 63;
      const int gk = k0 + k, gn = n0 + n;
      float4 v = make_float4(0.f, 0.f, 0.f, 0.f);
      if (gk < K) {
        const float* src = Bp + (size_t)gk * ldb + gn;
        if (gn + 3 < N) v = *(const float4*)src;
        else {
          if (gn     < N) v.x = src[0];
          if (gn + 1 < N) v.y = src[1];
          if (gn + 2 < N) v.z = src[2];
          if (gn + 3 < N) v.w = src[3];
        }
      }
      Bs[k][n] = v.x; Bs[k][n + 1] = v.y; Bs[k][n + 2] = v.z; Bs[k][n + 3] = v.w;
    }
    __syncthreads();
#pragma unroll
    for (int k = 0; k < 16; ++k) {
      const float a0 = As[k][ty * 4 + 0], a1 = As[k][ty * 4 + 1];
      const float a2 = As[k][ty * 4 + 2], a3 = As[k][ty * 4 + 3];
      const float b0 = Bs[k][tx * 4 + 0], b1 = Bs[k][tx * 4 + 1];
      const float b2 = Bs[k][tx * 4 + 2], b3 = Bs[k][tx * 4 + 3];
      acc[0][0] += a0 * b0; acc[0][1] += a0 * b1; acc[0][2] += a0 * b2; acc[0][3] += a0 * b3;
      acc[1][0] += a1 * b0; acc[1][1] += a1 * b1; acc[1][2] += a1 * b2; acc[1][3] += a1 * b3;
      acc[2][0] += a2 * b0; acc[2][1] += a2 * b1; acc[2][2] += a2 * b2; acc[2][3] += a2 * b3;
      acc[3][0] += a3 * b0; acc[3][1] += a3 * b1; acc[3][2] += a3 * b2; acc[3][3] += a3 * b3;
    }
    __syncthreads();
  }
#pragma unroll
  for (int i = 0; i < 4; ++i) {
    const int gm = m0 + ty * 4 + i;
    if (gm >= M) continue;
#pragma unroll
    for (int j = 0; j < 4; ++j) {
      const int gn = n0 + tx * 4 + j;
      if (gn >= N) continue;
      Cp[(size_t)gm * ldc + gn] = acc[i][j] + bias[gn];
    }
  }
}

// =================== weight transpose+convert ===================
// mode 0: PLAIN bf16-hi at orig k, no swizzle (dedup-B)
// mode 1: plain hi, swizzled (VA's B, gload path)
__global__ void convB_k(const float* __restrict__ src, int srcld, int K, int N,
                        unsigned short* __restrict__ dst, int dstld, int coff, int mode)
{
  __shared__ float t[32][33];
  const int kb = blockIdx.x * 32, nb = blockIdx.y * 32;
  const int tx = threadIdx.x & 31, ty = threadIdx.x >> 5;
#pragma unroll
  for (int i = 0; i < 32; i += 8) {
    const int k = kb + ty + i, n = nb + tx;
    t[ty + i][tx] = (k < K && n < N) ? src[(size_t)k * srcld + n] : 0.f;
  }
  __syncthreads();
#pragma unroll
  for (int i = 0; i < 32; i += 8) {
    const int n = nb + ty + i, k = kb + tx;
    if (n >= N || k >= K) continue;
    const float x = t[tx][ty + i];
    unsigned short* row = dst + (size_t)n * dstld;
    if (mode == 0) {
      row[coff + k] = f2b(x);
    } else {
      row[(coff + k) ^ (Frow(n & 15) << 3)] = f2b(x);
    }
  }
}

__global__ void zpad_plain_k(unsigned short* __restrict__ dst, int ld, int c0, int N)
{
  const int w = ld - c0;
  const int idx = blockIdx.x * 256 + threadIdx.x;
  if (idx >= N * w) return;
  dst[(size_t)(idx / w) * ld + c0 + (idx % w)] = 0;
}

__global__ void zfill_k(unsigned short* __restrict__ p, int n)
{
  const int i = blockIdx.x * 256 + threadIdx.x;
  if (i < n) p[i] = 0;
}

// plain elementwise f32 -> bf16 copy (W_ha k-major)
__global__ void f2bcopy_k(const float* __restrict__ in, unsigned short* __restrict__ out, int n)
{
  const int i = blockIdx.x * 256 + threadIdx.x;
  if (i < n) out[i] = f2b(in[i]);
}

// =================== fused feature pass: mean + bf16 convert ===================
__global__ void feat_pass_k(const float* __restrict__ feat, float* __restrict__ fm,
                            unsigned short* __restrict__ f16out)
{
  const int idx = blockIdx.x * 256 + threadIdx.x;   // NB * VD/8
  if (idx >= NB * (VD / 8)) return;
  const int d0 = (idx & (VD / 8 - 1)) * 8, b = idx / (VD / 8);
  const float* base = feat + (size_t)b * NR * VD + d0;
  float s[8] = {};
  for (int r = 0; r < NR; ++r) {
    const float4 x0 = *(const float4*)(base + (size_t)r * VD);
    const float4 x1 = *(const float4*)(base + (size_t)r * VD + 4);
    s[0] += x0.x; s[1] += x0.y; s[2] += x0.z; s[3] += x0.w;
    s[4] += x1.x; s[5] += x1.y; s[6] += x1.z; s[7] += x1.w;
    if (f16out) {
      unsigned short w[8] = {f2b(x0.x), f2b(x0.y), f2b(x0.z), f2b(x0.w),
                             f2b(x1.x), f2b(x1.y), f2b(x1.z), f2b(x1.w)};
      const int ro = b * NR + r;
      *(s8v*)(f16out + (size_t)ro * VD + (d0 ^ (Frow(ro & 15) << 3))) = *(const s8v*)w;
    }
  }
#pragma unroll
  for (int e = 0; e < 8; ++e) fm[(size_t)b * VD + d0 + e] = s[e] * (1.f / NR);
}

// X2: chunked split layout, swizzled by F(b)
__global__ void build_x2_k(const int* __restrict__ cap, const float* __restrict__ emb,
                           const float* __restrict__ vinp, unsigned short* __restrict__ X2)
{
  const int idx = blockIdx.x * 256 + threadIdx.x;
  if (idx >= NB * NT * X2LD) return;
  const int c = idx % X2LD;
  const int bt = idx / X2LD;
  const int t = bt % NT, b = bt / NT;
  const int Fs = Frow(b & 15) << 3;
  const int chunk = c >> 4, sub = (c >> 3) & 1, w = c & 7;
  const int d = chunk * 8 + w;
  unsigned short val = 0;
  if (d < IND) {
    const float v = (t == 0) ? vinp[b * IND + d]
                             : emb[(size_t)cap[b * (NT - 1) + (t - 1)] * IND + d];
    const unsigned short h = f2b(v);
    val = sub ? f2b(v - b2f(h)) : h;
  }
  X2[(size_t)bt * X2LD + (c ^ Fs)] = val;
}

// LSTM-c pointwise (unchanged)
__global__ void lstm_pw_c_k(const float* __restrict__ gp, const float* __restrict__ bc,
                            float* __restrict__ cc,
                            unsigned short* __restrict__ A2v, unsigned short* __restrict__ A2c,
                            unsigned short* __restrict__ outh2, int t)
{
  const int idx = blockIdx.x * 256 + threadIdx.x;
  if (idx >= NB * NH) return;
  const int n = idx & (NH - 1), b = idx >> 10;
  const size_t base = (size_t)b * H4;
  float gi = bc[n], gf = bc[NH + n], gg = bc[2 * NH + n], go = bc[3 * NH + n];
#pragma unroll
  for (int z = 0; z < ZGC; ++z) {
    const float* g = gp + (size_t)z * NB * H4 + base;
    gi += g[n]; gf += g[NH + n]; gg += g[2 * NH + n]; go += g[3 * NH + n];
  }
  const float c2 = sigm(gf) * cc[idx] + sigm(gi) * tanhf(gg);
  const float h2 = sigm(go) * tanhf(c2);
  cc[idx] = c2;
  const int Fs = Frow(b & 15) << 3;
  storeCK(A2v + (size_t)b * A2VLD, 0, n, h2, Fs);
  storeCK(A2c + (size_t)b * KGC, 6144, n, h2, Fs);
  const int ro = b * NT + t;
  storeCK(outh2 + (size_t)ro * KCL, 0, n, h2, Frow(ro & 15) << 3);
}

// =================== att_mega: LSTM-v reduce + ha + logits + softmax + feat_hat =
// one block per b (512 threads)
template<bool F16>
__global__ __launch_bounds__(512)
void att_mega_k(const float* __restrict__ gp,      // [ZGV][NB][H4] gates_v partials
                const float* __restrict__ fmg,     // feat_mean gates + b_v
                float* __restrict__ cv,
                const unsigned short* __restrict__ W16,  // [NH][NH] bf16 k-major W_ha
                const float* __restrict__ bha,
                const float* __restrict__ Wa, const float* __restrict__ ba,
                const unsigned short* __restrict__ va16,
                const unsigned short* __restrict__ f16,
                const float* __restrict__ f32,
                unsigned short* __restrict__ A2c, unsigned short* __restrict__ A2v,
                float* __restrict__ att_out, int t)
{
  const int b = blockIdx.x, tid = threadIdx.x;
  const int lane = tid & 63, wid = tid >> 6;
  __shared__ float hv_s[NH];
  __shared__ float ha_s[NH];
  __shared__ float wa_s[NH];
  __shared__ float red_s[128];
  const int Fs = Frow(b & 15) << 3;
  const size_t gbase = (size_t)b * H4;

  // ---- phase 1: reduce gates_v partials + LSTM-v update (2 cells/thread) ----
  for (int n = tid; n < NH; n += 512) {
    float gi = fmg[gbase + n], gf = fmg[gbase + NH + n];
    float gg = fmg[gbase + 2 * NH + n], go = fmg[gbase + 3 * NH + n];
#pragma unroll
    for (int z = 0; z < ZGV; ++z) {
      const float* g = gp + (size_t)z * NB * H4 + gbase;
      gi += g[n]; gf += g[NH + n]; gg += g[2 * NH + n]; go += g[3 * NH + n];
    }
    const int ci = b * NH + n;
    const float c2 = sigm(gf) * cv[ci] + sigm(gi) * tanhf(gg);
    const float h2 = sigm(go) * tanhf(c2);
    cv[ci] = c2;
    hv_s[n] = h2;
    storeCK(A2c + (size_t)b * KGC, 4096, n, h2, Fs);
    storeCK(A2v + (size_t)b * A2VLD, 2048, n, h2, Fs);
    wa_s[n] = Wa[n];
  }
  __syncthreads();

  // ---- phase 2: ha = h_v @ W_ha + b_ha (2 consecutive n per thread) ----
  {
    const int np = tid * 2;
    float h0 = 0.f, h1 = 0.f;
#pragma unroll 4
    for (int k = 0; k < NH; ++k) {
      const float hv = hv_s[k];
      const unsigned int w = *(const unsigned int*)(W16 + (size_t)k * NH + np);
      h0 += hv * b2f((unsigned short)(w & 0xffff));
      h1 += hv * b2f((unsigned short)(w >> 16));
    }
    ha_s[np]     = h0 + bha[np];
    ha_s[np + 1] = h1 + bha[np + 1];
  }
  __syncthreads();

  // ---- phase 3: logits ----
  for (int r = wid; r < NR; r += 8) {
    const unsigned short* vrow = va16 + ((size_t)b * NR + r) * NH + lane * 16;
    float s = 0.f;
#pragma unroll
    for (int u = 0; u < 2; ++u) {
      const s8v v = *(const s8v*)(vrow + u * 8);
      const int j0 = lane * 16 + u * 8;
#pragma unroll
      for (int e = 0; e < 8; ++e)
        s += tanhf(b2f((unsigned short)v[e]) + ha_s[j0 + e]) * wa_s[j0 + e];
    }
    for (int o = 32; o; o >>= 1) s += __shfl_down(s, o);
    if (lane == 0) red_s[r] = s + ba[0];
  }
  __syncthreads();

  // ---- phase 4: softmax over regions ----
  if (wid == 0) {
    float v0 = (lane < NR) ? red_s[lane] : -3.4e38f;
    float v1 = (lane + 64 < NR) ? red_s[lane + 64] : -3.4e38f;
    float m = fmaxf(v0, v1);
    for (int o = 32; o; o >>= 1) m = fmaxf(m, __shfl_xor(m, o));
    const float e0 = (lane < NR) ? expf(v0 - m) : 0.f;
    const float e1 = (lane + 64 < NR) ? expf(v1 - m) : 0.f;
    float s = e0 + e1;
    for (int o = 32; o; o >>= 1) s += __shfl_xor(s, o);
    const float inv = 1.f / s;
    if (lane < NR) red_s[lane] = e0 * inv;
    if (lane + 64 < NR) red_s[lane + 64] = e1 * inv;
  }
  __syncthreads();
  if (tid < NR) att_out[((size_t)b * NT + t) * NR + tid] = red_s[tid];

  // ---- phase 5: feat_hat (4 d per thread) ----
  const int d0 = tid * 4;
  float fh[4] = {};
  if constexpr (F16) {
    const unsigned short* fbase = f16 + (size_t)b * NR * VD;
    for (int r = 0; r < NR; ++r) {
      const int ro = b * NR + r;
      const ushort4 f = *(const ushort4*)(fbase + (size_t)r * VD + (d0 ^ (Frow(ro & 15) << 3)));
      const float a = red_s[r];
      fh[0] += a * b2f(f.x); fh[1] += a * b2f(f.y);
      fh[2] += a * b2f(f.z); fh[3] += a * b2f(f.w);
    }
  } else {
    const float* fb = f32 + (size_t)b * NR * VD + d0;
    for (int r = 0; r < NR; ++r) {
      const float4 x0 = *(const float4*)(fb + (size_t)r * VD);
      const float a = red_s[r];
      fh[0] += a * x0.x; fh[1] += a * x0.y; fh[2] += a * x0.z; fh[3] += a * x0.w;
    }
  }
  unsigned short* rowbase = A2c + (size_t)b * KGC;
#pragma unroll
  for (int e = 0; e < 4; ++e) storeCK(rowbase, 0, d0 + e, fh[e] * (1.f / NR), Fs);
}

inline void gemmF(hipStream_t st, const float* A, int lda, const float* B, int ldb,
                  float* C, int ldc, const float* bias, int M, int N, int K)
{
  dim3 g((N + 63) / 64, (M + 63) / 64);
  gemm_f32<<<g, 256, 0, st>>>(A, lda, B, ldb, C, ldc, bias, M, N, K);
}

inline void convB(hipStream_t st, const float* src, int srcld, int K, int N,
                  unsigned short* dst, int dstld, int coff, int mode)
{
  dim3 g((K + 31) / 32, (N + 31) / 32);
  convB_k<<<g, 256, 0, st>>>(src, srcld, K, N, dst, dstld, coff, mode);
}

} // namespace

extern "C" void kernel_launch(void* const* d_in, const int* in_sizes, int n_in,
                              void* d_out, int out_size, void* d_ws, size_t ws_size,
                              hipStream_t stream)
{
  const int*   caption = (const int*)  d_in[0];
  const float* feat    = (const float*)d_in[1];
  const float* emb     = (const float*)d_in[2];
  const float* W_vin   = (const float*)d_in[3];
  const float* b_vin   = (const float*)d_in[4];
  const float* W_ih_v  = (const float*)d_in[5];
  const float* W_hh_v  = (const float*)d_in[6];
  const float* b_v     = (const float*)d_in[7];
  const float* W_va    = (const float*)d_in[8];
  const float* b_va    = (const float*)d_in[9];
  const float* W_ha    = (const float*)d_in[10];
  const float* b_ha    = (const float*)d_in[11];
  const float* W_a     = (const float*)d_in[12];
  const float* b_a     = (const float*)d_in[13];
  const float* W_ih_c  = (const float*)d_in[14];
  const float* W_hh_c  = (const float*)d_in[15];
  const float* b_c     = (const float*)d_in[16];
  const float* W_cls   = (const float*)d_in[17];
  const float* b_cls   = (const float*)d_in[18];

  float* out_repr = (float*)d_out;                       // [NB,NT,VOC]
  float* out_att  = out_repr + (size_t)NB * NT * VOC;    // [NB,NT,NR]

  char* cur = (char*)d_ws;
  auto take = [&](size_t bytes) { char* p = cur; cur += bytes; return p; };

  unsigned short* A2v  = (unsigned short*)take((size_t)NB * A2VLD * 2);
  unsigned short* A2c  = (unsigned short*)take((size_t)NB * KGC * 2);
  float* CV            = (float*)take((size_t)NB * NH * 4);
  float* CC            = (float*)take((size_t)NB * NH * 4);
  const size_t ZERO_BYTES = (size_t)NB * A2VLD * 2 + (size_t)NB * KGC * 2
                          + 2 * (size_t)NB * NH * 4;

  float* FM            = (float*)take((size_t)NB * VD * 4);
  float* VINP          = (float*)take((size_t)NB * IND * 4);
  unsigned short* X2   = (unsigned short*)take((size_t)NB * NT * X2LD * 2);
  float* FMG           = (float*)take((size_t)NB * H4 * 4);
  unsigned short* VA16 = (unsigned short*)take((size_t)NB * NR * NH * 2);   // 52MB
  float* GP            = (float*)take((size_t)ZGC * NB * H4 * 4);           // 33.5MB
  unsigned short* OUTH2= (unsigned short*)take((size_t)NB * NT * KCL * 2);  // 21MB
  unsigned short* Wgv2t= (unsigned short*)take((size_t)H4 * KGVO * 2);      // 19.3MB
  unsigned short* W16  = (unsigned short*)take((size_t)NH * NH * 2);        // 2.1MB
  unsigned short* Wgc2t= (unsigned short*)take((size_t)H4 * KGCO * 2);      // 33.5MB
  unsigned short* Wcls2t=(unsigned short*)take((size_t)VOCP2 * KCLO * 2);   // 21MB
  unsigned short* Wva16t=(unsigned short*)take((size_t)NH * VD * 2);        // 4.2MB
  unsigned short* FEAT16=(unsigned short*)cur;                              // 105MB optional
  const bool useF16 = ((size_t)(cur - (char*)d_ws) + (size_t)NB * NR * VD * 2) <= ws_size;

  hipMemsetAsync(A2v, 0, ZERO_BYTES, stream);

  // ---- weight conversions ----
  convB(stream, W_ih_v + (size_t)2048 * H4, H4, 1024, H4, Wgv2t, KGVO, 0,    0);
  convB(stream, W_hh_v,                     H4, 1024, H4, Wgv2t, KGVO, 1024, 0);
  convB(stream, W_ih_v + (size_t)3072 * H4, H4, 300,  H4, Wgv2t, KGVO, 2048, 0);
  zpad_plain_k<<<((H4 * (KGVO - 2348)) + 255) / 256, 256, 0, stream>>>(
      Wgv2t, KGVO, 2348, H4);
  f2bcopy_k<<<(NH * NH + 255) / 256, 256, 0, stream>>>(W_ha, W16, NH * NH);
  convB(stream, W_ih_c,                     H4, 2048, H4, Wgc2t, KGCO, 0,    0);
  convB(stream, W_ih_c + (size_t)2048 * H4, H4, 1024, H4, Wgc2t, KGCO, 2048, 0);
  convB(stream, W_hh_c,                     H4, 1024, H4, Wgc2t, KGCO, 3072, 0);
  convB(stream, W_cls, VOC, 1024, VOC, Wcls2t, KCLO, 0, 0);
  zfill_k<<<(((VOCP2 - VOC) * KCLO) + 255) / 256, 256, 0, stream>>>(
      Wcls2t + (size_t)VOC * KCLO, (VOCP2 - VOC) * KCLO);
  convB(stream, W_va, NH, VD, NH, Wva16t, VD, 0, 1);

  // ---- setup ----
  feat_pass_k<<<(NB * (VD / 8) + 255) / 256, 256, 0, stream>>>(
      feat, FM, useF16 ? FEAT16 : nullptr);
  gemmF(stream, FM, VD, W_vin, IND, VINP, IND, b_vin, NB, IND, VD);
  build_x2_k<<<(NB * NT * X2LD + 255) / 256, 256, 0, stream>>>(caption, emb, VINP, X2);
  gemmF(stream, FM, VD, W_ih_v, H4, FMG, H4, b_v, NB, H4, VD);
  if (useF16) {
    dim3 g((NB * NR) / 128, NH / 256);
    gemm_wide<true, false><<<g, 256, 0, stream>>>(
        FEAT16, VD, Wva16t, VD, VA16, NH, b_va, NH, VD);
  } else {
    dim3 g((NB * NR) / 128, NH / 128);
    gemm_va_f32<<<g, 256, 0, stream>>>(feat, VD, Wva16t, VD, VA16, NH, b_va, NH, VD);
  }

  // ---- sequential decode: 4 kernels/step ----
  for (int t = 0; t < NT; ++t) {
    gemm_sk2<true><<<dim3(H4 / 128, 2, ZGV), 256, 0, stream>>>(
        A2v, A2VLD, X2, t, Wgv2t, KGVO, GP, H4, KGV, KSV);
    if (useF16)
      att_mega_k<true><<<NB, 512, 0, stream>>>(
          GP, FMG, CV, W16, b_ha, W_a, b_a, VA16, FEAT16, nullptr,
          A2c, A2v, out_att, t);
    else
      att_mega_k<false><<<NB, 512, 0, stream>>>(
          GP, FMG, CV, W16, b_ha, W_a, b_a, VA16, nullptr, feat,
          A2c, A2v, out_att, t);
    gemm_sk2<false><<<dim3(H4 / 128, 2, ZGC), 256, 0, stream>>>(
        A2c, KGC, nullptr, 0, Wgc2t, KGCO, GP, H4, KGC, KSC);
    lstm_pw_c_k<<<(NB * NH + 255) / 256, 256, 0, stream>>>(GP, b_c, CC, A2v, A2c, OUTH2, t);
  }

  // ---- classifier: 128x256 tiles, dedup-B ----
  {
    dim3 g((NB * NT) / 128, VOCP2 / 256);
    gemm_wide<false, true><<<g, 256, 0, stream>>>(
        OUTH2, KCL, Wcls2t, KCLO, out_repr, VOC, b_cls, VOC, KCL);
  }
}

// Round 13
// 3494.238 us; speedup vs baseline: 1.5334x; 1.5334x over previous
//
#include <hip/hip_runtime.h>
#include <math.h>

namespace {

constexpr int NB  = 256;
constexpr int NT  = 20;
constexpr int NR  = 100;
constexpr int IND = 300;
constexpr int NH  = 1024;
constexpr int VD  = 2048;
constexpr int H4  = 4096;
constexpr int VOC = 10000;
constexpr int VOCP = 10112;   // vocab padded to 128

// Chunk-interleaved split-bf16 K' layout (A side), dedup B:
//   orig k -> A hi at seg + ((k>>3)<<4) + (k&7), A lo at +8
//   B stored PLAIN [N][K_orig] bf16; duplicated at ds_write into paired slots.
constexpr int KGV = 4704;  constexpr int KGVO = 2352;
constexpr int KGC = 8192;  constexpr int KGCO = 4096;
constexpr int KHA = 2048;  constexpr int KHAO = 1024;
constexpr int KCL = 2048;  constexpr int KCLO = 1024;
constexpr int KFM = 4096;  constexpr int KFMO = 2048;   // FMG: feat_mean @ W_ih_v[0:2048]
constexpr int A2VLD = 4096;
constexpr int X2LD  = 608;

constexpr int ZGV = 8; constexpr int KSV = 608;
constexpr int ZGC = 8; constexpr int KSC = 1024;
constexpr int ZHA = 8; constexpr int KSH = 256;
constexpr int ZFM = 8; constexpr int KSF = 512;

typedef short  s8v  __attribute__((ext_vector_type(8)));
typedef float  f4v  __attribute__((ext_vector_type(4)));

__device__ __forceinline__ float sigm(float x) { return 1.f / (1.f + expf(-x)); }
__device__ __forceinline__ unsigned short f2b(float x) {
  return __builtin_bit_cast(unsigned short, (__bf16)x);
}
__device__ __forceinline__ float b2f(unsigned short u) {
  return (float)__builtin_bit_cast(__bf16, u);
}
__device__ __forceinline__ int Frow(int row) { return (row ^ (row >> 2)) & 3; }
__device__ __forceinline__ void storeCK(unsigned short* rowbase, int segkp, int korig,
                                        float x, int Fs) {
  const unsigned short h = f2b(x);
  const unsigned short l = f2b(x - b2f(h));
  const int ph = segkp + ((korig >> 3) << 4) + (korig & 7);
  rowbase[ph ^ Fs] = h;
  rowbase[(ph + 8) ^ Fs] = l;
}

__device__ __forceinline__ void gload16(const unsigned short* g, unsigned short* l) {
  __builtin_amdgcn_global_load_lds(
      (const __attribute__((address_space(1))) void*)g,
      (__attribute__((address_space(3))) void*)l, 16, 0, 0);
}

#define BARRIER()  __syncthreads()
#define VMWAIT0()  asm volatile("s_waitcnt vmcnt(0)" ::: "memory")

// =================== 128x128 bf16 MFMA GEMM, 2-phase dbuf =======================
// DUPB: A chunk-interleaved (gload), B plain [N][Kp/2] reg-staged + dup ds_write.
// !DUPB: plain bf16 A and B, both gload from swizzled storage (VA path).
template<bool OUT_BF16, bool DUPB>
__global__ __launch_bounds__(256)
void gemm128(const unsigned short* __restrict__ A, int lda,
             const unsigned short* __restrict__ Bt, int ldb,   // ldb = orig-K if DUPB
             void* __restrict__ Cv, int ldc,
             const float* __restrict__ bias,
             int N, int Kp)
{
  __shared__ unsigned short As[2][128 * 32];
  __shared__ unsigned short Bs[2][128 * 32];
  const int tid = threadIdx.x, wid = tid >> 6, lane = tid & 63;
  const int wm = (wid >> 1) * 64, wn = (wid & 1) * 64;
  const int m0 = blockIdx.x * 128, n0 = blockIdx.y * 128;
  const int sr = tid >> 2, sc = (tid & 3) * 8;
  const unsigned short* a0 = A + (size_t)(m0 + sr) * lda + sc;
  const unsigned short* a1 = a0 + (size_t)64 * lda;
  const unsigned short* bsrcD = Bt + (size_t)(n0 + (tid >> 1)) * ldb + (tid & 1) * 8;
  const unsigned short* b0 = Bt + (size_t)(n0 + sr) * ldb + sc;
  const unsigned short* b1 = b0 + (size_t)64 * ldb;
  const int rr = lane & 15;
  const int kc = (((lane >> 4) ^ Frow(rr)) & 3) * 8;
  const int wrow = tid >> 1, wc8 = tid & 1;
  const int wF = Frow(wrow & 15);

  f4v acc[4][4] = {};

  auto stageA = [&](int s, int k) {
    gload16(a0 + k, &As[s][tid * 8]);
    gload16(a1 + k, &As[s][2048 + tid * 8]);
  };
  auto stageBplain = [&](int s, int k) {
    gload16(b0 + k, &Bs[s][tid * 8]);
    gload16(b1 + k, &Bs[s][2048 + tid * 8]);
  };
  auto writeBdup = [&](int s, s8v v) {
    *(s8v*)&Bs[s][wrow * 32 + (((2 * wc8) ^ wF) * 8)] = v;
    *(s8v*)&Bs[s][wrow * 32 + (((2 * wc8 + 1) ^ wF) * 8)] = v;
  };
  auto compute = [&](int s) {
    s8v a[4], b[4];
#pragma unroll
    for (int i = 0; i < 4; ++i) a[i] = *(const s8v*)&As[s][(wm + i * 16 + rr) * 32 + kc];
#pragma unroll
    for (int j = 0; j < 4; ++j) b[j] = *(const s8v*)&Bs[s][(wn + j * 16 + rr) * 32 + kc];
#pragma unroll
    for (int i = 0; i < 4; ++i)
#pragma unroll
      for (int j = 0; j < 4; ++j)
        acc[i][j] = __builtin_amdgcn_mfma_f32_16x16x32_bf16(a[i], b[j], acc[i][j], 0, 0, 0);
  };

  // prologue
  stageA(0, 0);
  if constexpr (DUPB) {
    s8v v = *(const s8v*)(bsrcD);
    VMWAIT0();
    writeBdup(0, v);
  } else {
    stageBplain(0, 0);
    VMWAIT0();
  }
  BARRIER();

  int cur = 0;
  for (int k0 = 0; k0 < Kp; k0 += 32) {
    const bool more = (k0 + 32 < Kp);
    if constexpr (DUPB) {
      s8v v;
      if (more) { stageA(cur ^ 1, k0 + 32); v = *(const s8v*)(bsrcD + ((k0 + 32) >> 1)); }
      compute(cur);
      VMWAIT0();
      if (more) writeBdup(cur ^ 1, v);
    } else {
      if (more) { stageA(cur ^ 1, k0 + 32); stageBplain(cur ^ 1, k0 + 32); }
      compute(cur);
      VMWAIT0();
    }
    BARRIER();
    cur ^= 1;
  }

  const int cr = (lane >> 4) * 4, cc = lane & 15;
#pragma unroll
  for (int i = 0; i < 4; ++i) {
#pragma unroll
    for (int j = 0; j < 4; ++j) {
      const int gn = n0 + wn + j * 16 + cc;
      if (gn >= N) continue;
#pragma unroll
      for (int r = 0; r < 4; ++r) {
        const int gm = m0 + wm + i * 16 + cr + r;
        float v = acc[i][j][r] + bias[gn];
        if constexpr (OUT_BF16) ((unsigned short*)Cv)[(size_t)gm * ldc + gn] = f2b(v);
        else                    ((float*)Cv)[(size_t)gm * ldc + gn] = v;
      }
    }
  }
}

// =================== split-K GEMM, BM=128 (grid.y), BN=128, dedup-B =============
template<bool XSEG>
__global__ __launch_bounds__(256)
void gemm_sk2(const unsigned short* __restrict__ A, int lda,
              const unsigned short* __restrict__ X2, int t,
              const unsigned short* __restrict__ Bt, int ldb,   // orig-K stride
              float* __restrict__ P, int N, int Kp, int Ksplit)
{
  __shared__ unsigned short As[2][128 * 32];
  __shared__ unsigned short Bs[2][128 * 32];
  const int tid = threadIdx.x, wid = tid >> 6, lane = tid & 63;
  const int wm = (wid >> 1) * 64, wn = (wid & 1) * 64;
  const int m0 = blockIdx.y * 128, n0 = blockIdx.x * 128;
  const int kbeg = blockIdx.z * Ksplit;
  const int kend = min(Kp, kbeg + Ksplit);
  const int sr = tid >> 2, sc = (tid & 3) * 8;
  const unsigned short* a0 = A + (size_t)(m0 + sr) * lda + sc;
  const unsigned short* a1 = a0 + (size_t)64 * lda;
  const unsigned short* x0 = nullptr;
  const unsigned short* x1 = nullptr;
  if constexpr (XSEG) {
    x0 = X2 + ((size_t)(m0 + sr) * NT + t) * X2LD + sc;
    x1 = x0 + (size_t)64 * NT * X2LD;
  }
  const unsigned short* bsrcD = Bt + (size_t)(n0 + (tid >> 1)) * ldb + (tid & 1) * 8;
  const int rr = lane & 15;
  const int kc = (((lane >> 4) ^ Frow(rr)) & 3) * 8;
  const int wrow = tid >> 1, wc8 = tid & 1;
  const int wF = Frow(wrow & 15);

  f4v acc[4][4] = {};

  auto stageA = [&](int s, int k) {
    if constexpr (XSEG) {
      if (k >= A2VLD) {
        gload16(x0 + (k - A2VLD), &As[s][tid * 8]);
        gload16(x1 + (k - A2VLD), &As[s][2048 + tid * 8]);
      } else {
        gload16(a0 + k, &As[s][tid * 8]);
        gload16(a1 + k, &As[s][2048 + tid * 8]);
      }
    } else {
      gload16(a0 + k, &As[s][tid * 8]);
      gload16(a1 + k, &As[s][2048 + tid * 8]);
    }
  };
  auto writeBdup = [&](int s, s8v v) {
    *(s8v*)&Bs[s][wrow * 32 + (((2 * wc8) ^ wF) * 8)] = v;
    *(s8v*)&Bs[s][wrow * 32 + (((2 * wc8 + 1) ^ wF) * 8)] = v;
  };
  auto compute = [&](int s) {
    s8v a[4], b[4];
#pragma unroll
    for (int i = 0; i < 4; ++i) a[i] = *(const s8v*)&As[s][(wm + i * 16 + rr) * 32 + kc];
#pragma unroll
    for (int j = 0; j < 4; ++j) b[j] = *(const s8v*)&Bs[s][(wn + j * 16 + rr) * 32 + kc];
#pragma unroll
    for (int i = 0; i < 4; ++i)
#pragma unroll
      for (int j = 0; j < 4; ++j)
        acc[i][j] = __builtin_amdgcn_mfma_f32_16x16x32_bf16(a[i], b[j], acc[i][j], 0, 0, 0);
  };

  stageA(0, kbeg);
  {
    s8v v = *(const s8v*)(bsrcD + (kbeg >> 1));
    VMWAIT0();
    writeBdup(0, v);
  }
  BARRIER();

  int cur = 0;
  for (int k0 = kbeg; k0 < kend; k0 += 32) {
    const bool more = (k0 + 32 < kend);
    s8v v;
    if (more) { stageA(cur ^ 1, k0 + 32); v = *(const s8v*)(bsrcD + ((k0 + 32) >> 1)); }
    compute(cur);
    VMWAIT0();
    if (more) writeBdup(cur ^ 1, v);
    BARRIER();
    cur ^= 1;
  }

  float* out = P + (size_t)blockIdx.z * 256 * N;
  const int cr = (lane >> 4) * 4, cc = lane & 15;
#pragma unroll
  for (int i = 0; i < 4; ++i)
#pragma unroll
    for (int j = 0; j < 4; ++j)
#pragma unroll
      for (int r = 0; r < 4; ++r)
        out[(size_t)(m0 + wm + i * 16 + cr + r) * N + n0 + wn + j * 16 + cc] = acc[i][j][r];
}

// =================== 128x128 VA fallback (fp32 A converted on stage) ============
__global__ __launch_bounds__(256)
void gemm_va_f32(const float* __restrict__ A, int lda,
                 const unsigned short* __restrict__ Bt, int ldb,
                 unsigned short* __restrict__ C, int ldc,
                 const float* __restrict__ bias, int N, int Kp)
{
  __shared__ unsigned short As[128 * 32];
  __shared__ unsigned short Bs[128 * 32];
  const int tid = threadIdx.x, wid = tid >> 6, lane = tid & 63;
  const int wm = (wid >> 1) * 64, wn = (wid & 1) * 64;
  const int m0 = blockIdx.x * 128, n0 = blockIdx.y * 128;
  const unsigned short* bsrc0 = Bt + (size_t)(n0 + (tid >> 2)) * ldb + (tid & 3) * 8;
  const unsigned short* bsrc1 = bsrc0 + (size_t)64 * ldb;
  const int rr = lane & 15;
  const int kc = (((lane >> 4) ^ Frow(rr)) & 3) * 8;

  f4v acc[4][4] = {};
  for (int k0 = 0; k0 < Kp; k0 += 32) {
#pragma unroll
    for (int it = 0; it < 4; ++it) {
      const int r = it * 32 + (tid >> 3), c = (tid & 7) * 4;
      const float4 v = *(const float4*)(A + (size_t)(m0 + r) * lda + k0 + c);
      ushort4 w;
      w.x = f2b(v.x); w.y = f2b(v.y); w.z = f2b(v.z); w.w = f2b(v.w);
      *(ushort4*)&As[r * 32 + (c ^ (Frow(r & 15) << 3))] = w;
    }
    gload16(bsrc0 + k0, &Bs[tid * 8]);
    gload16(bsrc1 + k0, &Bs[2048 + tid * 8]);
    __syncthreads();
    s8v a[4], b[4];
#pragma unroll
    for (int i = 0; i < 4; ++i) a[i] = *(const s8v*)&As[(wm + i * 16 + rr) * 32 + kc];
#pragma unroll
    for (int j = 0; j < 4; ++j) b[j] = *(const s8v*)&Bs[(wn + j * 16 + rr) * 32 + kc];
#pragma unroll
    for (int i = 0; i < 4; ++i)
#pragma unroll
      for (int j = 0; j < 4; ++j)
        acc[i][j] = __builtin_amdgcn_mfma_f32_16x16x32_bf16(a[i], b[j], acc[i][j], 0, 0, 0);
    __syncthreads();
  }
  const int cr = (lane >> 4) * 4, cc = lane & 15;
#pragma unroll
  for (int i = 0; i < 4; ++i)
#pragma unroll
    for (int j = 0; j < 4; ++j) {
      const int gn = n0 + wn + j * 16 + cc;
      if (gn >= N) continue;
#pragma unroll
      for (int r = 0; r < 4; ++r)
        C[(size_t)(m0 + wm + i * 16 + cr + r) * ldc + gn] = f2b(acc[i][j][r] + bias[gn]);
    }
}

// =================== fp32 GEMM (setup-only, small) ===================
__global__ __launch_bounds__(256)
void gemm_f32(const float* __restrict__ Ap, int lda,
              const float* __restrict__ Bp, int ldb,
              float* __restrict__ Cp, int ldc,
              const float* __restrict__ bias,
              int M, int N, int K)
{
  __shared__ float As[16][64];
  __shared__ float Bs[16][64];
  const int n0 = blockIdx.x * 64, m0 = blockIdx.y * 64;
  const int tid = threadIdx.x;
  const int tx = tid & 15, ty = tid >> 4;
  float acc[4][4] = {};
  for (int k0 = 0; k0 < K; k0 += 16) {
    {
      const int e = tid << 2;
      const int m = e >> 4, k = e & 15;
      const int gm = m0 + m, gk = k0 + k;
      float4 v = make_float4(0.f, 0.f, 0.f, 0.f);
      if (gm < M) {
        const float* src = Ap + (size_t)gm * lda + gk;
        if (gk + 3 < K) v = *(const float4*)src;
        else {
          if (gk     < K) v.x = src[0];
          if (gk + 1 < K) v.y = src[1];
          if (gk + 2 < K) v.z = src[2];
          if (gk + 3 < K) v.w = src[3];
        }
      }
      As[k][m] = v.x; As[k + 1][m] = v.y; As[k + 2][m] = v.z; As[k + 3][m] = v.w;
    }
    {
      const int e = tid << 2;
      const int k = e >> 6, n = e & 63;
      const int gk = k0 + k, gn = n0 + n;
      float4 v = make_float4(0.f, 0.f, 0.f, 0.f);
      if (gk < K) {
        const float* src = Bp + (size_t)gk * ldb + gn;
        if (gn + 3 < N) v = *(const float4*)src;
        else {
          if (gn     < N) v.x = src[0];
          if (gn + 1 < N) v.y = src[1];
          if (gn + 2 < N) v.z = src[2];
          if (gn + 3 < N) v.w = src[3];
        }
      }
      Bs[k][n] = v.x; Bs[k][n + 1] = v.y; Bs[k][n + 2] = v.z; Bs[k][n + 3] = v.w;
    }
    __syncthreads();
#pragma unroll
    for (int k = 0; k < 16; ++k) {
      const float a0 = As[k][ty * 4 + 0], a1 = As[k][ty * 4 + 1];
      const float a2 = As[k][ty * 4 + 2], a3 = As[k][ty * 4 + 3];
      const float b0 = Bs[k][tx * 4 + 0], b1 = Bs[k][tx * 4 + 1];
      const float b2 = Bs[k][tx * 4 + 2], b3 = Bs[k][tx * 4 + 3];
      acc[0][0] += a0 * b0; acc[0][1] += a0 * b1; acc[0][2] += a0 * b2; acc[0][3] += a0 * b3;
      acc[1][0] += a1 * b0; acc[1][1] += a1 * b1; acc[1][2] += a1 * b2; acc[1][3] += a1 * b3;
      acc[2][0] += a2 * b0; acc[2][1] += a2 * b1; acc[2][2] += a2 * b2; acc[2][3] += a2 * b3;
      acc[3][0] += a3 * b0; acc[3][1] += a3 * b1; acc[3][2] += a3 * b2; acc[3][3] += a3 * b3;
    }
    __syncthreads();
  }
#pragma unroll
  for (int i = 0; i < 4; ++i) {
    const int gm = m0 + ty * 4 + i;
    if (gm >= M) continue;
#pragma unroll
    for (int j = 0; j < 4; ++j) {
      const int gn = n0 + tx * 4 + j;
      if (gn >= N) continue;
      Cp[(size_t)gm * ldc + gn] = acc[i][j] + bias[gn];
    }
  }
}

// =================== weight transpose+convert ===================
// mode 0: PLAIN bf16-hi at orig k, no swizzle (dedup-B buffers)
// mode 1: plain hi, swizzled (VA's B, gload path)
__global__ void convB_k(const float* __restrict__ src, int srcld, int K, int N,
                        unsigned short* __restrict__ dst, int dstld, int coff, int mode)
{
  __shared__ float t[32][33];
  const int kb = blockIdx.x * 32, nb = blockIdx.y * 32;
  const int tx = threadIdx.x & 31, ty = threadIdx.x >> 5;
#pragma unroll
  for (int i = 0; i < 32; i += 8) {
    const int k = kb + ty + i, n = nb + tx;
    t[ty + i][tx] = (k < K && n < N) ? src[(size_t)k * srcld + n] : 0.f;
  }
  __syncthreads();
#pragma unroll
  for (int i = 0; i < 32; i += 8) {
    const int n = nb + ty + i, k = kb + tx;
    if (n >= N || k >= K) continue;
    const float x = t[tx][ty + i];
    unsigned short* row = dst + (size_t)n * dstld;
    if (mode == 0) {
      row[coff + k] = f2b(x);
    } else {
      row[(coff + k) ^ (Frow(n & 15) << 3)] = f2b(x);
    }
  }
}

// zero plain columns [c0, ld)
__global__ void zpad_plain_k(unsigned short* __restrict__ dst, int ld, int c0, int N)
{
  const int w = ld - c0;
  const int idx = blockIdx.x * 256 + threadIdx.x;
  if (idx >= N * w) return;
  dst[(size_t)(idx / w) * ld + c0 + (idx % w)] = 0;
}

__global__ void zfill_k(unsigned short* __restrict__ p, int n)
{
  const int i = blockIdx.x * 256 + threadIdx.x;
  if (i < n) p[i] = 0;
}

// =================== fused feature pass: mean + bf16 convert ===================
__global__ void feat_pass_k(const float* __restrict__ feat, float* __restrict__ fm,
                            unsigned short* __restrict__ f16out)
{
  const int idx = blockIdx.x * 256 + threadIdx.x;   // NB * VD/8
  if (idx >= NB * (VD / 8)) return;
  const int d0 = (idx & (VD / 8 - 1)) * 8, b = idx / (VD / 8);
  const float* base = feat + (size_t)b * NR * VD + d0;
  float s[8] = {};
  for (int r = 0; r < NR; ++r) {
    const float4 x0 = *(const float4*)(base + (size_t)r * VD);
    const float4 x1 = *(const float4*)(base + (size_t)r * VD + 4);
    s[0] += x0.x; s[1] += x0.y; s[2] += x0.z; s[3] += x0.w;
    s[4] += x1.x; s[5] += x1.y; s[6] += x1.z; s[7] += x1.w;
    if (f16out) {
      unsigned short w[8] = {f2b(x0.x), f2b(x0.y), f2b(x0.z), f2b(x0.w),
                             f2b(x1.x), f2b(x1.y), f2b(x1.z), f2b(x1.w)};
      const int ro = b * NR + r;
      *(s8v*)(f16out + (size_t)ro * VD + (d0 ^ (Frow(ro & 15) << 3))) = *(const s8v*)w;
    }
  }
#pragma unroll
  for (int e = 0; e < 8; ++e) fm[(size_t)b * VD + d0 + e] = s[e] * (1.f / NR);
}

// pack FM (fp32 [NB][VD]) -> FM2 chunked-split bf16 [NB][KFM], swizzled by F(b)
__global__ void pack_fm_k(const float* __restrict__ fm, unsigned short* __restrict__ fm2)
{
  const int idx = blockIdx.x * 256 + threadIdx.x;   // NB*VD
  if (idx >= NB * VD) return;
  const int k = idx & (VD - 1), b = idx >> 11;
  storeCK(fm2 + (size_t)b * KFM, 0, k, fm[idx], Frow(b & 15) << 3);
}

// FMG = b_v + sum_z GP[z]   (fp32 gates precompute)
__global__ void fmg_red_k(const float* __restrict__ gp, const float* __restrict__ bv,
                          float* __restrict__ fmg)
{
  const int idx = blockIdx.x * 256 + threadIdx.x;   // NB*H4
  if (idx >= NB * H4) return;
  float s = bv[idx & (H4 - 1)];
#pragma unroll
  for (int z = 0; z < ZFM; ++z) s += gp[(size_t)z * NB * H4 + idx];
  fmg[idx] = s;
}

// X2: chunked split layout, swizzled by F(b); payload d<300
__global__ void build_x2_k(const int* __restrict__ cap, const float* __restrict__ emb,
                           const float* __restrict__ vinp, unsigned short* __restrict__ X2)
{
  const int idx = blockIdx.x * 256 + threadIdx.x;
  if (idx >= NB * NT * X2LD) return;
  const int c = idx % X2LD;
  const int bt = idx / X2LD;
  const int t = bt % NT, b = bt / NT;
  const int Fs = Frow(b & 15) << 3;
  const int chunk = c >> 4, sub = (c >> 3) & 1, w = c & 7;
  const int d = chunk * 8 + w;
  unsigned short val = 0;
  if (d < IND) {
    const float v = (t == 0) ? vinp[b * IND + d]
                             : emb[(size_t)cap[b * (NT - 1) + (t - 1)] * IND + d];
    const unsigned short h = f2b(v);
    val = sub ? f2b(v - b2f(h)) : h;
  }
  X2[(size_t)bt * X2LD + (c ^ Fs)] = val;
}

__global__ void lstm_pw_v_k(const float* __restrict__ gp, const float* __restrict__ fmg,
                            float* __restrict__ cv,
                            unsigned short* __restrict__ A2c, unsigned short* __restrict__ A2v)
{
  const int idx = blockIdx.x * 256 + threadIdx.x;
  if (idx >= NB * NH) return;
  const int n = idx & (NH - 1), b = idx >> 10;
  const size_t base = (size_t)b * H4;
  float gi = fmg[base + n], gf = fmg[base + NH + n];
  float gg = fmg[base + 2 * NH + n], go = fmg[base + 3 * NH + n];
#pragma unroll
  for (int z = 0; z < ZGV; ++z) {
    const float* g = gp + (size_t)z * NB * H4 + base;
    gi += g[n]; gf += g[NH + n]; gg += g[2 * NH + n]; go += g[3 * NH + n];
  }
  const float c2 = sigm(gf) * cv[idx] + sigm(gi) * tanhf(gg);
  const float h2 = sigm(go) * tanhf(c2);
  cv[idx] = c2;
  const int Fs = Frow(b & 15) << 3;
  storeCK(A2c + (size_t)b * KGC, 4096, n, h2, Fs);
  storeCK(A2v + (size_t)b * A2VLD, 2048, n, h2, Fs);
}

__global__ void lstm_pw_c_k(const float* __restrict__ gp, const float* __restrict__ bc,
                            float* __restrict__ cc,
                            unsigned short* __restrict__ A2v, unsigned short* __restrict__ A2c,
                            unsigned short* __restrict__ outh2, int t)
{
  const int idx = blockIdx.x * 256 + threadIdx.x;
  if (idx >= NB * NH) return;
  const int n = idx & (NH - 1), b = idx >> 10;
  const size_t base = (size_t)b * H4;
  float gi = bc[n], gf = bc[NH + n], gg = bc[2 * NH + n], go = bc[3 * NH + n];
#pragma unroll
  for (int z = 0; z < ZGC; ++z) {
    const float* g = gp + (size_t)z * NB * H4 + base;
    gi += g[n]; gf += g[NH + n]; gg += g[2 * NH + n]; go += g[3 * NH + n];
  }
  const float c2 = sigm(gf) * cc[idx] + sigm(gi) * tanhf(gg);
  const float h2 = sigm(go) * tanhf(c2);
  cc[idx] = c2;
  const int Fs = Frow(b & 15) << 3;
  storeCK(A2v + (size_t)b * A2VLD, 0, n, h2, Fs);
  storeCK(A2c + (size_t)b * KGC, 6144, n, h2, Fs);
  const int ro = b * NT + t;
  storeCK(outh2 + (size_t)ro * KCL, 0, n, h2, Frow(ro & 15) << 3);
}

// =================== fused attention: ha-reduce + logits + softmax + feat_hat ===
template<bool F16>
__global__ __launch_bounds__(512)
void att_fused_k(const unsigned short* __restrict__ va16,
                 const float* __restrict__ hap,   // [ZHA][NB][NH]
                 const float* __restrict__ bha,
                 const float* __restrict__ Wa, const float* __restrict__ ba,
                 const unsigned short* __restrict__ f16,
                 const float* __restrict__ f32,
                 unsigned short* __restrict__ A2c,
                 float* __restrict__ att_out, int t)
{
  const int b = blockIdx.x, tid = threadIdx.x;
  const int lane = tid & 63, wid = tid >> 6;
  __shared__ float ha_s[NH];
  __shared__ float wa_s[NH];
  __shared__ float red_s[128];

  for (int j = tid; j < NH; j += 512) {
    float s = bha[j];
#pragma unroll
    for (int z = 0; z < ZHA; ++z) s += hap[((size_t)z * NB + b) * NH + j];
    ha_s[j] = s;
    wa_s[j] = Wa[j];
  }
  __syncthreads();

  for (int r = wid; r < NR; r += 8) {
    const unsigned short* vrow = va16 + ((size_t)b * NR + r) * NH + lane * 16;
    float s = 0.f;
#pragma unroll
    for (int u = 0; u < 2; ++u) {
      const s8v v = *(const s8v*)(vrow + u * 8);
      const int j0 = lane * 16 + u * 8;
#pragma unroll
      for (int e = 0; e < 8; ++e)
        s += tanhf(b2f((unsigned short)v[e]) + ha_s[j0 + e]) * wa_s[j0 + e];
    }
    for (int o = 32; o; o >>= 1) s += __shfl_down(s, o);
    if (lane == 0) red_s[r] = s + ba[0];
  }
  __syncthreads();

  if (wid == 0) {
    float v0 = (lane < NR) ? red_s[lane] : -3.4e38f;
    float v1 = (lane + 64 < NR) ? red_s[lane + 64] : -3.4e38f;
    float m = fmaxf(v0, v1);
    for (int o = 32; o; o >>= 1) m = fmaxf(m, __shfl_xor(m, o));
    const float e0 = (lane < NR) ? expf(v0 - m) : 0.f;
    const float e1 = (lane + 64 < NR) ? expf(v1 - m) : 0.f;
    float s = e0 + e1;
    for (int o = 32; o; o >>= 1) s += __shfl_xor(s, o);
    const float inv = 1.f / s;
    if (lane < NR) red_s[lane] = e0 * inv;
    if (lane + 64 < NR) red_s[lane + 64] = e1 * inv;
  }
  __syncthreads();
  if (tid < NR) att_out[((size_t)b * NT + t) * NR + tid] = red_s[tid];

  // feat_hat: 2048 d over 512 threads = 4 each
  const int d0 = tid * 4;
  float fh[4] = {};
  if constexpr (F16) {
    const unsigned short* fbase = f16 + (size_t)b * NR * VD;
    for (int r = 0; r < NR; ++r) {
      const int ro = b * NR + r;
      const ushort4 f = *(const ushort4*)(fbase + (size_t)r * VD + (d0 ^ (Frow(ro & 15) << 3)));
      const float a = red_s[r];
      fh[0] += a * b2f(f.x); fh[1] += a * b2f(f.y);
      fh[2] += a * b2f(f.z); fh[3] += a * b2f(f.w);
    }
  } else {
    const float* fb = f32 + (size_t)b * NR * VD + d0;
    for (int r = 0; r < NR; ++r) {
      const float4 x0 = *(const float4*)(fb + (size_t)r * VD);
      const float a = red_s[r];
      fh[0] += a * x0.x; fh[1] += a * x0.y; fh[2] += a * x0.z; fh[3] += a * x0.w;
    }
  }
  unsigned short* rowbase = A2c + (size_t)b * KGC;
  const int Fs = Frow(b & 15) << 3;
#pragma unroll
  for (int e = 0; e < 4; ++e) storeCK(rowbase, 0, d0 + e, fh[e] * (1.f / NR), Fs);
}

inline void gemmF(hipStream_t st, const float* A, int lda, const float* B, int ldb,
                  float* C, int ldc, const float* bias, int M, int N, int K)
{
  dim3 g((N + 63) / 64, (M + 63) / 64);
  gemm_f32<<<g, 256, 0, st>>>(A, lda, B, ldb, C, ldc, bias, M, N, K);
}

inline void convB(hipStream_t st, const float* src, int srcld, int K, int N,
                  unsigned short* dst, int dstld, int coff, int mode)
{
  dim3 g((K + 31) / 32, (N + 31) / 32);
  convB_k<<<g, 256, 0, st>>>(src, srcld, K, N, dst, dstld, coff, mode);
}

} // namespace

extern "C" void kernel_launch(void* const* d_in, const int* in_sizes, int n_in,
                              void* d_out, int out_size, void* d_ws, size_t ws_size,
                              hipStream_t stream)
{
  const int*   caption = (const int*)  d_in[0];
  const float* feat    = (const float*)d_in[1];
  const float* emb     = (const float*)d_in[2];
  const float* W_vin   = (const float*)d_in[3];
  const float* b_vin   = (const float*)d_in[4];
  const float* W_ih_v  = (const float*)d_in[5];
  const float* W_hh_v  = (const float*)d_in[6];
  const float* b_v     = (const float*)d_in[7];
  const float* W_va    = (const float*)d_in[8];
  const float* b_va    = (const float*)d_in[9];
  const float* W_ha    = (const float*)d_in[10];
  const float* b_ha    = (const float*)d_in[11];
  const float* W_a     = (const float*)d_in[12];
  const float* b_a     = (const float*)d_in[13];
  const float* W_ih_c  = (const float*)d_in[14];
  const float* W_hh_c  = (const float*)d_in[15];
  const float* b_c     = (const float*)d_in[16];
  const float* W_cls   = (const float*)d_in[17];
  const float* b_cls   = (const float*)d_in[18];

  float* out_repr = (float*)d_out;                       // [NB,NT,VOC]
  float* out_att  = out_repr + (size_t)NB * NT * VOC;    // [NB,NT,NR]

  char* cur = (char*)d_ws;
  auto take = [&](size_t bytes) { char* p = cur; cur += bytes; return p; };

  unsigned short* A2v  = (unsigned short*)take((size_t)NB * A2VLD * 2);
  unsigned short* A2c  = (unsigned short*)take((size_t)NB * KGC * 2);
  float* CV            = (float*)take((size_t)NB * NH * 4);
  float* CC            = (float*)take((size_t)NB * NH * 4);
  const size_t ZERO_BYTES = (size_t)NB * A2VLD * 2 + (size_t)NB * KGC * 2
                          + 2 * (size_t)NB * NH * 4;

  float* FM            = (float*)take((size_t)NB * VD * 4);
  float* VINP          = (float*)take((size_t)NB * IND * 4);
  unsigned short* X2   = (unsigned short*)take((size_t)NB * NT * X2LD * 2);  // 6.2MB
  float* FMG           = (float*)take((size_t)NB * H4 * 4);
  unsigned short* FM2  = (unsigned short*)take((size_t)NB * KFM * 2);        // 2MB
  unsigned short* VA16 = (unsigned short*)take((size_t)NB * NR * NH * 2);    // 52MB
  float* GP            = (float*)take((size_t)ZGC * NB * H4 * 4);            // 33.5MB
  float* HAP           = (float*)take((size_t)ZHA * NB * NH * 4);            // 8.4MB
  unsigned short* OUTH2= (unsigned short*)take((size_t)NB * NT * KCL * 2);   // 21MB
  unsigned short* Wgv2t= (unsigned short*)take((size_t)H4 * KGVO * 2);       // 19.3MB
  unsigned short* Wha2t= (unsigned short*)take((size_t)NH * KHAO * 2);       // 2.1MB
  unsigned short* Wgc2t= (unsigned short*)take((size_t)H4 * KGCO * 2);       // 33.5MB
  unsigned short* Wfmg = (unsigned short*)take((size_t)H4 * KFMO * 2);       // 16.8MB
  unsigned short* Wcls2t=(unsigned short*)take((size_t)VOCP * KCLO * 2);     // 20.7MB
  unsigned short* Wva16t=(unsigned short*)take((size_t)NH * VD * 2);         // 4.2MB
  unsigned short* FEAT16=(unsigned short*)cur;                               // 105MB optional
  const bool useF16 = ((size_t)(cur - (char*)d_ws) + (size_t)NB * NR * VD * 2) <= ws_size;

  hipMemsetAsync(A2v, 0, ZERO_BYTES, stream);

  // ---- weight conversions (plain bf16-hi, dedup; VA swizzled) ----
  convB(stream, W_ih_v + (size_t)2048 * H4, H4, 1024, H4, Wgv2t, KGVO, 0,    0);
  convB(stream, W_hh_v,                     H4, 1024, H4, Wgv2t, KGVO, 1024, 0);
  convB(stream, W_ih_v + (size_t)3072 * H4, H4, 300,  H4, Wgv2t, KGVO, 2048, 0);
  zpad_plain_k<<<((H4 * (KGVO - 2348)) + 255) / 256, 256, 0, stream>>>(
      Wgv2t, KGVO, 2348, H4);
  convB(stream, W_ha, NH, 1024, NH, Wha2t, KHAO, 0, 0);
  convB(stream, W_ih_c,                     H4, 2048, H4, Wgc2t, KGCO, 0,    0);
  convB(stream, W_ih_c + (size_t)2048 * H4, H4, 1024, H4, Wgc2t, KGCO, 2048, 0);
  convB(stream, W_hh_c,                     H4, 1024, H4, Wgc2t, KGCO, 3072, 0);
  convB(stream, W_ih_v,                     H4, 2048, H4, Wfmg,  KFMO, 0,    0);
  convB(stream, W_cls, VOC, 1024, VOC, Wcls2t, KCLO, 0, 0);
  zfill_k<<<(((VOCP - VOC) * KCLO) + 255) / 256, 256, 0, stream>>>(
      Wcls2t + (size_t)VOC * KCLO, (VOCP - VOC) * KCLO);
  convB(stream, W_va, NH, VD, NH, Wva16t, VD, 0, 1);

  // ---- setup ----
  feat_pass_k<<<(NB * (VD / 8) + 255) / 256, 256, 0, stream>>>(
      feat, FM, useF16 ? FEAT16 : nullptr);
  gemmF(stream, FM, VD, W_vin, IND, VINP, IND, b_vin, NB, IND, VD);
  build_x2_k<<<(NB * NT * X2LD + 255) / 256, 256, 0, stream>>>(caption, emb, VINP, X2);
  // FMG via MFMA split-K (was 120us fp32 VALU GEMM)
  pack_fm_k<<<(NB * VD + 255) / 256, 256, 0, stream>>>(FM, FM2);
  gemm_sk2<false><<<dim3(H4 / 128, 2, ZFM), 256, 0, stream>>>(
      FM2, KFM, nullptr, 0, Wfmg, KFMO, GP, H4, KFM, KSF);
  fmg_red_k<<<(NB * H4 + 255) / 256, 256, 0, stream>>>(GP, b_v, FMG);
  if (useF16) {
    dim3 g((NB * NR) / 128, NH / 128);
    gemm128<true, false><<<g, 256, 0, stream>>>(
        FEAT16, VD, Wva16t, VD, VA16, NH, b_va, NH, VD);
  } else {
    dim3 g((NB * NR) / 128, NH / 128);
    gemm_va_f32<<<g, 256, 0, stream>>>(feat, VD, Wva16t, VD, VA16, NH, b_va, NH, VD);
  }

  // ---- sequential decode ----
  for (int t = 0; t < NT; ++t) {
    gemm_sk2<true><<<dim3(H4 / 128, 2, ZGV), 256, 0, stream>>>(
        A2v, A2VLD, X2, t, Wgv2t, KGVO, GP, H4, KGV, KSV);
    lstm_pw_v_k<<<(NB * NH + 255) / 256, 256, 0, stream>>>(GP, FMG, CV, A2c, A2v);
    gemm_sk2<false><<<dim3(NH / 128, 2, ZHA), 256, 0, stream>>>(
        A2c + 4096, KGC, nullptr, 0, Wha2t, KHAO, HAP, NH, KHA, KSH);
    if (useF16)
      att_fused_k<true><<<NB, 512, 0, stream>>>(
          VA16, HAP, b_ha, W_a, b_a, FEAT16, nullptr, A2c, out_att, t);
    else
      att_fused_k<false><<<NB, 512, 0, stream>>>(
          VA16, HAP, b_ha, W_a, b_a, nullptr, feat, A2c, out_att, t);
    gemm_sk2<false><<<dim3(H4 / 128, 2, ZGC), 256, 0, stream>>>(
        A2c, KGC, nullptr, 0, Wgc2t, KGCO, GP, H4, KGC, KSC);
    lstm_pw_c_k<<<(NB * NH + 255) / 256, 256, 0, stream>>>(GP, b_c, CC, A2v, A2c, OUTH2, t);
  }

  // ---- classifier: 128x128 tiles, dedup-B, K'=2048 ----
  {
    dim3 g((NB * NT) / 128, VOCP / 128);
    gemm128<false, true><<<g, 256, 0, stream>>>(
        OUTH2, KCL, Wcls2t, KCLO, out_repr, VOC, b_cls, VOC, KCL);
  }
}

// Round 14
// 3347.083 us; speedup vs baseline: 1.6008x; 1.0440x over previous
//
#include <hip/hip_runtime.h>
#include <math.h>

namespace {

constexpr int NB  = 256;
constexpr int NT  = 20;
constexpr int NR  = 100;
constexpr int IND = 300;
constexpr int NH  = 1024;
constexpr int VD  = 2048;
constexpr int H4  = 4096;
constexpr int VOC = 10000;
constexpr int VOCP = 10112;   // vocab padded to 128

// Chunk-interleaved split-bf16 K' layout (A side), dedup B:
//   orig k -> A hi at seg + ((k>>3)<<4) + (k&7), A lo at +8
//   B stored PLAIN [N][K_orig] bf16; duplicated at ds_write into paired slots.
constexpr int KGV = 4704;  constexpr int KGVO = 2352;
constexpr int KGC = 8192;  constexpr int KGCO = 4096;
constexpr int KHA = 2048;  constexpr int KHAO = 1024;
constexpr int KCL = 2048;  constexpr int KCLO = 1024;
constexpr int KFM = 4096;  constexpr int KFMO = 2048;   // FMG/VINP share FM2 (K'=4096)
constexpr int NVI = 384;    // VINP N padded to 3*128
constexpr int A2VLD = 4096;
constexpr int X2LD  = 608;

constexpr int ZGV = 8;  constexpr int KSV = 608;
constexpr int ZGC = 8;  constexpr int KSC = 1024;
constexpr int ZHA = 16; constexpr int KSH = 128;
constexpr int ZFM = 8;  constexpr int KSF = 512;

typedef short  s8v  __attribute__((ext_vector_type(8)));
typedef float  f4v  __attribute__((ext_vector_type(4)));

__device__ __forceinline__ float sigm(float x) { return 1.f / (1.f + expf(-x)); }
__device__ __forceinline__ unsigned short f2b(float x) {
  return __builtin_bit_cast(unsigned short, (__bf16)x);
}
__device__ __forceinline__ float b2f(unsigned short u) {
  return (float)__builtin_bit_cast(__bf16, u);
}
__device__ __forceinline__ int Frow(int row) { return (row ^ (row >> 2)) & 3; }
__device__ __forceinline__ void storeCK(unsigned short* rowbase, int segkp, int korig,
                                        float x, int Fs) {
  const unsigned short h = f2b(x);
  const unsigned short l = f2b(x - b2f(h));
  const int ph = segkp + ((korig >> 3) << 4) + (korig & 7);
  rowbase[ph ^ Fs] = h;
  rowbase[(ph + 8) ^ Fs] = l;
}

__device__ __forceinline__ void gload16(const unsigned short* g, unsigned short* l) {
  __builtin_amdgcn_global_load_lds(
      (const __attribute__((address_space(1))) void*)g,
      (__attribute__((address_space(3))) void*)l, 16, 0, 0);
}

#define BARRIER()  __syncthreads()
#define VMWAIT0()  asm volatile("s_waitcnt vmcnt(0)" ::: "memory")

// =================== 128x128 bf16 MFMA GEMM, 2-phase dbuf =======================
// DUPB: A chunk-interleaved (gload), B plain [N][Kp/2] reg-staged + dup ds_write.
// !DUPB: plain bf16 A and B, both gload from swizzled storage (VA path).
template<bool OUT_BF16, bool DUPB>
__global__ __launch_bounds__(256)
void gemm128(const unsigned short* __restrict__ A, int lda,
             const unsigned short* __restrict__ Bt, int ldb,   // ldb = orig-K if DUPB
             void* __restrict__ Cv, int ldc,
             const float* __restrict__ bias,
             int N, int Kp)
{
  __shared__ unsigned short As[2][128 * 32];
  __shared__ unsigned short Bs[2][128 * 32];
  const int tid = threadIdx.x, wid = tid >> 6, lane = tid & 63;
  const int wm = (wid >> 1) * 64, wn = (wid & 1) * 64;
  const int m0 = blockIdx.x * 128, n0 = blockIdx.y * 128;
  const int sr = tid >> 2, sc = (tid & 3) * 8;
  const unsigned short* a0 = A + (size_t)(m0 + sr) * lda + sc;
  const unsigned short* a1 = a0 + (size_t)64 * lda;
  const unsigned short* bsrcD = Bt + (size_t)(n0 + (tid >> 1)) * ldb + (tid & 1) * 8;
  const unsigned short* b0 = Bt + (size_t)(n0 + sr) * ldb + sc;
  const unsigned short* b1 = b0 + (size_t)64 * ldb;
  const int rr = lane & 15;
  const int kc = (((lane >> 4) ^ Frow(rr)) & 3) * 8;
  const int wrow = tid >> 1, wc8 = tid & 1;
  const int wF = Frow(wrow & 15);

  f4v acc[4][4] = {};

  auto stageA = [&](int s, int k) {
    gload16(a0 + k, &As[s][tid * 8]);
    gload16(a1 + k, &As[s][2048 + tid * 8]);
  };
  auto stageBplain = [&](int s, int k) {
    gload16(b0 + k, &Bs[s][tid * 8]);
    gload16(b1 + k, &Bs[s][2048 + tid * 8]);
  };
  auto writeBdup = [&](int s, s8v v) {
    *(s8v*)&Bs[s][wrow * 32 + (((2 * wc8) ^ wF) * 8)] = v;
    *(s8v*)&Bs[s][wrow * 32 + (((2 * wc8 + 1) ^ wF) * 8)] = v;
  };
  auto compute = [&](int s) {
    s8v a[4], b[4];
#pragma unroll
    for (int i = 0; i < 4; ++i) a[i] = *(const s8v*)&As[s][(wm + i * 16 + rr) * 32 + kc];
#pragma unroll
    for (int j = 0; j < 4; ++j) b[j] = *(const s8v*)&Bs[s][(wn + j * 16 + rr) * 32 + kc];
#pragma unroll
    for (int i = 0; i < 4; ++i)
#pragma unroll
      for (int j = 0; j < 4; ++j)
        acc[i][j] = __builtin_amdgcn_mfma_f32_16x16x32_bf16(a[i], b[j], acc[i][j], 0, 0, 0);
  };

  // prologue
  stageA(0, 0);
  if constexpr (DUPB) {
    s8v v = *(const s8v*)(bsrcD);
    VMWAIT0();
    writeBdup(0, v);
  } else {
    stageBplain(0, 0);
    VMWAIT0();
  }
  BARRIER();

  int cur = 0;
  for (int k0 = 0; k0 < Kp; k0 += 32) {
    const bool more = (k0 + 32 < Kp);
    if constexpr (DUPB) {
      s8v v;
      if (more) { stageA(cur ^ 1, k0 + 32); v = *(const s8v*)(bsrcD + ((k0 + 32) >> 1)); }
      compute(cur);
      VMWAIT0();
      if (more) writeBdup(cur ^ 1, v);
    } else {
      if (more) { stageA(cur ^ 1, k0 + 32); stageBplain(cur ^ 1, k0 + 32); }
      compute(cur);
      VMWAIT0();
    }
    BARRIER();
    cur ^= 1;
  }

  const int cr = (lane >> 4) * 4, cc = lane & 15;
#pragma unroll
  for (int i = 0; i < 4; ++i) {
#pragma unroll
    for (int j = 0; j < 4; ++j) {
      const int gn = n0 + wn + j * 16 + cc;
      if (gn >= N) continue;
#pragma unroll
      for (int r = 0; r < 4; ++r) {
        const int gm = m0 + wm + i * 16 + cr + r;
        float v = acc[i][j][r] + bias[gn];
        if constexpr (OUT_BF16) ((unsigned short*)Cv)[(size_t)gm * ldc + gn] = f2b(v);
        else                    ((float*)Cv)[(size_t)gm * ldc + gn] = v;
      }
    }
  }
}

// =================== split-K GEMM, BM=128 (grid.y), BN=128, dedup-B =============
template<bool XSEG>
__global__ __launch_bounds__(256)
void gemm_sk2(const unsigned short* __restrict__ A, int lda,
              const unsigned short* __restrict__ X2, int t,
              const unsigned short* __restrict__ Bt, int ldb,   // orig-K stride
              float* __restrict__ P, int N, int Kp, int Ksplit)
{
  __shared__ unsigned short As[2][128 * 32];
  __shared__ unsigned short Bs[2][128 * 32];
  const int tid = threadIdx.x, wid = tid >> 6, lane = tid & 63;
  const int wm = (wid >> 1) * 64, wn = (wid & 1) * 64;
  const int m0 = blockIdx.y * 128, n0 = blockIdx.x * 128;
  const int kbeg = blockIdx.z * Ksplit;
  const int kend = min(Kp, kbeg + Ksplit);
  const int sr = tid >> 2, sc = (tid & 3) * 8;
  const unsigned short* a0 = A + (size_t)(m0 + sr) * lda + sc;
  const unsigned short* a1 = a0 + (size_t)64 * lda;
  const unsigned short* x0 = nullptr;
  const unsigned short* x1 = nullptr;
  if constexpr (XSEG) {
    x0 = X2 + ((size_t)(m0 + sr) * NT + t) * X2LD + sc;
    x1 = x0 + (size_t)64 * NT * X2LD;
  }
  const unsigned short* bsrcD = Bt + (size_t)(n0 + (tid >> 1)) * ldb + (tid & 1) * 8;
  const int rr = lane & 15;
  const int kc = (((lane >> 4) ^ Frow(rr)) & 3) * 8;
  const int wrow = tid >> 1, wc8 = tid & 1;
  const int wF = Frow(wrow & 15);

  f4v acc[4][4] = {};

  auto stageA = [&](int s, int k) {
    if constexpr (XSEG) {
      if (k >= A2VLD) {
        gload16(x0 + (k - A2VLD), &As[s][tid * 8]);
        gload16(x1 + (k - A2VLD), &As[s][2048 + tid * 8]);
      } else {
        gload16(a0 + k, &As[s][tid * 8]);
        gload16(a1 + k, &As[s][2048 + tid * 8]);
      }
    } else {
      gload16(a0 + k, &As[s][tid * 8]);
      gload16(a1 + k, &As[s][2048 + tid * 8]);
    }
  };
  auto writeBdup = [&](int s, s8v v) {
    *(s8v*)&Bs[s][wrow * 32 + (((2 * wc8) ^ wF) * 8)] = v;
    *(s8v*)&Bs[s][wrow * 32 + (((2 * wc8 + 1) ^ wF) * 8)] = v;
  };
  auto compute = [&](int s) {
    s8v a[4], b[4];
#pragma unroll
    for (int i = 0; i < 4; ++i) a[i] = *(const s8v*)&As[s][(wm + i * 16 + rr) * 32 + kc];
#pragma unroll
    for (int j = 0; j < 4; ++j) b[j] = *(const s8v*)&Bs[s][(wn + j * 16 + rr) * 32 + kc];
#pragma unroll
    for (int i = 0; i < 4; ++i)
#pragma unroll
      for (int j = 0; j < 4; ++j)
        acc[i][j] = __builtin_amdgcn_mfma_f32_16x16x32_bf16(a[i], b[j], acc[i][j], 0, 0, 0);
  };

  stageA(0, kbeg);
  {
    s8v v = *(const s8v*)(bsrcD + (kbeg >> 1));
    VMWAIT0();
    writeBdup(0, v);
  }
  BARRIER();

  int cur = 0;
  for (int k0 = kbeg; k0 < kend; k0 += 32) {
    const bool more = (k0 + 32 < kend);
    s8v v;
    if (more) { stageA(cur ^ 1, k0 + 32); v = *(const s8v*)(bsrcD + ((k0 + 32) >> 1)); }
    compute(cur);
    VMWAIT0();
    if (more) writeBdup(cur ^ 1, v);
    BARRIER();
    cur ^= 1;
  }

  float* out = P + (size_t)blockIdx.z * 256 * N;
  const int cr = (lane >> 4) * 4, cc = lane & 15;
#pragma unroll
  for (int i = 0; i < 4; ++i)
#pragma unroll
    for (int j = 0; j < 4; ++j)
#pragma unroll
      for (int r = 0; r < 4; ++r)
        out[(size_t)(m0 + wm + i * 16 + cr + r) * N + n0 + wn + j * 16 + cc] = acc[i][j][r];
}

// =================== 128x128 VA fallback (fp32 A converted on stage) ============
__global__ __launch_bounds__(256)
void gemm_va_f32(const float* __restrict__ A, int lda,
                 const unsigned short* __restrict__ Bt, int ldb,
                 unsigned short* __restrict__ C, int ldc,
                 const float* __restrict__ bias, int N, int Kp)
{
  __shared__ unsigned short As[128 * 32];
  __shared__ unsigned short Bs[128 * 32];
  const int tid = threadIdx.x, wid = tid >> 6, lane = tid & 63;
  const int wm = (wid >> 1) * 64, wn = (wid & 1) * 64;
  const int m0 = blockIdx.x * 128, n0 = blockIdx.y * 128;
  const unsigned short* bsrc0 = Bt + (size_t)(n0 + (tid >> 2)) * ldb + (tid & 3) * 8;
  const unsigned short* bsrc1 = bsrc0 + (size_t)64 * ldb;
  const int rr = lane & 15;
  const int kc = (((lane >> 4) ^ Frow(rr)) & 3) * 8;

  f4v acc[4][4] = {};
  for (int k0 = 0; k0 < Kp; k0 += 32) {
#pragma unroll
    for (int it = 0; it < 4; ++it) {
      const int r = it * 32 + (tid >> 3), c = (tid & 7) * 4;
      const float4 v = *(const float4*)(A + (size_t)(m0 + r) * lda + k0 + c);
      ushort4 w;
      w.x = f2b(v.x); w.y = f2b(v.y); w.z = f2b(v.z); w.w = f2b(v.w);
      *(ushort4*)&As[r * 32 + (c ^ (Frow(r & 15) << 3))] = w;
    }
    gload16(bsrc0 + k0, &Bs[tid * 8]);
    gload16(bsrc1 + k0, &Bs[2048 + tid * 8]);
    __syncthreads();
    s8v a[4], b[4];
#pragma unroll
    for (int i = 0; i < 4; ++i) a[i] = *(const s8v*)&As[(wm + i * 16 + rr) * 32 + kc];
#pragma unroll
    for (int j = 0; j < 4; ++j) b[j] = *(const s8v*)&Bs[(wn + j * 16 + rr) * 32 + kc];
#pragma unroll
    for (int i = 0; i < 4; ++i)
#pragma unroll
      for (int j = 0; j < 4; ++j)
        acc[i][j] = __builtin_amdgcn_mfma_f32_16x16x32_bf16(a[i], b[j], acc[i][j], 0, 0, 0);
    __syncthreads();
  }
  const int cr = (lane >> 4) * 4, cc = lane & 15;
#pragma unroll
  for (int i = 0; i < 4; ++i)
#pragma unroll
    for (int j = 0; j < 4; ++j) {
      const int gn = n0 + wn + j * 16 + cc;
      if (gn >= N) continue;
#pragma unroll
      for (int r = 0; r < 4; ++r)
        C[(size_t)(m0 + wm + i * 16 + cr + r) * ldc + gn] = f2b(acc[i][j][r] + bias[gn]);
    }
}

// =================== weight transpose+convert ===================
// mode 0: PLAIN bf16-hi at orig k, no swizzle (dedup-B buffers)
// mode 1: plain hi, swizzled (VA's B, gload path)
__global__ void convB_k(const float* __restrict__ src, int srcld, int K, int N,
                        unsigned short* __restrict__ dst, int dstld, int coff, int mode)
{
  __shared__ float t[32][33];
  const int kb = blockIdx.x * 32, nb = blockIdx.y * 32;
  const int tx = threadIdx.x & 31, ty = threadIdx.x >> 5;
#pragma unroll
  for (int i = 0; i < 32; i += 8) {
    const int k = kb + ty + i, n = nb + tx;
    t[ty + i][tx] = (k < K && n < N) ? src[(size_t)k * srcld + n] : 0.f;
  }
  __syncthreads();
#pragma unroll
  for (int i = 0; i < 32; i += 8) {
    const int n = nb + ty + i, k = kb + tx;
    if (n >= N || k >= K) continue;
    const float x = t[tx][ty + i];
    unsigned short* row = dst + (size_t)n * dstld;
    if (mode == 0) {
      row[coff + k] = f2b(x);
    } else {
      row[(coff + k) ^ (Frow(n & 15) << 3)] = f2b(x);
    }
  }
}

// zero plain columns [c0, ld)
__global__ void zpad_plain_k(unsigned short* __restrict__ dst, int ld, int c0, int N)
{
  const int w = ld - c0;
  const int idx = blockIdx.x * 256 + threadIdx.x;
  if (idx >= N * w) return;
  dst[(size_t)(idx / w) * ld + c0 + (idx % w)] = 0;
}

__global__ void zfill_k(unsigned short* __restrict__ p, int n)
{
  const int i = blockIdx.x * 256 + threadIdx.x;
  if (i < n) p[i] = 0;
}

// =================== fused feature pass: mean + bf16 convert ===================
__global__ void feat_pass_k(const float* __restrict__ feat, float* __restrict__ fm,
                            unsigned short* __restrict__ f16out)
{
  const int idx = blockIdx.x * 256 + threadIdx.x;   // NB * VD/8
  if (idx >= NB * (VD / 8)) return;
  const int d0 = (idx & (VD / 8 - 1)) * 8, b = idx / (VD / 8);
  const float* base = feat + (size_t)b * NR * VD + d0;
  float s[8] = {};
  for (int r = 0; r < NR; ++r) {
    const float4 x0 = *(const float4*)(base + (size_t)r * VD);
    const float4 x1 = *(const float4*)(base + (size_t)r * VD + 4);
    s[0] += x0.x; s[1] += x0.y; s[2] += x0.z; s[3] += x0.w;
    s[4] += x1.x; s[5] += x1.y; s[6] += x1.z; s[7] += x1.w;
    if (f16out) {
      unsigned short w[8] = {f2b(x0.x), f2b(x0.y), f2b(x0.z), f2b(x0.w),
                             f2b(x1.x), f2b(x1.y), f2b(x1.z), f2b(x1.w)};
      const int ro = b * NR + r;
      *(s8v*)(f16out + (size_t)ro * VD + (d0 ^ (Frow(ro & 15) << 3))) = *(const s8v*)w;
    }
  }
#pragma unroll
  for (int e = 0; e < 8; ++e) fm[(size_t)b * VD + d0 + e] = s[e] * (1.f / NR);
}

// pack FM (fp32 [NB][VD]) -> FM2 chunked-split bf16 [NB][KFM], swizzled by F(b)
__global__ void pack_fm_k(const float* __restrict__ fm, unsigned short* __restrict__ fm2)
{
  const int idx = blockIdx.x * 256 + threadIdx.x;   // NB*VD
  if (idx >= NB * VD) return;
  const int k = idx & (VD - 1), b = idx >> 11;
  storeCK(fm2 + (size_t)b * KFM, 0, k, fm[idx], Frow(b & 15) << 3);
}

// FMG = b_v + sum_z GP[z]
__global__ void fmg_red_k(const float* __restrict__ gp, const float* __restrict__ bv,
                          float* __restrict__ fmg)
{
  const int idx = blockIdx.x * 256 + threadIdx.x;   // NB*H4
  if (idx >= NB * H4) return;
  float s = bv[idx & (H4 - 1)];
#pragma unroll
  for (int z = 0; z < ZFM; ++z) s += gp[(size_t)z * NB * H4 + idx];
  fmg[idx] = s;
}

// VINP = b_vin + sum_z GP[z] (N=NVI partials, keep n<IND)
__global__ void vinp_red_k(const float* __restrict__ gp, const float* __restrict__ bvin,
                           float* __restrict__ vinp)
{
  const int idx = blockIdx.x * 256 + threadIdx.x;   // NB*IND
  if (idx >= NB * IND) return;
  const int n = idx % IND, b = idx / IND;
  float s = bvin[n];
#pragma unroll
  for (int z = 0; z < ZFM; ++z) s += gp[(size_t)z * NB * NVI + (size_t)b * NVI + n];
  vinp[idx] = s;
}

// X2: chunked split layout, swizzled by F(b); payload d<300
__global__ void build_x2_k(const int* __restrict__ cap, const float* __restrict__ emb,
                           const float* __restrict__ vinp, unsigned short* __restrict__ X2)
{
  const int idx = blockIdx.x * 256 + threadIdx.x;
  if (idx >= NB * NT * X2LD) return;
  const int c = idx % X2LD;
  const int bt = idx / X2LD;
  const int t = bt % NT, b = bt / NT;
  const int Fs = Frow(b & 15) << 3;
  const int chunk = c >> 4, sub = (c >> 3) & 1, w = c & 7;
  const int d = chunk * 8 + w;
  unsigned short val = 0;
  if (d < IND) {
    const float v = (t == 0) ? vinp[b * IND + d]
                             : emb[(size_t)cap[b * (NT - 1) + (t - 1)] * IND + d];
    const unsigned short h = f2b(v);
    val = sub ? f2b(v - b2f(h)) : h;
  }
  X2[(size_t)bt * X2LD + (c ^ Fs)] = val;
}

__global__ void lstm_pw_v_k(const float* __restrict__ gp, const float* __restrict__ fmg,
                            float* __restrict__ cv,
                            unsigned short* __restrict__ A2c, unsigned short* __restrict__ A2v)
{
  const int idx = blockIdx.x * 256 + threadIdx.x;
  if (idx >= NB * NH) return;
  const int n = idx & (NH - 1), b = idx >> 10;
  const size_t base = (size_t)b * H4;
  float gi = fmg[base + n], gf = fmg[base + NH + n];
  float gg = fmg[base + 2 * NH + n], go = fmg[base + 3 * NH + n];
#pragma unroll
  for (int z = 0; z < ZGV; ++z) {
    const float* g = gp + (size_t)z * NB * H4 + base;
    gi += g[n]; gf += g[NH + n]; gg += g[2 * NH + n]; go += g[3 * NH + n];
  }
  const float c2 = sigm(gf) * cv[idx] + sigm(gi) * tanhf(gg);
  const float h2 = sigm(go) * tanhf(c2);
  cv[idx] = c2;
  const int Fs = Frow(b & 15) << 3;
  storeCK(A2c + (size_t)b * KGC, 4096, n, h2, Fs);
  storeCK(A2v + (size_t)b * A2VLD, 2048, n, h2, Fs);
}

__global__ void lstm_pw_c_k(const float* __restrict__ gp, const float* __restrict__ bc,
                            float* __restrict__ cc,
                            unsigned short* __restrict__ A2v, unsigned short* __restrict__ A2c,
                            unsigned short* __restrict__ outh2, int t)
{
  const int idx = blockIdx.x * 256 + threadIdx.x;
  if (idx >= NB * NH) return;
  const int n = idx & (NH - 1), b = idx >> 10;
  const size_t base = (size_t)b * H4;
  float gi = bc[n], gf = bc[NH + n], gg = bc[2 * NH + n], go = bc[3 * NH + n];
#pragma unroll
  for (int z = 0; z < ZGC; ++z) {
    const float* g = gp + (size_t)z * NB * H4 + base;
    gi += g[n]; gf += g[NH + n]; gg += g[2 * NH + n]; go += g[3 * NH + n];
  }
  const float c2 = sigm(gf) * cc[idx] + sigm(gi) * tanhf(gg);
  const float h2 = sigm(go) * tanhf(c2);
  cc[idx] = c2;
  const int Fs = Frow(b & 15) << 3;
  storeCK(A2v + (size_t)b * A2VLD, 0, n, h2, Fs);
  storeCK(A2c + (size_t)b * KGC, 6144, n, h2, Fs);
  const int ro = b * NT + t;
  storeCK(outh2 + (size_t)ro * KCL, 0, n, h2, Frow(ro & 15) << 3);
}

// =================== fused attention: ha-reduce + logits + softmax + feat_hat ===
template<bool F16>
__global__ __launch_bounds__(512)
void att_fused_k(const unsigned short* __restrict__ va16,
                 const float* __restrict__ hap,   // [ZHA][NB][NH]
                 const float* __restrict__ bha,
                 const float* __restrict__ Wa, const float* __restrict__ ba,
                 const unsigned short* __restrict__ f16,
                 const float* __restrict__ f32,
                 unsigned short* __restrict__ A2c,
                 float* __restrict__ att_out, int t)
{
  const int b = blockIdx.x, tid = threadIdx.x;
  const int lane = tid & 63, wid = tid >> 6;
  __shared__ float ha_s[NH];
  __shared__ float wa_s[NH];
  __shared__ float red_s[128];
  __shared__ float fh_s[2][VD];

  for (int j = tid; j < NH; j += 512) {
    float s = bha[j];
#pragma unroll
    for (int z = 0; z < ZHA; ++z) s += hap[((size_t)z * NB + b) * NH + j];
    ha_s[j] = s;
    wa_s[j] = Wa[j];
  }
  __syncthreads();

  for (int r = wid; r < NR; r += 8) {
    const unsigned short* vrow = va16 + ((size_t)b * NR + r) * NH + lane * 16;
    float s = 0.f;
#pragma unroll
    for (int u = 0; u < 2; ++u) {
      const s8v v = *(const s8v*)(vrow + u * 8);
      const int j0 = lane * 16 + u * 8;
#pragma unroll
      for (int e = 0; e < 8; ++e)
        s += tanhf(b2f((unsigned short)v[e]) + ha_s[j0 + e]) * wa_s[j0 + e];
    }
    for (int o = 32; o; o >>= 1) s += __shfl_down(s, o);
    if (lane == 0) red_s[r] = s + ba[0];
  }
  __syncthreads();

  if (wid == 0) {
    float v0 = (lane < NR) ? red_s[lane] : -3.4e38f;
    float v1 = (lane + 64 < NR) ? red_s[lane + 64] : -3.4e38f;
    float m = fmaxf(v0, v1);
    for (int o = 32; o; o >>= 1) m = fmaxf(m, __shfl_xor(m, o));
    const float e0 = (lane < NR) ? expf(v0 - m) : 0.f;
    const float e1 = (lane + 64 < NR) ? expf(v1 - m) : 0.f;
    float s = e0 + e1;
    for (int o = 32; o; o >>= 1) s += __shfl_xor(s, o);
    const float inv = 1.f / s;
    if (lane < NR) red_s[lane] = e0 * inv;
    if (lane + 64 < NR) red_s[lane + 64] = e1 * inv;
  }
  __syncthreads();
  if (tid < NR) att_out[((size_t)b * NT + t) * NR + tid] = red_s[tid];

  // feat_hat: split rows across 2 thread-halves; 8 d's (16B) per thread
  const int half = tid >> 8;              // 0 or 1
  const int dd = (tid & 255) * 8;         // 8-aligned d
  const int r0 = half * 50, r1 = r0 + 50;
  float fh8[8] = {};
  if constexpr (F16) {
    const unsigned short* fbase = f16 + (size_t)b * NR * VD;
    for (int r = r0; r < r1; ++r) {
      const int ro = b * NR + r;
      const s8v f = *(const s8v*)(fbase + (size_t)r * VD + (dd ^ (Frow(ro & 15) << 3)));
      const float a = red_s[r];
#pragma unroll
      for (int e = 0; e < 8; ++e) fh8[e] += a * b2f((unsigned short)f[e]);
    }
  } else {
    const float* fb = f32 + (size_t)b * NR * VD + dd;
    for (int r = r0; r < r1; ++r) {
      const float4 x0 = *(const float4*)(fb + (size_t)r * VD);
      const float4 x1 = *(const float4*)(fb + (size_t)r * VD + 4);
      const float a = red_s[r];
      fh8[0] += a * x0.x; fh8[1] += a * x0.y; fh8[2] += a * x0.z; fh8[3] += a * x0.w;
      fh8[4] += a * x1.x; fh8[5] += a * x1.y; fh8[6] += a * x1.z; fh8[7] += a * x1.w;
    }
  }
#pragma unroll
  for (int e = 0; e < 8; ++e) fh_s[half][dd + e] = fh8[e];
  __syncthreads();

  unsigned short* rowbase = A2c + (size_t)b * KGC;
  const int Fs = Frow(b & 15) << 3;
  const int d0 = tid * 4;
#pragma unroll
  for (int e = 0; e < 4; ++e) {
    const float v = (fh_s[0][d0 + e] + fh_s[1][d0 + e]) * (1.f / NR);
    storeCK(rowbase, 0, d0 + e, v, Fs);
  }
}

inline void convB(hipStream_t st, const float* src, int srcld, int K, int N,
                  unsigned short* dst, int dstld, int coff, int mode)
{
  dim3 g((K + 31) / 32, (N + 31) / 32);
  convB_k<<<g, 256, 0, st>>>(src, srcld, K, N, dst, dstld, coff, mode);
}

} // namespace

extern "C" void kernel_launch(void* const* d_in, const int* in_sizes, int n_in,
                              void* d_out, int out_size, void* d_ws, size_t ws_size,
                              hipStream_t stream)
{
  const int*   caption = (const int*)  d_in[0];
  const float* feat    = (const float*)d_in[1];
  const float* emb     = (const float*)d_in[2];
  const float* W_vin   = (const float*)d_in[3];
  const float* b_vin   = (const float*)d_in[4];
  const float* W_ih_v  = (const float*)d_in[5];
  const float* W_hh_v  = (const float*)d_in[6];
  const float* b_v     = (const float*)d_in[7];
  const float* W_va    = (const float*)d_in[8];
  const float* b_va    = (const float*)d_in[9];
  const float* W_ha    = (const float*)d_in[10];
  const float* b_ha    = (const float*)d_in[11];
  const float* W_a     = (const float*)d_in[12];
  const float* b_a     = (const float*)d_in[13];
  const float* W_ih_c  = (const float*)d_in[14];
  const float* W_hh_c  = (const float*)d_in[15];
  const float* b_c     = (const float*)d_in[16];
  const float* W_cls   = (const float*)d_in[17];
  const float* b_cls   = (const float*)d_in[18];

  float* out_repr = (float*)d_out;                       // [NB,NT,VOC]
  float* out_att  = out_repr + (size_t)NB * NT * VOC;    // [NB,NT,NR]

  char* cur = (char*)d_ws;
  auto take = [&](size_t bytes) { char* p = cur; cur += bytes; return p; };

  unsigned short* A2v  = (unsigned short*)take((size_t)NB * A2VLD * 2);
  unsigned short* A2c  = (unsigned short*)take((size_t)NB * KGC * 2);
  float* CV            = (float*)take((size_t)NB * NH * 4);
  float* CC            = (float*)take((size_t)NB * NH * 4);
  const size_t ZERO_BYTES = (size_t)NB * A2VLD * 2 + (size_t)NB * KGC * 2
                          + 2 * (size_t)NB * NH * 4;

  float* FM            = (float*)take((size_t)NB * VD * 4);
  float* VINP          = (float*)take((size_t)NB * IND * 4);
  unsigned short* X2   = (unsigned short*)take((size_t)NB * NT * X2LD * 2);  // 6.2MB
  float* FMG           = (float*)take((size_t)NB * H4 * 4);
  unsigned short* FM2  = (unsigned short*)take((size_t)NB * KFM * 2);        // 2MB
  unsigned short* VA16 = (unsigned short*)take((size_t)NB * NR * NH * 2);    // 52MB
  float* GP            = (float*)take((size_t)ZGC * NB * H4 * 4);            // 33.5MB
  float* HAP           = (float*)take((size_t)ZHA * NB * NH * 4);            // 16.8MB
  unsigned short* OUTH2= (unsigned short*)take((size_t)NB * NT * KCL * 2);   // 21MB
  unsigned short* Wgv2t= (unsigned short*)take((size_t)H4 * KGVO * 2);       // 19.3MB
  unsigned short* Wha2t= (unsigned short*)take((size_t)NH * KHAO * 2);       // 2.1MB
  unsigned short* Wgc2t= (unsigned short*)take((size_t)H4 * KGCO * 2);       // 33.5MB
  unsigned short* Wfmg = (unsigned short*)take((size_t)H4 * KFMO * 2);       // 16.8MB
  unsigned short* WvinT= (unsigned short*)take((size_t)NVI * KFMO * 2);      // 1.6MB
  unsigned short* Wcls2t=(unsigned short*)take((size_t)VOCP * KCLO * 2);     // 20.7MB
  unsigned short* Wva16t=(unsigned short*)take((size_t)NH * VD * 2);         // 4.2MB
  unsigned short* FEAT16=(unsigned short*)cur;                               // 105MB optional
  const bool useF16 = ((size_t)(cur - (char*)d_ws) + (size_t)NB * NR * VD * 2) <= ws_size;

  hipMemsetAsync(A2v, 0, ZERO_BYTES, stream);

  // ---- weight conversions (plain bf16-hi, dedup; VA swizzled) ----
  convB(stream, W_ih_v + (size_t)2048 * H4, H4, 1024, H4, Wgv2t, KGVO, 0,    0);
  convB(stream, W_hh_v,                     H4, 1024, H4, Wgv2t, KGVO, 1024, 0);
  convB(stream, W_ih_v + (size_t)3072 * H4, H4, 300,  H4, Wgv2t, KGVO, 2048, 0);
  zpad_plain_k<<<((H4 * (KGVO - 2348)) + 255) / 256, 256, 0, stream>>>(
      Wgv2t, KGVO, 2348, H4);
  convB(stream, W_ha, NH, 1024, NH, Wha2t, KHAO, 0, 0);
  convB(stream, W_ih_c,                     H4, 2048, H4, Wgc2t, KGCO, 0,    0);
  convB(stream, W_ih_c + (size_t)2048 * H4, H4, 1024, H4, Wgc2t, KGCO, 2048, 0);
  convB(stream, W_hh_c,                     H4, 1024, H4, Wgc2t, KGCO, 3072, 0);
  convB(stream, W_ih_v,                     H4, 2048, H4, Wfmg,  KFMO, 0,    0);
  convB(stream, W_vin, IND, 2048, IND, WvinT, KFMO, 0, 0);
  zfill_k<<<(((NVI - IND) * KFMO) + 255) / 256, 256, 0, stream>>>(
      WvinT + (size_t)IND * KFMO, (NVI - IND) * KFMO);
  convB(stream, W_cls, VOC, 1024, VOC, Wcls2t, KCLO, 0, 0);
  zfill_k<<<(((VOCP - VOC) * KCLO) + 255) / 256, 256, 0, stream>>>(
      Wcls2t + (size_t)VOC * KCLO, (VOCP - VOC) * KCLO);
  convB(stream, W_va, NH, VD, NH, Wva16t, VD, 0, 1);

  // ---- setup ----
  feat_pass_k<<<(NB * (VD / 8) + 255) / 256, 256, 0, stream>>>(
      feat, FM, useF16 ? FEAT16 : nullptr);
  pack_fm_k<<<(NB * VD + 255) / 256, 256, 0, stream>>>(FM, FM2);
  // VINP via MFMA split-K (was fp32 VALU GEMM)
  gemm_sk2<false><<<dim3(NVI / 128, 2, ZFM), 256, 0, stream>>>(
      FM2, KFM, nullptr, 0, WvinT, KFMO, GP, NVI, KFM, KSF);
  vinp_red_k<<<(NB * IND + 255) / 256, 256, 0, stream>>>(GP, b_vin, VINP);
  build_x2_k<<<(NB * NT * X2LD + 255) / 256, 256, 0, stream>>>(caption, emb, VINP, X2);
  // FMG via MFMA split-K
  gemm_sk2<false><<<dim3(H4 / 128, 2, ZFM), 256, 0, stream>>>(
      FM2, KFM, nullptr, 0, Wfmg, KFMO, GP, H4, KFM, KSF);
  fmg_red_k<<<(NB * H4 + 255) / 256, 256, 0, stream>>>(GP, b_v, FMG);
  if (useF16) {
    dim3 g((NB * NR) / 128, NH / 128);
    gemm128<true, false><<<g, 256, 0, stream>>>(
        FEAT16, VD, Wva16t, VD, VA16, NH, b_va, NH, VD);
  } else {
    dim3 g((NB * NR) / 128, NH / 128);
    gemm_va_f32<<<g, 256, 0, stream>>>(feat, VD, Wva16t, VD, VA16, NH, b_va, NH, VD);
  }

  // ---- sequential decode ----
  for (int t = 0; t < NT; ++t) {
    gemm_sk2<true><<<dim3(H4 / 128, 2, ZGV), 256, 0, stream>>>(
        A2v, A2VLD, X2, t, Wgv2t, KGVO, GP, H4, KGV, KSV);
    lstm_pw_v_k<<<(NB * NH + 255) / 256, 256, 0, stream>>>(GP, FMG, CV, A2c, A2v);
    gemm_sk2<false><<<dim3(NH / 128, 2, ZHA), 256, 0, stream>>>(
        A2c + 4096, KGC, nullptr, 0, Wha2t, KHAO, HAP, NH, KHA, KSH);
    if (useF16)
      att_fused_k<true><<<NB, 512, 0, stream>>>(
          VA16, HAP, b_ha, W_a, b_a, FEAT16, nullptr, A2c, out_att, t);
    else
      att_fused_k<false><<<NB, 512, 0, stream>>>(
          VA16, HAP, b_ha, W_a, b_a, nullptr, feat, A2c, out_att, t);
    gemm_sk2<false><<<dim3(H4 / 128, 2, ZGC), 256, 0, stream>>>(
        A2c, KGC, nullptr, 0, Wgc2t, KGCO, GP, H4, KGC, KSC);
    lstm_pw_c_k<<<(NB * NH + 255) / 256, 256, 0, stream>>>(GP, b_c, CC, A2v, A2c, OUTH2, t);
  }

  // ---- classifier: 128x128 tiles, dedup-B, K'=2048 ----
  {
    dim3 g((NB * NT) / 128, VOCP / 128);
    gemm128<false, true><<<g, 256, 0, stream>>>(
        OUTH2, KCL, Wcls2t, KCLO, out_repr, VOC, b_cls, VOC, KCL);
  }
}

// Round 15
// 2860.908 us; speedup vs baseline: 1.8728x; 1.1699x over previous
//
#include <hip/hip_runtime.h>
#include <math.h>

namespace {

constexpr int NB  = 256;
constexpr int NT  = 20;
constexpr int NR  = 100;
constexpr int IND = 300;
constexpr int NH  = 1024;
constexpr int VD  = 2048;
constexpr int H4  = 4096;
constexpr int VOC = 10000;
constexpr int VOCP = 10112;   // vocab padded to 128

// Activations now PLAIN bf16-hi (1-slot), rows swizzled by Frow(row&15)<<3.
// Only the classifier A-side (OUTH2) keeps the chunked 2-slot split:
//   orig k -> hi at ((k>>3)<<4)+(k&7), lo at +8  (KCL = 2*1024)
constexpr int KGV = 2368;     // gates_v: hc1024 + hv1024 + x300 -> pad 2368
constexpr int KGC = 4096;     // gates_c: feat2048 + hv1024 + hc1024
constexpr int KHA = 1024;
constexpr int KCL = 2048;  constexpr int KCLO = 1024;
constexpr int KFM = 2048;     // FMG/VINP from FM16
constexpr int NVI = 384;      // VINP N padded to 3*128
constexpr int A2VLD = 2048;   // A2v row: [h_c(1024) | h_v(1024)]; x-seg from X2
constexpr int X2LD  = 320;    // 300 payload + 20 zero pad

constexpr int ZGV = 8;  constexpr int KSV = 320;   // 7x320 + 128
constexpr int ZGC = 8;  constexpr int KSC = 512;
constexpr int ZHA = 8;  constexpr int KSH = 128;
constexpr int ZFM = 8;  constexpr int KSF = 256;

typedef short  s8v  __attribute__((ext_vector_type(8)));
typedef float  f4v  __attribute__((ext_vector_type(4)));

__device__ __forceinline__ float sigm(float x) { return 1.f / (1.f + expf(-x)); }
__device__ __forceinline__ unsigned short f2b(float x) {
  return __builtin_bit_cast(unsigned short, (__bf16)x);
}
__device__ __forceinline__ float b2f(unsigned short u) {
  return (float)__builtin_bit_cast(__bf16, u);
}
__device__ __forceinline__ int Frow(int row) { return (row ^ (row >> 2)) & 3; }
// plain 1-slot store (swizzled row)
__device__ __forceinline__ void store1(unsigned short* rowbase, int k, float x, int Fs) {
  rowbase[k ^ Fs] = f2b(x);
}
// chunked 2-slot store (classifier A only)
__device__ __forceinline__ void storeCK(unsigned short* rowbase, int korig, float x, int Fs) {
  const unsigned short h = f2b(x);
  const unsigned short l = f2b(x - b2f(h));
  const int ph = ((korig >> 3) << 4) + (korig & 7);
  rowbase[ph ^ Fs] = h;
  rowbase[(ph + 8) ^ Fs] = l;
}

__device__ __forceinline__ void gload16(const unsigned short* g, unsigned short* l) {
  __builtin_amdgcn_global_load_lds(
      (const __attribute__((address_space(1))) void*)g,
      (__attribute__((address_space(3))) void*)l, 16, 0, 0);
}

#define BARRIER()  __syncthreads()
#define VMWAIT0()  asm volatile("s_waitcnt vmcnt(0)" ::: "memory")

// =================== 128x128 bf16 MFMA GEMM, 2-phase dbuf =======================
// DUPB: A chunk-interleaved 2-slot (gload), B plain [N][Kp/2] reg-staged + dup.
// !DUPB: plain bf16 A and B, both gload from swizzled storage.
template<bool OUT_BF16, bool DUPB>
__global__ __launch_bounds__(256)
void gemm128(const unsigned short* __restrict__ A, int lda,
             const unsigned short* __restrict__ Bt, int ldb,
             void* __restrict__ Cv, int ldc,
             const float* __restrict__ bias,
             int N, int Kp)
{
  __shared__ unsigned short As[2][128 * 32];
  __shared__ unsigned short Bs[2][128 * 32];
  const int tid = threadIdx.x, wid = tid >> 6, lane = tid & 63;
  const int wm = (wid >> 1) * 64, wn = (wid & 1) * 64;
  const int m0 = blockIdx.x * 128, n0 = blockIdx.y * 128;
  const int sr = tid >> 2, sc = (tid & 3) * 8;
  const unsigned short* a0 = A + (size_t)(m0 + sr) * lda + sc;
  const unsigned short* a1 = a0 + (size_t)64 * lda;
  const unsigned short* bsrcD = Bt + (size_t)(n0 + (tid >> 1)) * ldb + (tid & 1) * 8;
  const unsigned short* b0 = Bt + (size_t)(n0 + sr) * ldb + sc;
  const unsigned short* b1 = b0 + (size_t)64 * ldb;
  const int rr = lane & 15;
  const int kc = (((lane >> 4) ^ Frow(rr)) & 3) * 8;
  const int wrow = tid >> 1, wc8 = tid & 1;
  const int wF = Frow(wrow & 15);

  f4v acc[4][4] = {};

  auto stageA = [&](int s, int k) {
    gload16(a0 + k, &As[s][tid * 8]);
    gload16(a1 + k, &As[s][2048 + tid * 8]);
  };
  auto stageBplain = [&](int s, int k) {
    gload16(b0 + k, &Bs[s][tid * 8]);
    gload16(b1 + k, &Bs[s][2048 + tid * 8]);
  };
  auto writeBdup = [&](int s, s8v v) {
    *(s8v*)&Bs[s][wrow * 32 + (((2 * wc8) ^ wF) * 8)] = v;
    *(s8v*)&Bs[s][wrow * 32 + (((2 * wc8 + 1) ^ wF) * 8)] = v;
  };
  auto compute = [&](int s) {
    s8v a[4], b[4];
#pragma unroll
    for (int i = 0; i < 4; ++i) a[i] = *(const s8v*)&As[s][(wm + i * 16 + rr) * 32 + kc];
#pragma unroll
    for (int j = 0; j < 4; ++j) b[j] = *(const s8v*)&Bs[s][(wn + j * 16 + rr) * 32 + kc];
#pragma unroll
    for (int i = 0; i < 4; ++i)
#pragma unroll
      for (int j = 0; j < 4; ++j)
        acc[i][j] = __builtin_amdgcn_mfma_f32_16x16x32_bf16(a[i], b[j], acc[i][j], 0, 0, 0);
  };

  stageA(0, 0);
  if constexpr (DUPB) {
    s8v v = *(const s8v*)(bsrcD);
    VMWAIT0();
    writeBdup(0, v);
  } else {
    stageBplain(0, 0);
    VMWAIT0();
  }
  BARRIER();

  int cur = 0;
  for (int k0 = 0; k0 < Kp; k0 += 32) {
    const bool more = (k0 + 32 < Kp);
    if constexpr (DUPB) {
      s8v v;
      if (more) { stageA(cur ^ 1, k0 + 32); v = *(const s8v*)(bsrcD + ((k0 + 32) >> 1)); }
      compute(cur);
      VMWAIT0();
      if (more) writeBdup(cur ^ 1, v);
    } else {
      if (more) { stageA(cur ^ 1, k0 + 32); stageBplain(cur ^ 1, k0 + 32); }
      compute(cur);
      VMWAIT0();
    }
    BARRIER();
    cur ^= 1;
  }

  const int cr = (lane >> 4) * 4, cc = lane & 15;
#pragma unroll
  for (int i = 0; i < 4; ++i) {
#pragma unroll
    for (int j = 0; j < 4; ++j) {
      const int gn = n0 + wn + j * 16 + cc;
      if (gn >= N) continue;
#pragma unroll
      for (int r = 0; r < 4; ++r) {
        const int gm = m0 + wm + i * 16 + cr + r;
        float v = acc[i][j][r] + bias[gn];
        if constexpr (OUT_BF16) ((unsigned short*)Cv)[(size_t)gm * ldc + gn] = f2b(v);
        else                    ((float*)Cv)[(size_t)gm * ldc + gn] = v;
      }
    }
  }
}

// =================== split-K GEMM, plain bf16 A+B (both gload, swizzled) ========
template<bool XSEG>
__global__ __launch_bounds__(256)
void gemm_sk2(const unsigned short* __restrict__ A, int lda,
              const unsigned short* __restrict__ X2, int t,
              const unsigned short* __restrict__ Bt, int ldb,
              float* __restrict__ P, int N, int Kp, int Ksplit)
{
  __shared__ unsigned short As[2][128 * 32];
  __shared__ unsigned short Bs[2][128 * 32];
  const int tid = threadIdx.x, wid = tid >> 6, lane = tid & 63;
  const int wm = (wid >> 1) * 64, wn = (wid & 1) * 64;
  const int m0 = blockIdx.y * 128, n0 = blockIdx.x * 128;
  const int kbeg = blockIdx.z * Ksplit;
  const int kend = min(Kp, kbeg + Ksplit);
  const int sr = tid >> 2, sc = (tid & 3) * 8;
  const unsigned short* a0 = A + (size_t)(m0 + sr) * lda + sc;
  const unsigned short* a1 = a0 + (size_t)64 * lda;
  const unsigned short* x0 = nullptr;
  const unsigned short* x1 = nullptr;
  if constexpr (XSEG) {
    x0 = X2 + ((size_t)(m0 + sr) * NT + t) * X2LD + sc;
    x1 = x0 + (size_t)64 * NT * X2LD;
  }
  const unsigned short* b0 = Bt + (size_t)(n0 + sr) * ldb + sc;
  const unsigned short* b1 = b0 + (size_t)64 * ldb;
  const int rr = lane & 15;
  const int kc = (((lane >> 4) ^ Frow(rr)) & 3) * 8;

  f4v acc[4][4] = {};

  auto stage = [&](int s, int k) {
    if constexpr (XSEG) {
      if (k >= A2VLD) {
        gload16(x0 + (k - A2VLD), &As[s][tid * 8]);
        gload16(x1 + (k - A2VLD), &As[s][2048 + tid * 8]);
      } else {
        gload16(a0 + k, &As[s][tid * 8]);
        gload16(a1 + k, &As[s][2048 + tid * 8]);
      }
    } else {
      gload16(a0 + k, &As[s][tid * 8]);
      gload16(a1 + k, &As[s][2048 + tid * 8]);
    }
    gload16(b0 + k, &Bs[s][tid * 8]);
    gload16(b1 + k, &Bs[s][2048 + tid * 8]);
  };
  auto compute = [&](int s) {
    s8v a[4], b[4];
#pragma unroll
    for (int i = 0; i < 4; ++i) a[i] = *(const s8v*)&As[s][(wm + i * 16 + rr) * 32 + kc];
#pragma unroll
    for (int j = 0; j < 4; ++j) b[j] = *(const s8v*)&Bs[s][(wn + j * 16 + rr) * 32 + kc];
#pragma unroll
    for (int i = 0; i < 4; ++i)
#pragma unroll
      for (int j = 0; j < 4; ++j)
        acc[i][j] = __builtin_amdgcn_mfma_f32_16x16x32_bf16(a[i], b[j], acc[i][j], 0, 0, 0);
  };

  stage(0, kbeg);
  VMWAIT0();
  BARRIER();

  int cur = 0;
  for (int k0 = kbeg; k0 < kend; k0 += 32) {
    if (k0 + 32 < kend) stage(cur ^ 1, k0 + 32);
    compute(cur);
    VMWAIT0();
    BARRIER();
    cur ^= 1;
  }

  float* out = P + (size_t)blockIdx.z * 256 * N;
  const int cr = (lane >> 4) * 4, cc = lane & 15;
#pragma unroll
  for (int i = 0; i < 4; ++i)
#pragma unroll
    for (int j = 0; j < 4; ++j)
#pragma unroll
      for (int r = 0; r < 4; ++r)
        out[(size_t)(m0 + wm + i * 16 + cr + r) * N + n0 + wn + j * 16 + cc] = acc[i][j][r];
}

// =================== 128x128 VA fallback (fp32 A converted on stage) ============
__global__ __launch_bounds__(256)
void gemm_va_f32(const float* __restrict__ A, int lda,
                 const unsigned short* __restrict__ Bt, int ldb,
                 unsigned short* __restrict__ C, int ldc,
                 const float* __restrict__ bias, int N, int Kp)
{
  __shared__ unsigned short As[128 * 32];
  __shared__ unsigned short Bs[128 * 32];
  const int tid = threadIdx.x, wid = tid >> 6, lane = tid & 63;
  const int wm = (wid >> 1) * 64, wn = (wid & 1) * 64;
  const int m0 = blockIdx.x * 128, n0 = blockIdx.y * 128;
  const unsigned short* bsrc0 = Bt + (size_t)(n0 + (tid >> 2)) * ldb + (tid & 3) * 8;
  const unsigned short* bsrc1 = bsrc0 + (size_t)64 * ldb;
  const int rr = lane & 15;
  const int kc = (((lane >> 4) ^ Frow(rr)) & 3) * 8;

  f4v acc[4][4] = {};
  for (int k0 = 0; k0 < Kp; k0 += 32) {
#pragma unroll
    for (int it = 0; it < 4; ++it) {
      const int r = it * 32 + (tid >> 3), c = (tid & 7) * 4;
      const float4 v = *(const float4*)(A + (size_t)(m0 + r) * lda + k0 + c);
      ushort4 w;
      w.x = f2b(v.x); w.y = f2b(v.y); w.z = f2b(v.z); w.w = f2b(v.w);
      *(ushort4*)&As[r * 32 + (c ^ (Frow(r & 15) << 3))] = w;
    }
    gload16(bsrc0 + k0, &Bs[tid * 8]);
    gload16(bsrc1 + k0, &Bs[2048 + tid * 8]);
    __syncthreads();
    s8v a[4], b[4];
#pragma unroll
    for (int i = 0; i < 4; ++i) a[i] = *(const s8v*)&As[(wm + i * 16 + rr) * 32 + kc];
#pragma unroll
    for (int j = 0; j < 4; ++j) b[j] = *(const s8v*)&Bs[(wn + j * 16 + rr) * 32 + kc];
#pragma unroll
    for (int i = 0; i < 4; ++i)
#pragma unroll
      for (int j = 0; j < 4; ++j)
        acc[i][j] = __builtin_amdgcn_mfma_f32_16x16x32_bf16(a[i], b[j], acc[i][j], 0, 0, 0);
    __syncthreads();
  }
  const int cr = (lane >> 4) * 4, cc = lane & 15;
#pragma unroll
  for (int i = 0; i < 4; ++i)
#pragma unroll
    for (int j = 0; j < 4; ++j) {
      const int gn = n0 + wn + j * 16 + cc;
      if (gn >= N) continue;
#pragma unroll
      for (int r = 0; r < 4; ++r)
        C[(size_t)(m0 + wm + i * 16 + cr + r) * ldc + gn] = f2b(acc[i][j][r] + bias[gn]);
    }
}

// =================== weight transpose+convert ===================
// mode 0: PLAIN bf16-hi at orig k, no swizzle (classifier dedup-B)
// mode 1: bf16-hi at swizzled position (gload-path operands)
__global__ void convB_k(const float* __restrict__ src, int srcld, int K, int N,
                        unsigned short* __restrict__ dst, int dstld, int coff, int mode)
{
  __shared__ float t[32][33];
  const int kb = blockIdx.x * 32, nb = blockIdx.y * 32;
  const int tx = threadIdx.x & 31, ty = threadIdx.x >> 5;
#pragma unroll
  for (int i = 0; i < 32; i += 8) {
    const int k = kb + ty + i, n = nb + tx;
    t[ty + i][tx] = (k < K && n < N) ? src[(size_t)k * srcld + n] : 0.f;
  }
  __syncthreads();
#pragma unroll
  for (int i = 0; i < 32; i += 8) {
    const int n = nb + ty + i, k = kb + tx;
    if (n >= N || k >= K) continue;
    const float x = t[tx][ty + i];
    unsigned short* row = dst + (size_t)n * dstld;
    if (mode == 0) {
      row[coff + k] = f2b(x);
    } else {
      row[(coff + k) ^ (Frow(n & 15) << 3)] = f2b(x);
    }
  }
}

// zero swizzled columns [c0, ld)
__global__ void zpad_swz_k(unsigned short* __restrict__ dst, int ld, int c0, int N)
{
  const int w = ld - c0;
  const int idx = blockIdx.x * 256 + threadIdx.x;
  if (idx >= N * w) return;
  const int n = idx / w, c = c0 + (idx % w);
  dst[(size_t)n * ld + (c ^ (Frow(n & 15) << 3))] = 0;
}

__global__ void zfill_k(unsigned short* __restrict__ p, int n)
{
  const int i = blockIdx.x * 256 + threadIdx.x;
  if (i < n) p[i] = 0;
}

// ============ fused feature pass: mean(bf16 swizzled) + feat bf16 convert =======
__global__ void feat_pass_k(const float* __restrict__ feat,
                            unsigned short* __restrict__ fm16,
                            unsigned short* __restrict__ f16out)
{
  const int idx = blockIdx.x * 256 + threadIdx.x;   // NB * VD/8
  if (idx >= NB * (VD / 8)) return;
  const int d0 = (idx & (VD / 8 - 1)) * 8, b = idx / (VD / 8);
  const float* base = feat + (size_t)b * NR * VD + d0;
  float s[8] = {};
  for (int r = 0; r < NR; ++r) {
    const float4 x0 = *(const float4*)(base + (size_t)r * VD);
    const float4 x1 = *(const float4*)(base + (size_t)r * VD + 4);
    s[0] += x0.x; s[1] += x0.y; s[2] += x0.z; s[3] += x0.w;
    s[4] += x1.x; s[5] += x1.y; s[6] += x1.z; s[7] += x1.w;
    if (f16out) {
      unsigned short w[8] = {f2b(x0.x), f2b(x0.y), f2b(x0.z), f2b(x0.w),
                             f2b(x1.x), f2b(x1.y), f2b(x1.z), f2b(x1.w)};
      const int ro = b * NR + r;
      *(s8v*)(f16out + (size_t)ro * VD + (d0 ^ (Frow(ro & 15) << 3))) = *(const s8v*)w;
    }
  }
  unsigned short w[8];
#pragma unroll
  for (int e = 0; e < 8; ++e) w[e] = f2b(s[e] * (1.f / NR));
  *(s8v*)(fm16 + (size_t)b * KFM + (d0 ^ (Frow(b & 15) << 3))) = *(const s8v*)w;
}

// FMG = b_v + sum_z GP[z]
__global__ void fmg_red_k(const float* __restrict__ gp, const float* __restrict__ bv,
                          float* __restrict__ fmg)
{
  const int idx = blockIdx.x * 256 + threadIdx.x;   // NB*H4
  if (idx >= NB * H4) return;
  float s = bv[idx & (H4 - 1)];
#pragma unroll
  for (int z = 0; z < ZFM; ++z) s += gp[(size_t)z * NB * H4 + idx];
  fmg[idx] = s;
}

// VINP = b_vin + sum_z GP[z] (N=NVI partials, keep n<IND)
__global__ void vinp_red_k(const float* __restrict__ gp, const float* __restrict__ bvin,
                           float* __restrict__ vinp)
{
  const int idx = blockIdx.x * 256 + threadIdx.x;   // NB*IND
  if (idx >= NB * IND) return;
  const int n = idx % IND, b = idx / IND;
  float s = bvin[n];
#pragma unroll
  for (int z = 0; z < ZFM; ++z) s += gp[(size_t)z * NB * NVI + (size_t)b * NVI + n];
  vinp[idx] = s;
}

// X2: plain bf16-hi, swizzled by F(b); payload d<300
__global__ void build_x2_k(const int* __restrict__ cap, const float* __restrict__ emb,
                           const float* __restrict__ vinp, unsigned short* __restrict__ X2)
{
  const int idx = blockIdx.x * 256 + threadIdx.x;
  if (idx >= NB * NT * X2LD) return;
  const int c = idx % X2LD;
  const int bt = idx / X2LD;
  const int t = bt % NT, b = bt / NT;
  const int Fs = Frow(b & 15) << 3;
  unsigned short val = 0;
  if (c < IND) {
    const float v = (t == 0) ? vinp[b * IND + c]
                             : emb[(size_t)cap[b * (NT - 1) + (t - 1)] * IND + c];
    val = f2b(v);
  }
  X2[(size_t)bt * X2LD + (c ^ Fs)] = val;
}

__global__ void lstm_pw_v_k(const float* __restrict__ gp, const float* __restrict__ fmg,
                            float* __restrict__ cv,
                            unsigned short* __restrict__ A2c, unsigned short* __restrict__ A2v)
{
  const int idx = blockIdx.x * 256 + threadIdx.x;
  if (idx >= NB * NH) return;
  const int n = idx & (NH - 1), b = idx >> 10;
  const size_t base = (size_t)b * H4;
  float gi = fmg[base + n], gf = fmg[base + NH + n];
  float gg = fmg[base + 2 * NH + n], go = fmg[base + 3 * NH + n];
#pragma unroll
  for (int z = 0; z < ZGV; ++z) {
    const float* g = gp + (size_t)z * NB * H4 + base;
    gi += g[n]; gf += g[NH + n]; gg += g[2 * NH + n]; go += g[3 * NH + n];
  }
  const float c2 = sigm(gf) * cv[idx] + sigm(gi) * tanhf(gg);
  const float h2 = sigm(go) * tanhf(c2);
  cv[idx] = c2;
  const int Fs = Frow(b & 15) << 3;
  store1(A2c + (size_t)b * KGC, 2048 + n, h2, Fs);
  store1(A2v + (size_t)b * A2VLD, 1024 + n, h2, Fs);
}

__global__ void lstm_pw_c_k(const float* __restrict__ gp, const float* __restrict__ bc,
                            float* __restrict__ cc,
                            unsigned short* __restrict__ A2v, unsigned short* __restrict__ A2c,
                            unsigned short* __restrict__ outh2, int t)
{
  const int idx = blockIdx.x * 256 + threadIdx.x;
  if (idx >= NB * NH) return;
  const int n = idx & (NH - 1), b = idx >> 10;
  const size_t base = (size_t)b * H4;
  float gi = bc[n], gf = bc[NH + n], gg = bc[2 * NH + n], go = bc[3 * NH + n];
#pragma unroll
  for (int z = 0; z < ZGC; ++z) {
    const float* g = gp + (size_t)z * NB * H4 + base;
    gi += g[n]; gf += g[NH + n]; gg += g[2 * NH + n]; go += g[3 * NH + n];
  }
  const float c2 = sigm(gf) * cc[idx] + sigm(gi) * tanhf(gg);
  const float h2 = sigm(go) * tanhf(c2);
  cc[idx] = c2;
  const int Fs = Frow(b & 15) << 3;
  store1(A2v + (size_t)b * A2VLD, n, h2, Fs);
  store1(A2c + (size_t)b * KGC, 3072 + n, h2, Fs);
  const int ro = b * NT + t;
  storeCK(outh2 + (size_t)ro * KCL, n, h2, Frow(ro & 15) << 3);
}

// =================== fused attention: ha-reduce + logits + softmax + feat_hat ===
template<bool F16>
__global__ __launch_bounds__(512)
void att_fused_k(const unsigned short* __restrict__ va16,
                 const float* __restrict__ hap,   // [ZHA][NB][NH]
                 const float* __restrict__ bha,
                 const float* __restrict__ Wa, const float* __restrict__ ba,
                 const unsigned short* __restrict__ f16,
                 const float* __restrict__ f32,
                 unsigned short* __restrict__ A2c,
                 float* __restrict__ att_out, int t)
{
  const int b = blockIdx.x, tid = threadIdx.x;
  const int lane = tid & 63, wid = tid >> 6;
  __shared__ float ha_s[NH];
  __shared__ float wa_s[NH];
  __shared__ float red_s[128];
  __shared__ float fh_s[2][VD];

  for (int j = tid; j < NH; j += 512) {
    float s = bha[j];
#pragma unroll
    for (int z = 0; z < ZHA; ++z) s += hap[((size_t)z * NB + b) * NH + j];
    ha_s[j] = s;
    wa_s[j] = Wa[j];
  }
  __syncthreads();

  for (int r = wid; r < NR; r += 8) {
    const unsigned short* vrow = va16 + ((size_t)b * NR + r) * NH + lane * 16;
    float s = 0.f;
#pragma unroll
    for (int u = 0; u < 2; ++u) {
      const s8v v = *(const s8v*)(vrow + u * 8);
      const int j0 = lane * 16 + u * 8;
#pragma unroll
      for (int e = 0; e < 8; ++e)
        s += tanhf(b2f((unsigned short)v[e]) + ha_s[j0 + e]) * wa_s[j0 + e];
    }
    for (int o = 32; o; o >>= 1) s += __shfl_down(s, o);
    if (lane == 0) red_s[r] = s + ba[0];
  }
  __syncthreads();

  if (wid == 0) {
    float v0 = (lane < NR) ? red_s[lane] : -3.4e38f;
    float v1 = (lane + 64 < NR) ? red_s[lane + 64] : -3.4e38f;
    float m = fmaxf(v0, v1);
    for (int o = 32; o; o >>= 1) m = fmaxf(m, __shfl_xor(m, o));
    const float e0 = (lane < NR) ? expf(v0 - m) : 0.f;
    const float e1 = (lane + 64 < NR) ? expf(v1 - m) : 0.f;
    float s = e0 + e1;
    for (int o = 32; o; o >>= 1) s += __shfl_xor(s, o);
    const float inv = 1.f / s;
    if (lane < NR) red_s[lane] = e0 * inv;
    if (lane + 64 < NR) red_s[lane + 64] = e1 * inv;
  }
  __syncthreads();
  if (tid < NR) att_out[((size_t)b * NT + t) * NR + tid] = red_s[tid];

  // feat_hat: split rows across 2 thread-halves; 8 d's (16B) per thread
  const int half = tid >> 8;
  const int dd = (tid & 255) * 8;
  const int r0 = half * 50, r1 = r0 + 50;
  float fh8[8] = {};
  if constexpr (F16) {
    const unsigned short* fbase = f16 + (size_t)b * NR * VD;
    for (int r = r0; r < r1; ++r) {
      const int ro = b * NR + r;
      const s8v f = *(const s8v*)(fbase + (size_t)r * VD + (dd ^ (Frow(ro & 15) << 3)));
      const float a = red_s[r];
#pragma unroll
      for (int e = 0; e < 8; ++e) fh8[e] += a * b2f((unsigned short)f[e]);
    }
  } else {
    const float* fb = f32 + (size_t)b * NR * VD + dd;
    for (int r = r0; r < r1; ++r) {
      const float4 x0 = *(const float4*)(fb + (size_t)r * VD);
      const float4 x1 = *(const float4*)(fb + (size_t)r * VD + 4);
      const float a = red_s[r];
      fh8[0] += a * x0.x; fh8[1] += a * x0.y; fh8[2] += a * x0.z; fh8[3] += a * x0.w;
      fh8[4] += a * x1.x; fh8[5] += a * x1.y; fh8[6] += a * x1.z; fh8[7] += a * x1.w;
    }
  }
#pragma unroll
  for (int e = 0; e < 8; ++e) fh_s[half][dd + e] = fh8[e];
  __syncthreads();

  unsigned short* rowbase = A2c + (size_t)b * KGC;
  const int Fs = Frow(b & 15) << 3;
  const int d0 = tid * 4;
#pragma unroll
  for (int e = 0; e < 4; ++e) {
    const float v = (fh_s[0][d0 + e] + fh_s[1][d0 + e]) * (1.f / NR);
    store1(rowbase, d0 + e, v, Fs);
  }
}

inline void convB(hipStream_t st, const float* src, int srcld, int K, int N,
                  unsigned short* dst, int dstld, int coff, int mode)
{
  dim3 g((K + 31) / 32, (N + 31) / 32);
  convB_k<<<g, 256, 0, st>>>(src, srcld, K, N, dst, dstld, coff, mode);
}

} // namespace

extern "C" void kernel_launch(void* const* d_in, const int* in_sizes, int n_in,
                              void* d_out, int out_size, void* d_ws, size_t ws_size,
                              hipStream_t stream)
{
  const int*   caption = (const int*)  d_in[0];
  const float* feat    = (const float*)d_in[1];
  const float* emb     = (const float*)d_in[2];
  const float* W_vin   = (const float*)d_in[3];
  const float* b_vin   = (const float*)d_in[4];
  const float* W_ih_v  = (const float*)d_in[5];
  const float* W_hh_v  = (const float*)d_in[6];
  const float* b_v     = (const float*)d_in[7];
  const float* W_va    = (const float*)d_in[8];
  const float* b_va    = (const float*)d_in[9];
  const float* W_ha    = (const float*)d_in[10];
  const float* b_ha    = (const float*)d_in[11];
  const float* W_a     = (const float*)d_in[12];
  const float* b_a     = (const float*)d_in[13];
  const float* W_ih_c  = (const float*)d_in[14];
  const float* W_hh_c  = (const float*)d_in[15];
  const float* b_c     = (const float*)d_in[16];
  const float* W_cls   = (const float*)d_in[17];
  const float* b_cls   = (const float*)d_in[18];

  float* out_repr = (float*)d_out;                       // [NB,NT,VOC]
  float* out_att  = out_repr + (size_t)NB * NT * VOC;    // [NB,NT,NR]

  char* cur = (char*)d_ws;
  auto take = [&](size_t bytes) { char* p = cur; cur += bytes; return p; };

  unsigned short* A2v  = (unsigned short*)take((size_t)NB * A2VLD * 2);      // 1MB
  unsigned short* A2c  = (unsigned short*)take((size_t)NB * KGC * 2);        // 2MB
  float* CV            = (float*)take((size_t)NB * NH * 4);
  float* CC            = (float*)take((size_t)NB * NH * 4);
  const size_t ZERO_BYTES = (size_t)NB * A2VLD * 2 + (size_t)NB * KGC * 2
                          + 2 * (size_t)NB * NH * 4;

  float* VINP          = (float*)take((size_t)NB * IND * 4);
  unsigned short* X2   = (unsigned short*)take((size_t)NB * NT * X2LD * 2);  // 3.3MB
  float* FMG           = (float*)take((size_t)NB * H4 * 4);
  unsigned short* FM16 = (unsigned short*)take((size_t)NB * KFM * 2);        // 1MB
  unsigned short* VA16 = (unsigned short*)take((size_t)NB * NR * NH * 2);    // 52MB
  float* GP            = (float*)take((size_t)ZGC * NB * H4 * 4);            // 33.5MB
  float* HAP           = (float*)take((size_t)ZHA * NB * NH * 4);            // 8.4MB
  unsigned short* OUTH2= (unsigned short*)take((size_t)NB * NT * KCL * 2);   // 21MB
  unsigned short* Wgv2t= (unsigned short*)take((size_t)H4 * KGV * 2);        // 19.4MB
  unsigned short* Wha2t= (unsigned short*)take((size_t)NH * KHA * 2);        // 2.1MB
  unsigned short* Wgc2t= (unsigned short*)take((size_t)H4 * KGC * 2);        // 33.5MB
  unsigned short* Wfmg = (unsigned short*)take((size_t)H4 * KFM * 2);        // 16.8MB
  unsigned short* WvinT= (unsigned short*)take((size_t)NVI * KFM * 2);       // 1.6MB
  unsigned short* Wcls2t=(unsigned short*)take((size_t)VOCP * KCLO * 2);     // 20.7MB
  unsigned short* Wva16t=(unsigned short*)take((size_t)NH * VD * 2);         // 4.2MB
  unsigned short* FEAT16=(unsigned short*)cur;                               // 105MB optional
  const bool useF16 = ((size_t)(cur - (char*)d_ws) + (size_t)NB * NR * VD * 2) <= ws_size;

  hipMemsetAsync(A2v, 0, ZERO_BYTES, stream);

  // ---- weight conversions ----
  // gates_v B (swizzled): [W_ih_v[2048:3072] | W_hh_v | W_ih_v[3072:3372]] -> [4096][2368]
  convB(stream, W_ih_v + (size_t)2048 * H4, H4, 1024, H4, Wgv2t, KGV, 0,    1);
  convB(stream, W_hh_v,                     H4, 1024, H4, Wgv2t, KGV, 1024, 1);
  convB(stream, W_ih_v + (size_t)3072 * H4, H4, 300,  H4, Wgv2t, KGV, 2048, 1);
  zpad_swz_k<<<((H4 * (KGV - 2348)) + 255) / 256, 256, 0, stream>>>(
      Wgv2t, KGV, 2348, H4);
  convB(stream, W_ha, NH, 1024, NH, Wha2t, KHA, 0, 1);
  convB(stream, W_ih_c,                     H4, 2048, H4, Wgc2t, KGC, 0,    1);
  convB(stream, W_ih_c + (size_t)2048 * H4, H4, 1024, H4, Wgc2t, KGC, 2048, 1);
  convB(stream, W_hh_c,                     H4, 1024, H4, Wgc2t, KGC, 3072, 1);
  convB(stream, W_ih_v,                     H4, 2048, H4, Wfmg,  KFM, 0,    1);
  convB(stream, W_vin, IND, 2048, IND, WvinT, KFM, 0, 1);
  zfill_k<<<(((NVI - IND) * KFM) + 255) / 256, 256, 0, stream>>>(
      WvinT + (size_t)IND * KFM, (NVI - IND) * KFM);
  convB(stream, W_cls, VOC, 1024, VOC, Wcls2t, KCLO, 0, 0);
  zfill_k<<<(((VOCP - VOC) * KCLO) + 255) / 256, 256, 0, stream>>>(
      Wcls2t + (size_t)VOC * KCLO, (VOCP - VOC) * KCLO);
  convB(stream, W_va, NH, VD, NH, Wva16t, VD, 0, 1);

  // ---- setup ----
  feat_pass_k<<<(NB * (VD / 8) + 255) / 256, 256, 0, stream>>>(
      feat, FM16, useF16 ? FEAT16 : nullptr);
  // VINP via MFMA split-K
  gemm_sk2<false><<<dim3(NVI / 128, 2, ZFM), 256, 0, stream>>>(
      FM16, KFM, nullptr, 0, WvinT, KFM, GP, NVI, KFM, KSF);
  vinp_red_k<<<(NB * IND + 255) / 256, 256, 0, stream>>>(GP, b_vin, VINP);
  build_x2_k<<<(NB * NT * X2LD + 255) / 256, 256, 0, stream>>>(caption, emb, VINP, X2);
  // FMG via MFMA split-K
  gemm_sk2<false><<<dim3(H4 / 128, 2, ZFM), 256, 0, stream>>>(
      FM16, KFM, nullptr, 0, Wfmg, KFM, GP, H4, KFM, KSF);
  fmg_red_k<<<(NB * H4 + 255) / 256, 256, 0, stream>>>(GP, b_v, FMG);
  if (useF16) {
    dim3 g((NB * NR) / 128, NH / 128);
    gemm128<true, false><<<g, 256, 0, stream>>>(
        FEAT16, VD, Wva16t, VD, VA16, NH, b_va, NH, VD);
  } else {
    dim3 g((NB * NR) / 128, NH / 128);
    gemm_va_f32<<<g, 256, 0, stream>>>(feat, VD, Wva16t, VD, VA16, NH, b_va, NH, VD);
  }

  // ---- sequential decode ----
  for (int t = 0; t < NT; ++t) {
    gemm_sk2<true><<<dim3(H4 / 128, 2, ZGV), 256, 0, stream>>>(
        A2v, A2VLD, X2, t, Wgv2t, KGV, GP, H4, KGV, KSV);
    lstm_pw_v_k<<<(NB * NH + 255) / 256, 256, 0, stream>>>(GP, FMG, CV, A2c, A2v);
    gemm_sk2<false><<<dim3(NH / 128, 2, ZHA), 256, 0, stream>>>(
        A2c + 2048, KGC, nullptr, 0, Wha2t, KHA, HAP, NH, KHA, KSH);
    if (useF16)
      att_fused_k<true><<<NB, 512, 0, stream>>>(
          VA16, HAP, b_ha, W_a, b_a, FEAT16, nullptr, A2c, out_att, t);
    else
      att_fused_k<false><<<NB, 512, 0, stream>>>(
          VA16, HAP, b_ha, W_a, b_a, nullptr, feat, A2c, out_att, t);
    gemm_sk2<false><<<dim3(H4 / 128, 2, ZGC), 256, 0, stream>>>(
        A2c, KGC, nullptr, 0, Wgc2t, KGC, GP, H4, KGC, KSC);
    lstm_pw_c_k<<<(NB * NH + 255) / 256, 256, 0, stream>>>(GP, b_c, CC, A2v, A2c, OUTH2, t);
  }

  // ---- classifier: 128x128 tiles, dedup-B, A = 2-slot OUTH2 (output precision) ----
  {
    dim3 g((NB * NT) / 128, VOCP / 128);
    gemm128<false, true><<<g, 256, 0, stream>>>(
        OUTH2, KCL, Wcls2t, KCLO, out_repr, VOC, b_cls, VOC, KCL);
  }
}

// Round 16
// 2770.435 us; speedup vs baseline: 1.9340x; 1.0327x over previous
//
#include <hip/hip_runtime.h>
#include <math.h>

namespace {

constexpr int NB  = 256;
constexpr int NT  = 20;
constexpr int NR  = 100;
constexpr int IND = 300;
constexpr int NH  = 1024;
constexpr int VD  = 2048;
constexpr int H4  = 4096;
constexpr int VOC = 10000;
constexpr int VOCP = 10112;   // vocab padded to 128

// ALL activations and weights plain bf16-hi (1-slot), rows swizzled by
// Frow(row&15)<<3 on the 8-elem slot index (gload-linear LDS + XOR read).
constexpr int KGV = 2368;     // gates_v: hc1024 + hv1024 + x300 -> pad 2368
constexpr int KGC = 4096;     // gates_c: feat2048 + hv1024 + hc1024
constexpr int KHA = 1024;
constexpr int KCL = 1024;     // classifier (1-slot both sides)
constexpr int KFM = 2048;     // FMG/VINP from FM16
constexpr int NVI = 384;      // VINP N padded to 3*128
constexpr int A2VLD = 2048;   // A2v row: [h_c(1024) | h_v(1024)]; x-seg from X2
constexpr int X2LD  = 320;    // 300 payload + 20 zero pad

constexpr int ZGV = 8;  constexpr int KSV = 320;   // 7x320 + 128
constexpr int ZGC = 8;  constexpr int KSC = 512;
constexpr int ZHA = 8;  constexpr int KSH = 128;
constexpr int ZFM = 8;  constexpr int KSF = 256;

typedef short  s8v  __attribute__((ext_vector_type(8)));
typedef float  f4v  __attribute__((ext_vector_type(4)));

__device__ __forceinline__ float sigm(float x) { return 1.f / (1.f + expf(-x)); }
__device__ __forceinline__ unsigned short f2b(float x) {
  return __builtin_bit_cast(unsigned short, (__bf16)x);
}
__device__ __forceinline__ float b2f(unsigned short u) {
  return (float)__builtin_bit_cast(__bf16, u);
}
__device__ __forceinline__ int Frow(int row) { return (row ^ (row >> 2)) & 3; }
__device__ __forceinline__ void store1(unsigned short* rowbase, int k, float x, int Fs) {
  rowbase[k ^ Fs] = f2b(x);
}

__device__ __forceinline__ void gload16(const unsigned short* g, unsigned short* l) {
  __builtin_amdgcn_global_load_lds(
      (const __attribute__((address_space(1))) void*)g,
      (__attribute__((address_space(3))) void*)l, 16, 0, 0);
}

#define BARRIER()  __syncthreads()
#define VMWAIT0()  asm volatile("s_waitcnt vmcnt(0)" ::: "memory")

// =================== 128x128 bf16 MFMA GEMM, 2-phase dbuf (plain A+B) ===========
template<bool OUT_BF16>
__global__ __launch_bounds__(256)
void gemm128(const unsigned short* __restrict__ A, int lda,
             const unsigned short* __restrict__ Bt, int ldb,
             void* __restrict__ Cv, int ldc,
             const float* __restrict__ bias,
             int N, int Kp)
{
  __shared__ unsigned short As[2][128 * 32];
  __shared__ unsigned short Bs[2][128 * 32];
  const int tid = threadIdx.x, wid = tid >> 6, lane = tid & 63;
  const int wm = (wid >> 1) * 64, wn = (wid & 1) * 64;
  const int m0 = blockIdx.x * 128, n0 = blockIdx.y * 128;
  const int sr = tid >> 2, sc = (tid & 3) * 8;
  const unsigned short* a0 = A + (size_t)(m0 + sr) * lda + sc;
  const unsigned short* a1 = a0 + (size_t)64 * lda;
  const unsigned short* b0 = Bt + (size_t)(n0 + sr) * ldb + sc;
  const unsigned short* b1 = b0 + (size_t)64 * ldb;
  const int rr = lane & 15;
  const int kc = (((lane >> 4) ^ Frow(rr)) & 3) * 8;

  f4v acc[4][4] = {};

  auto stage = [&](int s, int k) {
    gload16(a0 + k, &As[s][tid * 8]);
    gload16(a1 + k, &As[s][2048 + tid * 8]);
    gload16(b0 + k, &Bs[s][tid * 8]);
    gload16(b1 + k, &Bs[s][2048 + tid * 8]);
  };
  auto compute = [&](int s) {
    s8v a[4], b[4];
#pragma unroll
    for (int i = 0; i < 4; ++i) a[i] = *(const s8v*)&As[s][(wm + i * 16 + rr) * 32 + kc];
#pragma unroll
    for (int j = 0; j < 4; ++j) b[j] = *(const s8v*)&Bs[s][(wn + j * 16 + rr) * 32 + kc];
#pragma unroll
    for (int i = 0; i < 4; ++i)
#pragma unroll
      for (int j = 0; j < 4; ++j)
        acc[i][j] = __builtin_amdgcn_mfma_f32_16x16x32_bf16(a[i], b[j], acc[i][j], 0, 0, 0);
  };

  stage(0, 0);
  VMWAIT0();
  BARRIER();

  int cur = 0;
  for (int k0 = 0; k0 < Kp; k0 += 32) {
    if (k0 + 32 < Kp) stage(cur ^ 1, k0 + 32);
    compute(cur);
    VMWAIT0();
    BARRIER();
    cur ^= 1;
  }

  const int cr = (lane >> 4) * 4, cc = lane & 15;
#pragma unroll
  for (int i = 0; i < 4; ++i) {
#pragma unroll
    for (int j = 0; j < 4; ++j) {
      const int gn = n0 + wn + j * 16 + cc;
      if (gn >= N) continue;
#pragma unroll
      for (int r = 0; r < 4; ++r) {
        const int gm = m0 + wm + i * 16 + cr + r;
        float v = acc[i][j][r] + bias[gn];
        if constexpr (OUT_BF16) ((unsigned short*)Cv)[(size_t)gm * ldc + gn] = f2b(v);
        else                    ((float*)Cv)[(size_t)gm * ldc + gn] = v;
      }
    }
  }
}

// =================== split-K GEMM, plain bf16 A+B (both gload, swizzled) ========
template<bool XSEG>
__global__ __launch_bounds__(256)
void gemm_sk2(const unsigned short* __restrict__ A, int lda,
              const unsigned short* __restrict__ X2, int t,
              const unsigned short* __restrict__ Bt, int ldb,
              float* __restrict__ P, int N, int Kp, int Ksplit)
{
  __shared__ unsigned short As[2][128 * 32];
  __shared__ unsigned short Bs[2][128 * 32];
  const int tid = threadIdx.x, wid = tid >> 6, lane = tid & 63;
  const int wm = (wid >> 1) * 64, wn = (wid & 1) * 64;
  const int m0 = blockIdx.y * 128, n0 = blockIdx.x * 128;
  const int kbeg = blockIdx.z * Ksplit;
  const int kend = min(Kp, kbeg + Ksplit);
  const int sr = tid >> 2, sc = (tid & 3) * 8;
  const unsigned short* a0 = A + (size_t)(m0 + sr) * lda + sc;
  const unsigned short* a1 = a0 + (size_t)64 * lda;
  const unsigned short* x0 = nullptr;
  const unsigned short* x1 = nullptr;
  if constexpr (XSEG) {
    x0 = X2 + ((size_t)(m0 + sr) * NT + t) * X2LD + sc;
    x1 = x0 + (size_t)64 * NT * X2LD;
  }
  const unsigned short* b0 = Bt + (size_t)(n0 + sr) * ldb + sc;
  const unsigned short* b1 = b0 + (size_t)64 * ldb;
  const int rr = lane & 15;
  const int kc = (((lane >> 4) ^ Frow(rr)) & 3) * 8;

  f4v acc[4][4] = {};

  auto stage = [&](int s, int k) {
    if constexpr (XSEG) {
      if (k >= A2VLD) {
        gload16(x0 + (k - A2VLD), &As[s][tid * 8]);
        gload16(x1 + (k - A2VLD), &As[s][2048 + tid * 8]);
      } else {
        gload16(a0 + k, &As[s][tid * 8]);
        gload16(a1 + k, &As[s][2048 + tid * 8]);
      }
    } else {
      gload16(a0 + k, &As[s][tid * 8]);
      gload16(a1 + k, &As[s][2048 + tid * 8]);
    }
    gload16(b0 + k, &Bs[s][tid * 8]);
    gload16(b1 + k, &Bs[s][2048 + tid * 8]);
  };
  auto compute = [&](int s) {
    s8v a[4], b[4];
#pragma unroll
    for (int i = 0; i < 4; ++i) a[i] = *(const s8v*)&As[s][(wm + i * 16 + rr) * 32 + kc];
#pragma unroll
    for (int j = 0; j < 4; ++j) b[j] = *(const s8v*)&Bs[s][(wn + j * 16 + rr) * 32 + kc];
#pragma unroll
    for (int i = 0; i < 4; ++i)
#pragma unroll
      for (int j = 0; j < 4; ++j)
        acc[i][j] = __builtin_amdgcn_mfma_f32_16x16x32_bf16(a[i], b[j], acc[i][j], 0, 0, 0);
  };

  stage(0, kbeg);
  VMWAIT0();
  BARRIER();

  int cur = 0;
  for (int k0 = kbeg; k0 < kend; k0 += 32) {
    if (k0 + 32 < kend) stage(cur ^ 1, k0 + 32);
    compute(cur);
    VMWAIT0();
    BARRIER();
    cur ^= 1;
  }

  float* out = P + (size_t)blockIdx.z * 256 * N;
  const int cr = (lane >> 4) * 4, cc = lane & 15;
#pragma unroll
  for (int i = 0; i < 4; ++i)
#pragma unroll
    for (int j = 0; j < 4; ++j)
#pragma unroll
      for (int r = 0; r < 4; ++r)
        out[(size_t)(m0 + wm + i * 16 + cr + r) * N + n0 + wn + j * 16 + cc] = acc[i][j][r];
}

// =================== 128x128 VA fallback (fp32 A converted on stage) ============
__global__ __launch_bounds__(256)
void gemm_va_f32(const float* __restrict__ A, int lda,
                 const unsigned short* __restrict__ Bt, int ldb,
                 unsigned short* __restrict__ C, int ldc,
                 const float* __restrict__ bias, int N, int Kp)
{
  __shared__ unsigned short As[128 * 32];
  __shared__ unsigned short Bs[128 * 32];
  const int tid = threadIdx.x, wid = tid >> 6, lane = tid & 63;
  const int wm = (wid >> 1) * 64, wn = (wid & 1) * 64;
  const int m0 = blockIdx.x * 128, n0 = blockIdx.y * 128;
  const unsigned short* bsrc0 = Bt + (size_t)(n0 + (tid >> 2)) * ldb + (tid & 3) * 8;
  const unsigned short* bsrc1 = bsrc0 + (size_t)64 * ldb;
  const int rr = lane & 15;
  const int kc = (((lane >> 4) ^ Frow(rr)) & 3) * 8;

  f4v acc[4][4] = {};
  for (int k0 = 0; k0 < Kp; k0 += 32) {
#pragma unroll
    for (int it = 0; it < 4; ++it) {
      const int r = it * 32 + (tid >> 3), c = (tid & 7) * 4;
      const float4 v = *(const float4*)(A + (size_t)(m0 + r) * lda + k0 + c);
      ushort4 w;
      w.x = f2b(v.x); w.y = f2b(v.y); w.z = f2b(v.z); w.w = f2b(v.w);
      *(ushort4*)&As[r * 32 + (c ^ (Frow(r & 15) << 3))] = w;
    }
    gload16(bsrc0 + k0, &Bs[tid * 8]);
    gload16(bsrc1 + k0, &Bs[2048 + tid * 8]);
    __syncthreads();
    s8v a[4], b[4];
#pragma unroll
    for (int i = 0; i < 4; ++i) a[i] = *(const s8v*)&As[(wm + i * 16 + rr) * 32 + kc];
#pragma unroll
    for (int j = 0; j < 4; ++j) b[j] = *(const s8v*)&Bs[(wn + j * 16 + rr) * 32 + kc];
#pragma unroll
    for (int i = 0; i < 4; ++i)
#pragma unroll
      for (int j = 0; j < 4; ++j)
        acc[i][j] = __builtin_amdgcn_mfma_f32_16x16x32_bf16(a[i], b[j], acc[i][j], 0, 0, 0);
    __syncthreads();
  }
  const int cr = (lane >> 4) * 4, cc = lane & 15;
#pragma unroll
  for (int i = 0; i < 4; ++i)
#pragma unroll
    for (int j = 0; j < 4; ++j) {
      const int gn = n0 + wn + j * 16 + cc;
      if (gn >= N) continue;
#pragma unroll
      for (int r = 0; r < 4; ++r)
        C[(size_t)(m0 + wm + i * 16 + cr + r) * ldc + gn] = f2b(acc[i][j][r] + bias[gn]);
    }
}

// =================== weight transpose+convert (swizzled bf16-hi) ================
__global__ void convB_k(const float* __restrict__ src, int srcld, int K, int N,
                        unsigned short* __restrict__ dst, int dstld, int coff)
{
  __shared__ float t[32][33];
  const int kb = blockIdx.x * 32, nb = blockIdx.y * 32;
  const int tx = threadIdx.x & 31, ty = threadIdx.x >> 5;
#pragma unroll
  for (int i = 0; i < 32; i += 8) {
    const int k = kb + ty + i, n = nb + tx;
    t[ty + i][tx] = (k < K && n < N) ? src[(size_t)k * srcld + n] : 0.f;
  }
  __syncthreads();
#pragma unroll
  for (int i = 0; i < 32; i += 8) {
    const int n = nb + ty + i, k = kb + tx;
    if (n >= N || k >= K) continue;
    unsigned short* row = dst + (size_t)n * dstld;
    row[(coff + k) ^ (Frow(n & 15) << 3)] = f2b(t[tx][ty + i]);
  }
}

// zero swizzled columns [c0, ld)
__global__ void zpad_swz_k(unsigned short* __restrict__ dst, int ld, int c0, int N)
{
  const int w = ld - c0;
  const int idx = blockIdx.x * 256 + threadIdx.x;
  if (idx >= N * w) return;
  const int n = idx / w, c = c0 + (idx % w);
  dst[(size_t)n * ld + (c ^ (Frow(n & 15) << 3))] = 0;
}

__global__ void zfill_k(unsigned short* __restrict__ p, int n)
{
  const int i = blockIdx.x * 256 + threadIdx.x;
  if (i < n) p[i] = 0;
}

// ============ fused feature pass: mean(bf16 swizzled) + feat bf16 convert =======
__global__ void feat_pass_k(const float* __restrict__ feat,
                            unsigned short* __restrict__ fm16,
                            unsigned short* __restrict__ f16out)
{
  const int idx = blockIdx.x * 256 + threadIdx.x;   // NB * VD/8
  if (idx >= NB * (VD / 8)) return;
  const int d0 = (idx & (VD / 8 - 1)) * 8, b = idx / (VD / 8);
  const float* base = feat + (size_t)b * NR * VD + d0;
  float s[8] = {};
  for (int r = 0; r < NR; ++r) {
    const float4 x0 = *(const float4*)(base + (size_t)r * VD);
    const float4 x1 = *(const float4*)(base + (size_t)r * VD + 4);
    s[0] += x0.x; s[1] += x0.y; s[2] += x0.z; s[3] += x0.w;
    s[4] += x1.x; s[5] += x1.y; s[6] += x1.z; s[7] += x1.w;
    if (f16out) {
      unsigned short w[8] = {f2b(x0.x), f2b(x0.y), f2b(x0.z), f2b(x0.w),
                             f2b(x1.x), f2b(x1.y), f2b(x1.z), f2b(x1.w)};
      const int ro = b * NR + r;
      *(s8v*)(f16out + (size_t)ro * VD + (d0 ^ (Frow(ro & 15) << 3))) = *(const s8v*)w;
    }
  }
  unsigned short w[8];
#pragma unroll
  for (int e = 0; e < 8; ++e) w[e] = f2b(s[e] * (1.f / NR));
  *(s8v*)(fm16 + (size_t)b * KFM + (d0 ^ (Frow(b & 15) << 3))) = *(const s8v*)w;
}

// FMG = b_v + sum_z GP[z]
__global__ void fmg_red_k(const float* __restrict__ gp, const float* __restrict__ bv,
                          float* __restrict__ fmg)
{
  const int idx = blockIdx.x * 256 + threadIdx.x;   // NB*H4
  if (idx >= NB * H4) return;
  float s = bv[idx & (H4 - 1)];
#pragma unroll
  for (int z = 0; z < ZFM; ++z) s += gp[(size_t)z * NB * H4 + idx];
  fmg[idx] = s;
}

// VINP = b_vin + sum_z GP[z] (N=NVI partials, keep n<IND)
__global__ void vinp_red_k(const float* __restrict__ gp, const float* __restrict__ bvin,
                           float* __restrict__ vinp)
{
  const int idx = blockIdx.x * 256 + threadIdx.x;   // NB*IND
  if (idx >= NB * IND) return;
  const int n = idx % IND, b = idx / IND;
  float s = bvin[n];
#pragma unroll
  for (int z = 0; z < ZFM; ++z) s += gp[(size_t)z * NB * NVI + (size_t)b * NVI + n];
  vinp[idx] = s;
}

// X2: plain bf16-hi, swizzled by F(b); payload d<300
__global__ void build_x2_k(const int* __restrict__ cap, const float* __restrict__ emb,
                           const float* __restrict__ vinp, unsigned short* __restrict__ X2)
{
  const int idx = blockIdx.x * 256 + threadIdx.x;
  if (idx >= NB * NT * X2LD) return;
  const int c = idx % X2LD;
  const int bt = idx / X2LD;
  const int t = bt % NT, b = bt / NT;
  const int Fs = Frow(b & 15) << 3;
  unsigned short val = 0;
  if (c < IND) {
    const float v = (t == 0) ? vinp[b * IND + c]
                             : emb[(size_t)cap[b * (NT - 1) + (t - 1)] * IND + c];
    val = f2b(v);
  }
  X2[(size_t)bt * X2LD + (c ^ Fs)] = val;
}

__global__ void lstm_pw_v_k(const float* __restrict__ gp, const float* __restrict__ fmg,
                            float* __restrict__ cv,
                            unsigned short* __restrict__ A2c, unsigned short* __restrict__ A2v)
{
  const int idx = blockIdx.x * 256 + threadIdx.x;
  if (idx >= NB * NH) return;
  const int n = idx & (NH - 1), b = idx >> 10;
  const size_t base = (size_t)b * H4;
  float gi = fmg[base + n], gf = fmg[base + NH + n];
  float gg = fmg[base + 2 * NH + n], go = fmg[base + 3 * NH + n];
#pragma unroll
  for (int z = 0; z < ZGV; ++z) {
    const float* g = gp + (size_t)z * NB * H4 + base;
    gi += g[n]; gf += g[NH + n]; gg += g[2 * NH + n]; go += g[3 * NH + n];
  }
  const float c2 = sigm(gf) * cv[idx] + sigm(gi) * tanhf(gg);
  const float h2 = sigm(go) * tanhf(c2);
  cv[idx] = c2;
  const int Fs = Frow(b & 15) << 3;
  store1(A2c + (size_t)b * KGC, 2048 + n, h2, Fs);
  store1(A2v + (size_t)b * A2VLD, 1024 + n, h2, Fs);
}

__global__ void lstm_pw_c_k(const float* __restrict__ gp, const float* __restrict__ bc,
                            float* __restrict__ cc,
                            unsigned short* __restrict__ A2v, unsigned short* __restrict__ A2c,
                            unsigned short* __restrict__ outh2, int t)
{
  const int idx = blockIdx.x * 256 + threadIdx.x;
  if (idx >= NB * NH) return;
  const int n = idx & (NH - 1), b = idx >> 10;
  const size_t base = (size_t)b * H4;
  float gi = bc[n], gf = bc[NH + n], gg = bc[2 * NH + n], go = bc[3 * NH + n];
#pragma unroll
  for (int z = 0; z < ZGC; ++z) {
    const float* g = gp + (size_t)z * NB * H4 + base;
    gi += g[n]; gf += g[NH + n]; gg += g[2 * NH + n]; go += g[3 * NH + n];
  }
  const float c2 = sigm(gf) * cc[idx] + sigm(gi) * tanhf(gg);
  const float h2 = sigm(go) * tanhf(c2);
  cc[idx] = c2;
  const int Fs = Frow(b & 15) << 3;
  store1(A2v + (size_t)b * A2VLD, n, h2, Fs);
  store1(A2c + (size_t)b * KGC, 3072 + n, h2, Fs);
  const int ro = b * NT + t;
  store1(outh2 + (size_t)ro * KCL, n, h2, Frow(ro & 15) << 3);
}

// =================== fused attention: ha-reduce + logits + softmax + feat_hat ===
template<bool F16>
__global__ __launch_bounds__(512)
void att_fused_k(const unsigned short* __restrict__ va16,
                 const float* __restrict__ hap,   // [ZHA][NB][NH]
                 const float* __restrict__ bha,
                 const float* __restrict__ Wa, const float* __restrict__ ba,
                 const unsigned short* __restrict__ f16,
                 const float* __restrict__ f32,
                 unsigned short* __restrict__ A2c,
                 float* __restrict__ att_out, int t)
{
  const int b = blockIdx.x, tid = threadIdx.x;
  const int lane = tid & 63, wid = tid >> 6;
  __shared__ float ha_s[NH];
  __shared__ float wa_s[NH];
  __shared__ float red_s[128];
  __shared__ float fh_s[2][VD];

  for (int j = tid; j < NH; j += 512) {
    float s = bha[j];
#pragma unroll
    for (int z = 0; z < ZHA; ++z) s += hap[((size_t)z * NB + b) * NH + j];
    ha_s[j] = s;
    wa_s[j] = Wa[j];
  }
  __syncthreads();

  for (int r = wid; r < NR; r += 8) {
    const unsigned short* vrow = va16 + ((size_t)b * NR + r) * NH + lane * 16;
    float s = 0.f;
#pragma unroll
    for (int u = 0; u < 2; ++u) {
      const s8v v = *(const s8v*)(vrow + u * 8);
      const int j0 = lane * 16 + u * 8;
#pragma unroll
      for (int e = 0; e < 8; ++e)
        s += tanhf(b2f((unsigned short)v[e]) + ha_s[j0 + e]) * wa_s[j0 + e];
    }
    for (int o = 32; o; o >>= 1) s += __shfl_down(s, o);
    if (lane == 0) red_s[r] = s + ba[0];
  }
  __syncthreads();

  if (wid == 0) {
    float v0 = (lane < NR) ? red_s[lane] : -3.4e38f;
    float v1 = (lane + 64 < NR) ? red_s[lane + 64] : -3.4e38f;
    float m = fmaxf(v0, v1);
    for (int o = 32; o; o >>= 1) m = fmaxf(m, __shfl_xor(m, o));
    const float e0 = (lane < NR) ? expf(v0 - m) : 0.f;
    const float e1 = (lane + 64 < NR) ? expf(v1 - m) : 0.f;
    float s = e0 + e1;
    for (int o = 32; o; o >>= 1) s += __shfl_xor(s, o);
    const float inv = 1.f / s;
    if (lane < NR) red_s[lane] = e0 * inv;
    if (lane + 64 < NR) red_s[lane + 64] = e1 * inv;
  }
  __syncthreads();
  if (tid < NR) att_out[((size_t)b * NT + t) * NR + tid] = red_s[tid];

  // feat_hat: split rows across 2 thread-halves; 8 d's (16B) per thread
  const int half = tid >> 8;
  const int dd = (tid & 255) * 8;
  const int r0 = half * 50, r1 = r0 + 50;
  float fh8[8] = {};
  if constexpr (F16) {
    const unsigned short* fbase = f16 + (size_t)b * NR * VD;
    for (int r = r0; r < r1; ++r) {
      const int ro = b * NR + r;
      const s8v f = *(const s8v*)(fbase + (size_t)r * VD + (dd ^ (Frow(ro & 15) << 3)));
      const float a = red_s[r];
#pragma unroll
      for (int e = 0; e < 8; ++e) fh8[e] += a * b2f((unsigned short)f[e]);
    }
  } else {
    const float* fb = f32 + (size_t)b * NR * VD + dd;
    for (int r = r0; r < r1; ++r) {
      const float4 x0 = *(const float4*)(fb + (size_t)r * VD);
      const float4 x1 = *(const float4*)(fb + (size_t)r * VD + 4);
      const float a = red_s[r];
      fh8[0] += a * x0.x; fh8[1] += a * x0.y; fh8[2] += a * x0.z; fh8[3] += a * x0.w;
      fh8[4] += a * x1.x; fh8[5] += a * x1.y; fh8[6] += a * x1.z; fh8[7] += a * x1.w;
    }
  }
#pragma unroll
  for (int e = 0; e < 8; ++e) fh_s[half][dd + e] = fh8[e];
  __syncthreads();

  unsigned short* rowbase = A2c + (size_t)b * KGC;
  const int Fs = Frow(b & 15) << 3;
  const int d0 = tid * 4;
#pragma unroll
  for (int e = 0; e < 4; ++e) {
    const float v = (fh_s[0][d0 + e] + fh_s[1][d0 + e]) * (1.f / NR);
    store1(rowbase, d0 + e, v, Fs);
  }
}

inline void convB(hipStream_t st, const float* src, int srcld, int K, int N,
                  unsigned short* dst, int dstld, int coff)
{
  dim3 g((K + 31) / 32, (N + 31) / 32);
  convB_k<<<g, 256, 0, st>>>(src, srcld, K, N, dst, dstld, coff);
}

} // namespace

extern "C" void kernel_launch(void* const* d_in, const int* in_sizes, int n_in,
                              void* d_out, int out_size, void* d_ws, size_t ws_size,
                              hipStream_t stream)
{
  const int*   caption = (const int*)  d_in[0];
  const float* feat    = (const float*)d_in[1];
  const float* emb     = (const float*)d_in[2];
  const float* W_vin   = (const float*)d_in[3];
  const float* b_vin   = (const float*)d_in[4];
  const float* W_ih_v  = (const float*)d_in[5];
  const float* W_hh_v  = (const float*)d_in[6];
  const float* b_v     = (const float*)d_in[7];
  const float* W_va    = (const float*)d_in[8];
  const float* b_va    = (const float*)d_in[9];
  const float* W_ha    = (const float*)d_in[10];
  const float* b_ha    = (const float*)d_in[11];
  const float* W_a     = (const float*)d_in[12];
  const float* b_a     = (const float*)d_in[13];
  const float* W_ih_c  = (const float*)d_in[14];
  const float* W_hh_c  = (const float*)d_in[15];
  const float* b_c     = (const float*)d_in[16];
  const float* W_cls   = (const float*)d_in[17];
  const float* b_cls   = (const float*)d_in[18];

  float* out_repr = (float*)d_out;                       // [NB,NT,VOC]
  float* out_att  = out_repr + (size_t)NB * NT * VOC;    // [NB,NT,NR]

  char* cur = (char*)d_ws;
  auto take = [&](size_t bytes) { char* p = cur; cur += bytes; return p; };

  unsigned short* A2v  = (unsigned short*)take((size_t)NB * A2VLD * 2);      // 1MB
  unsigned short* A2c  = (unsigned short*)take((size_t)NB * KGC * 2);        // 2MB
  float* CV            = (float*)take((size_t)NB * NH * 4);
  float* CC            = (float*)take((size_t)NB * NH * 4);
  const size_t ZERO_BYTES = (size_t)NB * A2VLD * 2 + (size_t)NB * KGC * 2
                          + 2 * (size_t)NB * NH * 4;

  float* VINP          = (float*)take((size_t)NB * IND * 4);
  unsigned short* X2   = (unsigned short*)take((size_t)NB * NT * X2LD * 2);  // 3.3MB
  float* FMG           = (float*)take((size_t)NB * H4 * 4);
  unsigned short* FM16 = (unsigned short*)take((size_t)NB * KFM * 2);        // 1MB
  unsigned short* VA16 = (unsigned short*)take((size_t)NB * NR * NH * 2);    // 52MB
  float* GP            = (float*)take((size_t)ZGC * NB * H4 * 4);            // 33.5MB
  float* HAP           = (float*)take((size_t)ZHA * NB * NH * 4);            // 8.4MB
  unsigned short* OUTH2= (unsigned short*)take((size_t)NB * NT * KCL * 2);   // 10.5MB
  unsigned short* Wgv2t= (unsigned short*)take((size_t)H4 * KGV * 2);        // 19.4MB
  unsigned short* Wha2t= (unsigned short*)take((size_t)NH * KHA * 2);        // 2.1MB
  unsigned short* Wgc2t= (unsigned short*)take((size_t)H4 * KGC * 2);        // 33.5MB
  unsigned short* Wfmg = (unsigned short*)take((size_t)H4 * KFM * 2);        // 16.8MB
  unsigned short* WvinT= (unsigned short*)take((size_t)NVI * KFM * 2);       // 1.6MB
  unsigned short* Wcls2t=(unsigned short*)take((size_t)VOCP * KCL * 2);      // 20.7MB
  unsigned short* Wva16t=(unsigned short*)take((size_t)NH * VD * 2);         // 4.2MB
  unsigned short* FEAT16=(unsigned short*)cur;                               // 105MB optional
  const bool useF16 = ((size_t)(cur - (char*)d_ws) + (size_t)NB * NR * VD * 2) <= ws_size;

  hipMemsetAsync(A2v, 0, ZERO_BYTES, stream);

  // ---- weight conversions (all swizzled bf16-hi) ----
  convB(stream, W_ih_v + (size_t)2048 * H4, H4, 1024, H4, Wgv2t, KGV, 0);
  convB(stream, W_hh_v,                     H4, 1024, H4, Wgv2t, KGV, 1024);
  convB(stream, W_ih_v + (size_t)3072 * H4, H4, 300,  H4, Wgv2t, KGV, 2048);
  zpad_swz_k<<<((H4 * (KGV - 2348)) + 255) / 256, 256, 0, stream>>>(
      Wgv2t, KGV, 2348, H4);
  convB(stream, W_ha, NH, 1024, NH, Wha2t, KHA, 0);
  convB(stream, W_ih_c,                     H4, 2048, H4, Wgc2t, KGC, 0);
  convB(stream, W_ih_c + (size_t)2048 * H4, H4, 1024, H4, Wgc2t, KGC, 2048);
  convB(stream, W_hh_c,                     H4, 1024, H4, Wgc2t, KGC, 3072);
  convB(stream, W_ih_v,                     H4, 2048, H4, Wfmg,  KFM, 0);
  convB(stream, W_vin, IND, 2048, IND, WvinT, KFM, 0);
  zfill_k<<<(((NVI - IND) * KFM) + 255) / 256, 256, 0, stream>>>(
      WvinT + (size_t)IND * KFM, (NVI - IND) * KFM);
  convB(stream, W_cls, VOC, 1024, VOC, Wcls2t, KCL, 0);
  zfill_k<<<(((VOCP - VOC) * KCL) + 255) / 256, 256, 0, stream>>>(
      Wcls2t + (size_t)VOC * KCL, (VOCP - VOC) * KCL);
  convB(stream, W_va, NH, VD, NH, Wva16t, VD, 0);

  // ---- setup ----
  feat_pass_k<<<(NB * (VD / 8) + 255) / 256, 256, 0, stream>>>(
      feat, FM16, useF16 ? FEAT16 : nullptr);
  // VINP via MFMA split-K
  gemm_sk2<false><<<dim3(NVI / 128, 2, ZFM), 256, 0, stream>>>(
      FM16, KFM, nullptr, 0, WvinT, KFM, GP, NVI, KFM, KSF);
  vinp_red_k<<<(NB * IND + 255) / 256, 256, 0, stream>>>(GP, b_vin, VINP);
  build_x2_k<<<(NB * NT * X2LD + 255) / 256, 256, 0, stream>>>(caption, emb, VINP, X2);
  // FMG via MFMA split-K
  gemm_sk2<false><<<dim3(H4 / 128, 2, ZFM), 256, 0, stream>>>(
      FM16, KFM, nullptr, 0, Wfmg, KFM, GP, H4, KFM, KSF);
  fmg_red_k<<<(NB * H4 + 255) / 256, 256, 0, stream>>>(GP, b_v, FMG);
  if (useF16) {
    dim3 g((NB * NR) / 128, NH / 128);
    gemm128<true><<<g, 256, 0, stream>>>(
        FEAT16, VD, Wva16t, VD, VA16, NH, b_va, NH, VD);
  } else {
    dim3 g((NB * NR) / 128, NH / 128);
    gemm_va_f32<<<g, 256, 0, stream>>>(feat, VD, Wva16t, VD, VA16, NH, b_va, NH, VD);
  }

  // ---- sequential decode ----
  for (int t = 0; t < NT; ++t) {
    gemm_sk2<true><<<dim3(H4 / 128, 2, ZGV), 256, 0, stream>>>(
        A2v, A2VLD, X2, t, Wgv2t, KGV, GP, H4, KGV, KSV);
    lstm_pw_v_k<<<(NB * NH + 255) / 256, 256, 0, stream>>>(GP, FMG, CV, A2c, A2v);
    gemm_sk2<false><<<dim3(NH / 128, 2, ZHA), 256, 0, stream>>>(
        A2c + 2048, KGC, nullptr, 0, Wha2t, KHA, HAP, NH, KHA, KSH);
    if (useF16)
      att_fused_k<true><<<NB, 512, 0, stream>>>(
          VA16, HAP, b_ha, W_a, b_a, FEAT16, nullptr, A2c, out_att, t);
    else
      att_fused_k<false><<<NB, 512, 0, stream>>>(
          VA16, HAP, b_ha, W_a, b_a, nullptr, feat, A2c, out_att, t);
    gemm_sk2<false><<<dim3(H4 / 128, 2, ZGC), 256, 0, stream>>>(
        A2c, KGC, nullptr, 0, Wgc2t, KGC, GP, H4, KGC, KSC);
    lstm_pw_c_k<<<(NB * NH + 255) / 256, 256, 0, stream>>>(GP, b_c, CC, A2v, A2c, OUTH2, t);
  }

  // ---- classifier: 128x128 tiles, plain bf16 both sides, K=1024 ----
  {
    dim3 g((NB * NT) / 128, VOCP / 128);
    gemm128<false><<<g, 256, 0, stream>>>(
        OUTH2, KCL, Wcls2t, KCL, out_repr, VOC, b_cls, VOC, KCL);
  }
}

// Round 17
// 2745.830 us; speedup vs baseline: 1.9513x; 1.0090x over previous
//
#include <hip/hip_runtime.h>
#include <math.h>

namespace {

constexpr int NB  = 256;
constexpr int NT  = 20;
constexpr int NR  = 100;
constexpr int IND = 300;
constexpr int NH  = 1024;
constexpr int VD  = 2048;
constexpr int H4  = 4096;
constexpr int VOC = 10000;
constexpr int VOCP = 10112;   // vocab padded to 128

// ALL activations and weights plain bf16-hi (1-slot), rows swizzled by
// Frow(row&15)<<3 on the 8-elem slot index (gload-linear LDS + XOR read).
constexpr int KGV = 2368;     // gates_v: hc1024 + hv1024 + x300 -> pad 2368
constexpr int KGC = 4096;     // gates_c: feat2048 + hv1024 + hc1024
constexpr int KHA = 1024;
constexpr int KCL = 1024;     // classifier (1-slot both sides)
constexpr int KFM = 2048;     // FMG/VINP from FM16
constexpr int NVI = 384;      // VINP N padded to 3*128
constexpr int A2VLD = 2048;   // A2v row: [h_c(1024) | h_v(1024)]; x-seg from X2
constexpr int X2LD  = 320;    // 300 payload + 20 zero pad

// per-step GEMMs: BN=64, Z=4 -> same 512 blocks (2/CU) but HALF the fp32
// partial traffic (was the hidden ~20us/step cost). ha: BN=64, Z=8 -> 1/CU.
constexpr int ZGV = 4;  constexpr int KSV = 608;   // 3x608 + 544
constexpr int ZGC = 4;  constexpr int KSC = 1024;
constexpr int ZHA = 8;  constexpr int KSH = 128;
constexpr int ZFM = 8;  constexpr int KSF = 256;   // setup (BN=128)

typedef short  s8v  __attribute__((ext_vector_type(8)));
typedef float  f4v  __attribute__((ext_vector_type(4)));

__device__ __forceinline__ float sigm(float x) { return 1.f / (1.f + expf(-x)); }
__device__ __forceinline__ unsigned short f2b(float x) {
  return __builtin_bit_cast(unsigned short, (__bf16)x);
}
__device__ __forceinline__ float b2f(unsigned short u) {
  return (float)__builtin_bit_cast(__bf16, u);
}
__device__ __forceinline__ int Frow(int row) { return (row ^ (row >> 2)) & 3; }
__device__ __forceinline__ void store1(unsigned short* rowbase, int k, float x, int Fs) {
  rowbase[k ^ Fs] = f2b(x);
}

__device__ __forceinline__ void gload16(const unsigned short* g, unsigned short* l) {
  __builtin_amdgcn_global_load_lds(
      (const __attribute__((address_space(1))) void*)g,
      (__attribute__((address_space(3))) void*)l, 16, 0, 0);
}

#define BARRIER()  __syncthreads()
#define VMWAIT0()  asm volatile("s_waitcnt vmcnt(0)" ::: "memory")

// =================== 128x128 bf16 MFMA GEMM, 2-phase dbuf (plain A+B) ===========
template<bool OUT_BF16>
__global__ __launch_bounds__(256)
void gemm128(const unsigned short* __restrict__ A, int lda,
             const unsigned short* __restrict__ Bt, int ldb,
             void* __restrict__ Cv, int ldc,
             const float* __restrict__ bias,
             int N, int Kp)
{
  __shared__ unsigned short As[2][128 * 32];
  __shared__ unsigned short Bs[2][128 * 32];
  const int tid = threadIdx.x, wid = tid >> 6, lane = tid & 63;
  const int wm = (wid >> 1) * 64, wn = (wid & 1) * 64;
  const int m0 = blockIdx.x * 128, n0 = blockIdx.y * 128;
  const int sr = tid >> 2, sc = (tid & 3) * 8;
  const unsigned short* a0 = A + (size_t)(m0 + sr) * lda + sc;
  const unsigned short* a1 = a0 + (size_t)64 * lda;
  const unsigned short* b0 = Bt + (size_t)(n0 + sr) * ldb + sc;
  const unsigned short* b1 = b0 + (size_t)64 * ldb;
  const int rr = lane & 15;
  const int kc = (((lane >> 4) ^ Frow(rr)) & 3) * 8;

  f4v acc[4][4] = {};

  auto stage = [&](int s, int k) {
    gload16(a0 + k, &As[s][tid * 8]);
    gload16(a1 + k, &As[s][2048 + tid * 8]);
    gload16(b0 + k, &Bs[s][tid * 8]);
    gload16(b1 + k, &Bs[s][2048 + tid * 8]);
  };
  auto compute = [&](int s) {
    s8v a[4], b[4];
#pragma unroll
    for (int i = 0; i < 4; ++i) a[i] = *(const s8v*)&As[s][(wm + i * 16 + rr) * 32 + kc];
#pragma unroll
    for (int j = 0; j < 4; ++j) b[j] = *(const s8v*)&Bs[s][(wn + j * 16 + rr) * 32 + kc];
#pragma unroll
    for (int i = 0; i < 4; ++i)
#pragma unroll
      for (int j = 0; j < 4; ++j)
        acc[i][j] = __builtin_amdgcn_mfma_f32_16x16x32_bf16(a[i], b[j], acc[i][j], 0, 0, 0);
  };

  stage(0, 0);
  VMWAIT0();
  BARRIER();

  int cur = 0;
  for (int k0 = 0; k0 < Kp; k0 += 32) {
    if (k0 + 32 < Kp) stage(cur ^ 1, k0 + 32);
    compute(cur);
    VMWAIT0();
    BARRIER();
    cur ^= 1;
  }

  const int cr = (lane >> 4) * 4, cc = lane & 15;
#pragma unroll
  for (int i = 0; i < 4; ++i) {
#pragma unroll
    for (int j = 0; j < 4; ++j) {
      const int gn = n0 + wn + j * 16 + cc;
      if (gn >= N) continue;
#pragma unroll
      for (int r = 0; r < 4; ++r) {
        const int gm = m0 + wm + i * 16 + cr + r;
        float v = acc[i][j][r] + bias[gn];
        if constexpr (OUT_BF16) ((unsigned short*)Cv)[(size_t)gm * ldc + gn] = f2b(v);
        else                    ((float*)Cv)[(size_t)gm * ldc + gn] = v;
      }
    }
  }
}

// ========= split-K GEMM, BM=128 (grid.y), BN templated (128 or 64) ==============
// 4 waves as 2m x 2n; wave tile 64 x (BN/2); acc[4][BN/32].
template<bool XSEG, int BN>
__global__ __launch_bounds__(256)
void gemm_sk2(const unsigned short* __restrict__ A, int lda,
              const unsigned short* __restrict__ X2, int t,
              const unsigned short* __restrict__ Bt, int ldb,
              float* __restrict__ P, int N, int Kp, int Ksplit)
{
  constexpr int FN = BN / 32;   // B fragments per wave
  __shared__ unsigned short As[2][128 * 32];
  __shared__ unsigned short Bs[2][BN * 32];
  const int tid = threadIdx.x, wid = tid >> 6, lane = tid & 63;
  const int wm = (wid >> 1) * 64, wn = (wid & 1) * (BN / 2);
  const int m0 = blockIdx.y * 128, n0 = blockIdx.x * BN;
  const int kbeg = blockIdx.z * Ksplit;
  const int kend = min(Kp, kbeg + Ksplit);
  const int sr = tid >> 2, sc = (tid & 3) * 8;
  const unsigned short* a0 = A + (size_t)(m0 + sr) * lda + sc;
  const unsigned short* a1 = a0 + (size_t)64 * lda;
  const unsigned short* x0 = nullptr;
  const unsigned short* x1 = nullptr;
  if constexpr (XSEG) {
    x0 = X2 + ((size_t)(m0 + sr) * NT + t) * X2LD + sc;
    x1 = x0 + (size_t)64 * NT * X2LD;
  }
  const unsigned short* b0 = Bt + (size_t)(n0 + sr) * ldb + sc;
  const unsigned short* b1 = b0 + (size_t)64 * ldb;   // used only when BN==128
  const int rr = lane & 15;
  const int kc = (((lane >> 4) ^ Frow(rr)) & 3) * 8;

  f4v acc[4][FN] = {};

  auto stage = [&](int s, int k) {
    if constexpr (XSEG) {
      if (k >= A2VLD) {
        gload16(x0 + (k - A2VLD), &As[s][tid * 8]);
        gload16(x1 + (k - A2VLD), &As[s][2048 + tid * 8]);
      } else {
        gload16(a0 + k, &As[s][tid * 8]);
        gload16(a1 + k, &As[s][2048 + tid * 8]);
      }
    } else {
      gload16(a0 + k, &As[s][tid * 8]);
      gload16(a1 + k, &As[s][2048 + tid * 8]);
    }
    gload16(b0 + k, &Bs[s][tid * 8]);
    if constexpr (BN == 128) gload16(b1 + k, &Bs[s][2048 + tid * 8]);
  };
  auto compute = [&](int s) {
    s8v a[4], b[FN];
#pragma unroll
    for (int i = 0; i < 4; ++i) a[i] = *(const s8v*)&As[s][(wm + i * 16 + rr) * 32 + kc];
#pragma unroll
    for (int j = 0; j < FN; ++j) b[j] = *(const s8v*)&Bs[s][(wn + j * 16 + rr) * 32 + kc];
#pragma unroll
    for (int i = 0; i < 4; ++i)
#pragma unroll
      for (int j = 0; j < FN; ++j)
        acc[i][j] = __builtin_amdgcn_mfma_f32_16x16x32_bf16(a[i], b[j], acc[i][j], 0, 0, 0);
  };

  stage(0, kbeg);
  VMWAIT0();
  BARRIER();

  int cur = 0;
  for (int k0 = kbeg; k0 < kend; k0 += 32) {
    if (k0 + 32 < kend) stage(cur ^ 1, k0 + 32);
    compute(cur);
    VMWAIT0();
    BARRIER();
    cur ^= 1;
  }

  float* out = P + (size_t)blockIdx.z * 256 * N;
  const int cr = (lane >> 4) * 4, cc = lane & 15;
#pragma unroll
  for (int i = 0; i < 4; ++i)
#pragma unroll
    for (int j = 0; j < FN; ++j)
#pragma unroll
      for (int r = 0; r < 4; ++r)
        out[(size_t)(m0 + wm + i * 16 + cr + r) * N + n0 + wn + j * 16 + cc] = acc[i][j][r];
}

// =================== 128x128 VA fallback (fp32 A converted on stage) ============
__global__ __launch_bounds__(256)
void gemm_va_f32(const float* __restrict__ A, int lda,
                 const unsigned short* __restrict__ Bt, int ldb,
                 unsigned short* __restrict__ C, int ldc,
                 const float* __restrict__ bias, int N, int Kp)
{
  __shared__ unsigned short As[128 * 32];
  __shared__ unsigned short Bs[128 * 32];
  const int tid = threadIdx.x, wid = tid >> 6, lane = tid & 63;
  const int wm = (wid >> 1) * 64, wn = (wid & 1) * 64;
  const int m0 = blockIdx.x * 128, n0 = blockIdx.y * 128;
  const unsigned short* bsrc0 = Bt + (size_t)(n0 + (tid >> 2)) * ldb + (tid & 3) * 8;
  const unsigned short* bsrc1 = bsrc0 + (size_t)64 * ldb;
  const int rr = lane & 15;
  const int kc = (((lane >> 4) ^ Frow(rr)) & 3) * 8;

  f4v acc[4][4] = {};
  for (int k0 = 0; k0 < Kp; k0 += 32) {
#pragma unroll
    for (int it = 0; it < 4; ++it) {
      const int r = it * 32 + (tid >> 3), c = (tid & 7) * 4;
      const float4 v = *(const float4*)(A + (size_t)(m0 + r) * lda + k0 + c);
      ushort4 w;
      w.x = f2b(v.x); w.y = f2b(v.y); w.z = f2b(v.z); w.w = f2b(v.w);
      *(ushort4*)&As[r * 32 + (c ^ (Frow(r & 15) << 3))] = w;
    }
    gload16(bsrc0 + k0, &Bs[tid * 8]);
    gload16(bsrc1 + k0, &Bs[2048 + tid * 8]);
    __syncthreads();
    s8v a[4], b[4];
#pragma unroll
    for (int i = 0; i < 4; ++i) a[i] = *(const s8v*)&As[(wm + i * 16 + rr) * 32 + kc];
#pragma unroll
    for (int j = 0; j < 4; ++j) b[j] = *(const s8v*)&Bs[(wn + j * 16 + rr) * 32 + kc];
#pragma unroll
    for (int i = 0; i < 4; ++i)
#pragma unroll
      for (int j = 0; j < 4; ++j)
        acc[i][j] = __builtin_amdgcn_mfma_f32_16x16x32_bf16(a[i], b[j], acc[i][j], 0, 0, 0);
    __syncthreads();
  }
  const int cr = (lane >> 4) * 4, cc = lane & 15;
#pragma unroll
  for (int i = 0; i < 4; ++i)
#pragma unroll
    for (int j = 0; j < 4; ++j) {
      const int gn = n0 + wn + j * 16 + cc;
      if (gn >= N) continue;
#pragma unroll
      for (int r = 0; r < 4; ++r)
        C[(size_t)(m0 + wm + i * 16 + cr + r) * ldc + gn] = f2b(acc[i][j][r] + bias[gn]);
    }
}

// =================== weight transpose+convert (swizzled bf16-hi) ================
__global__ void convB_k(const float* __restrict__ src, int srcld, int K, int N,
                        unsigned short* __restrict__ dst, int dstld, int coff)
{
  __shared__ float t[32][33];
  const int kb = blockIdx.x * 32, nb = blockIdx.y * 32;
  const int tx = threadIdx.x & 31, ty = threadIdx.x >> 5;
#pragma unroll
  for (int i = 0; i < 32; i += 8) {
    const int k = kb + ty + i, n = nb + tx;
    t[ty + i][tx] = (k < K && n < N) ? src[(size_t)k * srcld + n] : 0.f;
  }
  __syncthreads();
#pragma unroll
  for (int i = 0; i < 32; i += 8) {
    const int n = nb + ty + i, k = kb + tx;
    if (n >= N || k >= K) continue;
    unsigned short* row = dst + (size_t)n * dstld;
    row[(coff + k) ^ (Frow(n & 15) << 3)] = f2b(t[tx][ty + i]);
  }
}

// zero swizzled columns [c0, ld)
__global__ void zpad_swz_k(unsigned short* __restrict__ dst, int ld, int c0, int N)
{
  const int w = ld - c0;
  const int idx = blockIdx.x * 256 + threadIdx.x;
  if (idx >= N * w) return;
  const int n = idx / w, c = c0 + (idx % w);
  dst[(size_t)n * ld + (c ^ (Frow(n & 15) << 3))] = 0;
}

__global__ void zfill_k(unsigned short* __restrict__ p, int n)
{
  const int i = blockIdx.x * 256 + threadIdx.x;
  if (i < n) p[i] = 0;
}

// ============ fused feature pass: mean(bf16 swizzled) + feat bf16 convert =======
__global__ void feat_pass_k(const float* __restrict__ feat,
                            unsigned short* __restrict__ fm16,
                            unsigned short* __restrict__ f16out)
{
  const int idx = blockIdx.x * 256 + threadIdx.x;   // NB * VD/8
  if (idx >= NB * (VD / 8)) return;
  const int d0 = (idx & (VD / 8 - 1)) * 8, b = idx / (VD / 8);
  const float* base = feat + (size_t)b * NR * VD + d0;
  float s[8] = {};
  for (int r = 0; r < NR; ++r) {
    const float4 x0 = *(const float4*)(base + (size_t)r * VD);
    const float4 x1 = *(const float4*)(base + (size_t)r * VD + 4);
    s[0] += x0.x; s[1] += x0.y; s[2] += x0.z; s[3] += x0.w;
    s[4] += x1.x; s[5] += x1.y; s[6] += x1.z; s[7] += x1.w;
    if (f16out) {
      unsigned short w[8] = {f2b(x0.x), f2b(x0.y), f2b(x0.z), f2b(x0.w),
                             f2b(x1.x), f2b(x1.y), f2b(x1.z), f2b(x1.w)};
      const int ro = b * NR + r;
      *(s8v*)(f16out + (size_t)ro * VD + (d0 ^ (Frow(ro & 15) << 3))) = *(const s8v*)w;
    }
  }
  unsigned short w[8];
#pragma unroll
  for (int e = 0; e < 8; ++e) w[e] = f2b(s[e] * (1.f / NR));
  *(s8v*)(fm16 + (size_t)b * KFM + (d0 ^ (Frow(b & 15) << 3))) = *(const s8v*)w;
}

// FMG = b_v + sum_z GP[z]
__global__ void fmg_red_k(const float* __restrict__ gp, const float* __restrict__ bv,
                          float* __restrict__ fmg)
{
  const int idx = blockIdx.x * 256 + threadIdx.x;   // NB*H4
  if (idx >= NB * H4) return;
  float s = bv[idx & (H4 - 1)];
#pragma unroll
  for (int z = 0; z < ZFM; ++z) s += gp[(size_t)z * NB * H4 + idx];
  fmg[idx] = s;
}

// VINP = b_vin + sum_z GP[z] (N=NVI partials, keep n<IND)
__global__ void vinp_red_k(const float* __restrict__ gp, const float* __restrict__ bvin,
                           float* __restrict__ vinp)
{
  const int idx = blockIdx.x * 256 + threadIdx.x;   // NB*IND
  if (idx >= NB * IND) return;
  const int n = idx % IND, b = idx / IND;
  float s = bvin[n];
#pragma unroll
  for (int z = 0; z < ZFM; ++z) s += gp[(size_t)z * NB * NVI + (size_t)b * NVI + n];
  vinp[idx] = s;
}

// X2: plain bf16-hi, swizzled by F(b); payload d<300
__global__ void build_x2_k(const int* __restrict__ cap, const float* __restrict__ emb,
                           const float* __restrict__ vinp, unsigned short* __restrict__ X2)
{
  const int idx = blockIdx.x * 256 + threadIdx.x;
  if (idx >= NB * NT * X2LD) return;
  const int c = idx % X2LD;
  const int bt = idx / X2LD;
  const int t = bt % NT, b = bt / NT;
  const int Fs = Frow(b & 15) << 3;
  unsigned short val = 0;
  if (c < IND) {
    const float v = (t == 0) ? vinp[b * IND + c]
                             : emb[(size_t)cap[b * (NT - 1) + (t - 1)] * IND + c];
    val = f2b(v);
  }
  X2[(size_t)bt * X2LD + (c ^ Fs)] = val;
}

__global__ void lstm_pw_v_k(const float* __restrict__ gp, const float* __restrict__ fmg,
                            float* __restrict__ cv,
                            unsigned short* __restrict__ A2c, unsigned short* __restrict__ A2v)
{
  const int idx = blockIdx.x * 256 + threadIdx.x;
  if (idx >= NB * NH) return;
  const int n = idx & (NH - 1), b = idx >> 10;
  const size_t base = (size_t)b * H4;
  float gi = fmg[base + n], gf = fmg[base + NH + n];
  float gg = fmg[base + 2 * NH + n], go = fmg[base + 3 * NH + n];
#pragma unroll
  for (int z = 0; z < ZGV; ++z) {
    const float* g = gp + (size_t)z * NB * H4 + base;
    gi += g[n]; gf += g[NH + n]; gg += g[2 * NH + n]; go += g[3 * NH + n];
  }
  const float c2 = sigm(gf) * cv[idx] + sigm(gi) * tanhf(gg);
  const float h2 = sigm(go) * tanhf(c2);
  cv[idx] = c2;
  const int Fs = Frow(b & 15) << 3;
  store1(A2c + (size_t)b * KGC, 2048 + n, h2, Fs);
  store1(A2v + (size_t)b * A2VLD, 1024 + n, h2, Fs);
}

__global__ void lstm_pw_c_k(const float* __restrict__ gp, const float* __restrict__ bc,
                            float* __restrict__ cc,
                            unsigned short* __restrict__ A2v, unsigned short* __restrict__ A2c,
                            unsigned short* __restrict__ outh2, int t)
{
  const int idx = blockIdx.x * 256 + threadIdx.x;
  if (idx >= NB * NH) return;
  const int n = idx & (NH - 1), b = idx >> 10;
  const size_t base = (size_t)b * H4;
  float gi = bc[n], gf = bc[NH + n], gg = bc[2 * NH + n], go = bc[3 * NH + n];
#pragma unroll
  for (int z = 0; z < ZGC; ++z) {
    const float* g = gp + (size_t)z * NB * H4 + base;
    gi += g[n]; gf += g[NH + n]; gg += g[2 * NH + n]; go += g[3 * NH + n];
  }
  const float c2 = sigm(gf) * cc[idx] + sigm(gi) * tanhf(gg);
  const float h2 = sigm(go) * tanhf(c2);
  cc[idx] = c2;
  const int Fs = Frow(b & 15) << 3;
  store1(A2v + (size_t)b * A2VLD, n, h2, Fs);
  store1(A2c + (size_t)b * KGC, 3072 + n, h2, Fs);
  const int ro = b * NT + t;
  store1(outh2 + (size_t)ro * KCL, n, h2, Frow(ro & 15) << 3);
}

// =================== fused attention: ha-reduce + logits + softmax + feat_hat ===
template<bool F16>
__global__ __launch_bounds__(512)
void att_fused_k(const unsigned short* __restrict__ va16,
                 const float* __restrict__ hap,   // [ZHA][NB][NH]
                 const float* __restrict__ bha,
                 const float* __restrict__ Wa, const float* __restrict__ ba,
                 const unsigned short* __restrict__ f16,
                 const float* __restrict__ f32,
                 unsigned short* __restrict__ A2c,
                 float* __restrict__ att_out, int t)
{
  const int b = blockIdx.x, tid = threadIdx.x;
  const int lane = tid & 63, wid = tid >> 6;
  __shared__ float ha_s[NH];
  __shared__ float wa_s[NH];
  __shared__ float red_s[128];
  __shared__ float fh_s[2][VD];

  for (int j = tid; j < NH; j += 512) {
    float s = bha[j];
#pragma unroll
    for (int z = 0; z < ZHA; ++z) s += hap[((size_t)z * NB + b) * NH + j];
    ha_s[j] = s;
    wa_s[j] = Wa[j];
  }
  __syncthreads();

  for (int r = wid; r < NR; r += 8) {
    const unsigned short* vrow = va16 + ((size_t)b * NR + r) * NH + lane * 16;
    float s = 0.f;
#pragma unroll
    for (int u = 0; u < 2; ++u) {
      const s8v v = *(const s8v*)(vrow + u * 8);
      const int j0 = lane * 16 + u * 8;
#pragma unroll
      for (int e = 0; e < 8; ++e)
        s += tanhf(b2f((unsigned short)v[e]) + ha_s[j0 + e]) * wa_s[j0 + e];
    }
    for (int o = 32; o; o >>= 1) s += __shfl_down(s, o);
    if (lane == 0) red_s[r] = s + ba[0];
  }
  __syncthreads();

  if (wid == 0) {
    float v0 = (lane < NR) ? red_s[lane] : -3.4e38f;
    float v1 = (lane + 64 < NR) ? red_s[lane + 64] : -3.4e38f;
    float m = fmaxf(v0, v1);
    for (int o = 32; o; o >>= 1) m = fmaxf(m, __shfl_xor(m, o));
    const float e0 = (lane < NR) ? expf(v0 - m) : 0.f;
    const float e1 = (lane + 64 < NR) ? expf(v1 - m) : 0.f;
    float s = e0 + e1;
    for (int o = 32; o; o >>= 1) s += __shfl_xor(s, o);
    const float inv = 1.f / s;
    if (lane < NR) red_s[lane] = e0 * inv;
    if (lane + 64 < NR) red_s[lane + 64] = e1 * inv;
  }
  __syncthreads();
  if (tid < NR) att_out[((size_t)b * NT + t) * NR + tid] = red_s[tid];

  // feat_hat: split rows across 2 thread-halves; 8 d's (16B) per thread
  const int half = tid >> 8;
  const int dd = (tid & 255) * 8;
  const int r0 = half * 50, r1 = r0 + 50;
  float fh8[8] = {};
  if constexpr (F16) {
    const unsigned short* fbase = f16 + (size_t)b * NR * VD;
    for (int r = r0; r < r1; ++r) {
      const int ro = b * NR + r;
      const s8v f = *(const s8v*)(fbase + (size_t)r * VD + (dd ^ (Frow(ro & 15) << 3)));
      const float a = red_s[r];
#pragma unroll
      for (int e = 0; e < 8; ++e) fh8[e] += a * b2f((unsigned short)f[e]);
    }
  } else {
    const float* fb = f32 + (size_t)b * NR * VD + dd;
    for (int r = r0; r < r1; ++r) {
      const float4 x0 = *(const float4*)(fb + (size_t)r * VD);
      const float4 x1 = *(const float4*)(fb + (size_t)r * VD + 4);
      const float a = red_s[r];
      fh8[0] += a * x0.x; fh8[1] += a * x0.y; fh8[2] += a * x0.z; fh8[3] += a * x0.w;
      fh8[4] += a * x1.x; fh8[5] += a * x1.y; fh8[6] += a * x1.z; fh8[7] += a * x1.w;
    }
  }
#pragma unroll
  for (int e = 0; e < 8; ++e) fh_s[half][dd + e] = fh8[e];
  __syncthreads();

  unsigned short* rowbase = A2c + (size_t)b * KGC;
  const int Fs = Frow(b & 15) << 3;
  const int d0 = tid * 4;
#pragma unroll
  for (int e = 0; e < 4; ++e) {
    const float v = (fh_s[0][d0 + e] + fh_s[1][d0 + e]) * (1.f / NR);
    store1(rowbase, d0 + e, v, Fs);
  }
}

inline void convB(hipStream_t st, const float* src, int srcld, int K, int N,
                  unsigned short* dst, int dstld, int coff)
{
  dim3 g((K + 31) / 32, (N + 31) / 32);
  convB_k<<<g, 256, 0, st>>>(src, srcld, K, N, dst, dstld, coff);
}

} // namespace

extern "C" void kernel_launch(void* const* d_in, const int* in_sizes, int n_in,
                              void* d_out, int out_size, void* d_ws, size_t ws_size,
                              hipStream_t stream)
{
  const int*   caption = (const int*)  d_in[0];
  const float* feat    = (const float*)d_in[1];
  const float* emb     = (const float*)d_in[2];
  const float* W_vin   = (const float*)d_in[3];
  const float* b_vin   = (const float*)d_in[4];
  const float* W_ih_v  = (const float*)d_in[5];
  const float* W_hh_v  = (const float*)d_in[6];
  const float* b_v     = (const float*)d_in[7];
  const float* W_va    = (const float*)d_in[8];
  const float* b_va    = (const float*)d_in[9];
  const float* W_ha    = (const float*)d_in[10];
  const float* b_ha    = (const float*)d_in[11];
  const float* W_a     = (const float*)d_in[12];
  const float* b_a     = (const float*)d_in[13];
  const float* W_ih_c  = (const float*)d_in[14];
  const float* W_hh_c  = (const float*)d_in[15];
  const float* b_c     = (const float*)d_in[16];
  const float* W_cls   = (const float*)d_in[17];
  const float* b_cls   = (const float*)d_in[18];

  float* out_repr = (float*)d_out;                       // [NB,NT,VOC]
  float* out_att  = out_repr + (size_t)NB * NT * VOC;    // [NB,NT,NR]

  char* cur = (char*)d_ws;
  auto take = [&](size_t bytes) { char* p = cur; cur += bytes; return p; };

  unsigned short* A2v  = (unsigned short*)take((size_t)NB * A2VLD * 2);      // 1MB
  unsigned short* A2c  = (unsigned short*)take((size_t)NB * KGC * 2);        // 2MB
  float* CV            = (float*)take((size_t)NB * NH * 4);
  float* CC            = (float*)take((size_t)NB * NH * 4);
  const size_t ZERO_BYTES = (size_t)NB * A2VLD * 2 + (size_t)NB * KGC * 2
                          + 2 * (size_t)NB * NH * 4;

  float* VINP          = (float*)take((size_t)NB * IND * 4);
  unsigned short* X2   = (unsigned short*)take((size_t)NB * NT * X2LD * 2);  // 3.3MB
  float* FMG           = (float*)take((size_t)NB * H4 * 4);
  unsigned short* FM16 = (unsigned short*)take((size_t)NB * KFM * 2);        // 1MB
  unsigned short* VA16 = (unsigned short*)take((size_t)NB * NR * NH * 2);    // 52MB
  float* GP            = (float*)take((size_t)8 * NB * H4 * 4);              // 33.5MB (setup Z=8)
  float* HAP           = (float*)take((size_t)ZHA * NB * NH * 4);            // 8.4MB
  unsigned short* OUTH2= (unsigned short*)take((size_t)NB * NT * KCL * 2);   // 10.5MB
  unsigned short* Wgv2t= (unsigned short*)take((size_t)H4 * KGV * 2);        // 19.4MB
  unsigned short* Wha2t= (unsigned short*)take((size_t)NH * KHA * 2);        // 2.1MB
  unsigned short* Wgc2t= (unsigned short*)take((size_t)H4 * KGC * 2);        // 33.5MB
  unsigned short* Wfmg = (unsigned short*)take((size_t)H4 * KFM * 2);        // 16.8MB
  unsigned short* WvinT= (unsigned short*)take((size_t)NVI * KFM * 2);       // 1.6MB
  unsigned short* Wcls2t=(unsigned short*)take((size_t)VOCP * KCL * 2);      // 20.7MB
  unsigned short* Wva16t=(unsigned short*)take((size_t)NH * VD * 2);         // 4.2MB
  unsigned short* FEAT16=(unsigned short*)cur;                               // 105MB optional
  const bool useF16 = ((size_t)(cur - (char*)d_ws) + (size_t)NB * NR * VD * 2) <= ws_size;

  hipMemsetAsync(A2v, 0, ZERO_BYTES, stream);

  // ---- weight conversions (all swizzled bf16-hi) ----
  convB(stream, W_ih_v + (size_t)2048 * H4, H4, 1024, H4, Wgv2t, KGV, 0);
  convB(stream, W_hh_v,                     H4, 1024, H4, Wgv2t, KGV, 1024);
  convB(stream, W_ih_v + (size_t)3072 * H4, H4, 300,  H4, Wgv2t, KGV, 2048);
  zpad_swz_k<<<((H4 * (KGV - 2348)) + 255) / 256, 256, 0, stream>>>(
      Wgv2t, KGV, 2348, H4);
  convB(stream, W_ha, NH, 1024, NH, Wha2t, KHA, 0);
  convB(stream, W_ih_c,                     H4, 2048, H4, Wgc2t, KGC, 0);
  convB(stream, W_ih_c + (size_t)2048 * H4, H4, 1024, H4, Wgc2t, KGC, 2048);
  convB(stream, W_hh_c,                     H4, 1024, H4, Wgc2t, KGC, 3072);
  convB(stream, W_ih_v,                     H4, 2048, H4, Wfmg,  KFM, 0);
  convB(stream, W_vin, IND, 2048, IND, WvinT, KFM, 0);
  zfill_k<<<(((NVI - IND) * KFM) + 255) / 256, 256, 0, stream>>>(
      WvinT + (size_t)IND * KFM, (NVI - IND) * KFM);
  convB(stream, W_cls, VOC, 1024, VOC, Wcls2t, KCL, 0);
  zfill_k<<<(((VOCP - VOC) * KCL) + 255) / 256, 256, 0, stream>>>(
      Wcls2t + (size_t)VOC * KCL, (VOCP - VOC) * KCL);
  convB(stream, W_va, NH, VD, NH, Wva16t, VD, 0);

  // ---- setup ----
  feat_pass_k<<<(NB * (VD / 8) + 255) / 256, 256, 0, stream>>>(
      feat, FM16, useF16 ? FEAT16 : nullptr);
  // VINP via MFMA split-K (BN=128, Z=8)
  gemm_sk2<false, 128><<<dim3(NVI / 128, 2, ZFM), 256, 0, stream>>>(
      FM16, KFM, nullptr, 0, WvinT, KFM, GP, NVI, KFM, KSF);
  vinp_red_k<<<(NB * IND + 255) / 256, 256, 0, stream>>>(GP, b_vin, VINP);
  build_x2_k<<<(NB * NT * X2LD + 255) / 256, 256, 0, stream>>>(caption, emb, VINP, X2);
  // FMG via MFMA split-K (BN=128, Z=8)
  gemm_sk2<false, 128><<<dim3(H4 / 128, 2, ZFM), 256, 0, stream>>>(
      FM16, KFM, nullptr, 0, Wfmg, KFM, GP, H4, KFM, KSF);
  fmg_red_k<<<(NB * H4 + 255) / 256, 256, 0, stream>>>(GP, b_v, FMG);
  if (useF16) {
    dim3 g((NB * NR) / 128, NH / 128);
    gemm128<true><<<g, 256, 0, stream>>>(
        FEAT16, VD, Wva16t, VD, VA16, NH, b_va, NH, VD);
  } else {
    dim3 g((NB * NR) / 128, NH / 128);
    gemm_va_f32<<<g, 256, 0, stream>>>(feat, VD, Wva16t, VD, VA16, NH, b_va, NH, VD);
  }

  // ---- sequential decode ----
  for (int t = 0; t < NT; ++t) {
    // gates_v: BN=64, Z=4 -> 512 blocks, half the partial traffic
    gemm_sk2<true, 64><<<dim3(H4 / 64, 2, ZGV), 256, 0, stream>>>(
        A2v, A2VLD, X2, t, Wgv2t, KGV, GP, H4, KGV, KSV);
    lstm_pw_v_k<<<(NB * NH + 255) / 256, 256, 0, stream>>>(GP, FMG, CV, A2c, A2v);
    // ha: BN=64, Z=8 -> 256 blocks (1/CU)
    gemm_sk2<false, 64><<<dim3(NH / 64, 2, ZHA), 256, 0, stream>>>(
        A2c + 2048, KGC, nullptr, 0, Wha2t, KHA, HAP, NH, KHA, KSH);
    if (useF16)
      att_fused_k<true><<<NB, 512, 0, stream>>>(
          VA16, HAP, b_ha, W_a, b_a, FEAT16, nullptr, A2c, out_att, t);
    else
      att_fused_k<false><<<NB, 512, 0, stream>>>(
          VA16, HAP, b_ha, W_a, b_a, nullptr, feat, A2c, out_att, t);
    // gates_c: BN=64, Z=4
    gemm_sk2<false, 64><<<dim3(H4 / 64, 2, ZGC), 256, 0, stream>>>(
        A2c, KGC, nullptr, 0, Wgc2t, KGC, GP, H4, KGC, KSC);
    lstm_pw_c_k<<<(NB * NH + 255) / 256, 256, 0, stream>>>(GP, b_c, CC, A2v, A2c, OUTH2, t);
  }

  // ---- classifier: 128x128 tiles, plain bf16 both sides, K=1024 ----
  {
    dim3 g((NB * NT) / 128, VOCP / 128);
    gemm128<false><<<g, 256, 0, stream>>>(
        OUTH2, KCL, Wcls2t, KCL, out_repr, VOC, b_cls, VOC, KCL);
  }
}